// Round 4
// baseline (2837.362 us; speedup 1.0000x reference)
//
#include <hip/hip_runtime.h>
#include <stdint.h>

#define Bz 256
#define Tz 128
#define DWz 768
#define DHz 768
#define G4z 3072
#define NBLK 96

typedef __attribute__((ext_vector_type(8))) short short8;
typedef __attribute__((ext_vector_type(4))) float f32x4;
typedef __attribute__((ext_vector_type(4))) int i32x4;

__device__ __forceinline__ unsigned short f2bf(float x) {
    union { float f; unsigned int u; } v; v.f = x;
    unsigned int u = v.u;
    return (unsigned short)((u + 0x7fffu + ((u >> 16) & 1u)) >> 16);
}
__device__ __forceinline__ float bf2f(unsigned short h) {
    union { unsigned int u; float f; } v; v.u = ((unsigned int)h) << 16;
    return v.f;
}
// fast transcendentals: v_exp_f32 + v_rcp_f32 (1-ulp class, fine vs bf16 floor)
__device__ __forceinline__ float fsigm(float x) {
    return __builtin_amdgcn_rcpf(1.0f + __builtin_amdgcn_exp2f(x * -1.4426950408889634f));
}
__device__ __forceinline__ float ftanh(float x) {
    x = fminf(fmaxf(x, -15.0f), 15.0f);           // keep e finite: no inf -> NaN
    float e = __builtin_amdgcn_exp2f(x * -2.8853900817779268f);
    return (1.0f - e) * __builtin_amdgcn_rcpf(1.0f + e);
}
__device__ __forceinline__ int sboff(int n, int k) {
    return n * 40 + ((((k >> 3) ^ ((n >> 3) & 3))) << 3) + (k & 7);
}

// ---------- fp32 -> bf16 bulk convert ----------
__global__ void k_cvt4(const float* __restrict__ src, unsigned short* __restrict__ dst, int n4) {
    int i = blockIdx.x * blockDim.x + threadIdx.x;
    int st = gridDim.x * blockDim.x;
    for (; i < n4; i += st) {
        float4 v = ((const float4*)src)[i];
        ushort4 o;
        o.x = f2bf(v.x); o.y = f2bf(v.y); o.z = f2bf(v.z); o.w = f2bf(v.w);
        ((ushort4*)dst)[i] = o;
    }
}

// ---------- gather aspect embedding ----------
__global__ void k_prep_tx(const int* __restrict__ target, const float* __restrict__ temb,
                          float* __restrict__ tx) {
    int b = blockIdx.x;
    long row = (long)target[b] * DWz;
    for (int d = threadIdx.x; d < DWz; d += blockDim.x)
        tx[b * DWz + d] = temb[row + d];
}

// ---------- Whh -> pre-swizzled bf16 blobs matching the persistent kernel's LDS layout ----
__global__ void k_prep_whh(const float* __restrict__ Whh, unsigned short* __restrict__ WhhP) {
    int id = blockIdx.x * 256 + threadIdx.x;   // [0, 48*6144)
    int dblk = id / 6144;
    int rem = id - dblk * 6144;
    int k0c = rem >> 8;
    int slot = rem & 255;
    int nl = slot >> 2, cc = slot & 3;
    int q8 = cc ^ ((nl >> 1) & 3);
    int k = k0c * 32 + q8 * 8;
    int col = (nl >> 4) * 768 + dblk * 16 + (nl & 15);
    alignas(16) unsigned short o[8];
#pragma unroll
    for (int e = 0; e < 8; ++e) o[e] = f2bf(Whh[(long)(k + e) * G4z + col]);
    *(int4*)(WhhP + (long)id * 8) = *(const int4*)o;
}

// ---------- generic fp32 tiled GEMM with bias (for const_gates) ----------
__global__ void k_gemm_f32_bias(const float* __restrict__ A, const float* __restrict__ Bm,
                                const float* __restrict__ bias, float* __restrict__ C,
                                int M, int N, int K, int lda, int ldb) {
    __shared__ float sA[16][65];
    __shared__ float sB[16][65];
    int bn = blockIdx.x * 64, bm = blockIdx.y * 64;
    int tx = threadIdx.x & 15, ty = threadIdx.x >> 4;
    float acc[4][4] = {};
    for (int k0 = 0; k0 < K; k0 += 16) {
        for (int l = threadIdx.x; l < 64 * 16; l += 256) {
            int m = l >> 4, k = l & 15;
            sA[k][m] = A[(long)(bm + m) * lda + k0 + k];
        }
        for (int l = threadIdx.x; l < 16 * 64; l += 256) {
            int k = l >> 6, n = l & 63;
            sB[k][n] = Bm[(long)(k0 + k) * ldb + bn + n];
        }
        __syncthreads();
        for (int k = 0; k < 16; ++k) {
            float a0[4], b0[4];
#pragma unroll
            for (int i = 0; i < 4; ++i) a0[i] = sA[k][ty * 4 + i];
#pragma unroll
            for (int j = 0; j < 4; ++j) b0[j] = sB[k][tx * 4 + j];
#pragma unroll
            for (int i = 0; i < 4; ++i)
#pragma unroll
                for (int j = 0; j < 4; ++j) acc[i][j] += a0[i] * b0[j];
        }
        __syncthreads();
    }
#pragma unroll
    for (int i = 0; i < 4; ++i)
#pragma unroll
        for (int j = 0; j < 4; ++j) {
            int m = bm + ty * 4 + i, n = bn + tx * 4 + j;
            C[(long)m * N + n] = acc[i][j] + bias[n];
        }
}

// ---------- xW = emb[sent] @ W_ih[:768]  (bf16 MFMA) ----------
// Output written in the LSTM-blocked layout:
//   offset(ushort) = ((t*96 + blk)*4 + gate)*2048 + tid*8 + e
__global__ __launch_bounds__(256) void k_gemm_x(const float* __restrict__ emb,
                                                const int* __restrict__ sent,
                                                const unsigned short* __restrict__ Wb,
                                                unsigned short* __restrict__ xW) {
    __shared__ unsigned short sA[128 * 40];
    __shared__ unsigned short sB[128 * 40];
    int tid = threadIdx.x;
    int n0 = blockIdx.x * 128;
    int m0 = blockIdx.y * 128;
    int wid = tid >> 6, lane = tid & 63, l15 = lane & 15, q = lane >> 4;
    int wm = wid >> 1, wn = wid & 1;

    int arow = tid >> 1;
    int kp = (tid & 1) * 16;
    int m = m0 + arow;
    int tt = m >> 8;
    int bb = m & 255;
    long gbase = (long)sent[bb * Tz + tt] * DWz;

    f32x4 acc[4][4];
    f32x4 zz = {0.f, 0.f, 0.f, 0.f};
#pragma unroll
    for (int i = 0; i < 4; ++i)
#pragma unroll
        for (int j = 0; j < 4; ++j) acc[i][j] = zz;

    for (int k0 = 0; k0 < DWz; k0 += 32) {
        {
            const float* src = emb + gbase + k0 + kp;
            alignas(16) unsigned short tmp[16];
#pragma unroll
            for (int it = 0; it < 4; ++it) {
                float4 v = ((const float4*)src)[it];
                tmp[it * 4 + 0] = f2bf(v.x); tmp[it * 4 + 1] = f2bf(v.y);
                tmp[it * 4 + 2] = f2bf(v.z); tmp[it * 4 + 3] = f2bf(v.w);
            }
            *(int4*)(sA + arow * 40 + kp) = *(const int4*)tmp;
            *(int4*)(sA + arow * 40 + kp + 8) = *(const int4*)(tmp + 8);
        }
#pragma unroll
        for (int it = 0; it < 2; ++it) {
            int s = tid + it * 256;
            int k = s >> 4;
            int n = (s & 15) * 8;
            int4 v = *(const int4*)(Wb + (long)(k0 + k) * G4z + n0 + n);
            const unsigned short* pv = (const unsigned short*)&v;
#pragma unroll
            for (int e = 0; e < 8; ++e) sB[sboff(n + e, k)] = pv[e];
        }
        __syncthreads();
        short8 af[4], bfr[4];
#pragma unroll
        for (int i = 0; i < 4; ++i)
            af[i] = *(const short8*)(sA + (wm * 64 + i * 16 + l15) * 40 + q * 8);
#pragma unroll
        for (int j = 0; j < 4; ++j) {
            int n = wn * 64 + j * 16 + l15;
            bfr[j] = *(const short8*)(sB + n * 40 + ((q ^ ((n >> 3) & 3)) << 3));
        }
#pragma unroll
        for (int i = 0; i < 4; ++i)
#pragma unroll
            for (int j = 0; j < 4; ++j)
                acc[i][j] = __builtin_amdgcn_mfma_f32_16x16x32_bf16(af[i], bfr[j], acc[i][j], 0, 0, 0);
        __syncthreads();
    }
    // blocked-layout epilogue: 8 dense dwordx4 stores per thread
#pragma unroll
    for (int j = 0; j < 4; ++j) {
        int n = n0 + wn * 64 + j * 16 + l15;         // column (gate*768 + d)
        int g = n / 768;
        int dblk = (n - g * 768) >> 4;
#pragma unroll
        for (int ip = 0; ip < 2; ++ip) {
            int row = m0 + wm * 64 + ip * 32;        // covers i4 = ip*2, ip*2+1
            int t = row >> 8;
            int bq = (row & 255) + q * 4;
            int blk = dblk * 2 + (bq >> 7);
            int tidd = ((bq & 127) >> 5) * 64 + q * 16 + l15;
            alignas(16) unsigned short o[8];
#pragma unroll
            for (int r = 0; r < 4; ++r) {
                o[r]     = f2bf(acc[ip * 2][j][r]);      // e = 0*4+r
                o[4 + r] = f2bf(acc[ip * 2 + 1][j][r]);  // e = 1*4+r
            }
            *(int4*)(xW + (((long)t * 96 + blk) * 4 + g) * 2048 + (long)tidd * 8) = *(const int4*)o;
        }
    }
}

// ---------- persistent LSTM, wave-level dataflow, single-counter arrive ----------
// 96 blocks: bm = blockIdx&1 (128 batch rows), dblk = blockIdx>>1 (16 d's per gate).
// h dependency is wave-to-wave: consumer wave wid reads only batch rows
// wid*32..wid*32+31, produced by wave wid of every producer block in the same bm.
// Arrival: each producer wave, after its counted vmcnt(4) drain of the h stores,
// fires ONE no-return agent-scope atomicAdd on cnt[bm][wid]. Consumers poll the
// single counter with ONE lane until cnt >= 48*t. This replaces the previous
// 48-line x 48-lane gather (18k load packets per poll round hammering the flag
// lines) with 1 packet/wave/round -- the poll flood was congesting the very lines
// the producers had to write through.
#define UNPACK(PF, G)                                                        \
    {                                                                        \
        const unsigned short* ch_ = (const unsigned short*)&(PF);            \
        _Pragma("unroll")                                                    \
        for (int i_ = 0; i_ < 2; ++i_)                                       \
            _Pragma("unroll")                                                \
            for (int r_ = 0; r_ < 4; ++r_)                                   \
                xg[i_][G][r_] = bf2f(ch_[i_ * 4 + r_]) + xgc[i_][G][r_];     \
    }

__global__ __launch_bounds__(256, 1) void k_lstm_all(int t0, int t1,
        const unsigned short* __restrict__ xW, const float* __restrict__ constg,
        const unsigned short* __restrict__ WhhP, unsigned short* __restrict__ Hbf,
        float* __restrict__ cbuf, const int* __restrict__ lens,
        unsigned* __restrict__ bar) {
    extern __shared__ unsigned short sB[];   // 96 KB
    int tid = threadIdx.x;
    int bm = blockIdx.x & 1;
    int dblk = blockIdx.x >> 1;
    int d0 = dblk * 16;
    int lane = tid & 63, wid = tid >> 6;
    int l15 = lane & 15, q = lane >> 4;
    int d = d0 + l15;
    unsigned* cnt = bar + ((bm * 4 + wid) << 5);   // 8 counters, 128B apart

    {   // stage pre-swizzled B once
        const int4* src = (const int4*)WhhP + (long)dblk * 6144;
        for (int s = tid; s < 6144; s += 256) ((int4*)sB)[s] = src[s];
    }

    int brow[8];
    int lenr[8];
    float c[8], h[8];
    float xgc[2][4][4];   // step-invariant gate constants, register-resident
#pragma unroll
    for (int i = 0; i < 2; ++i)
#pragma unroll
        for (int r = 0; r < 4; ++r) {
            int ir = i * 4 + r;
            int b = bm * 128 + wid * 32 + i * 16 + q * 4 + r;
            brow[ir] = b;
            lenr[ir] = lens[b];
            long cbase = (long)b * G4z + d;
#pragma unroll
            for (int j = 0; j < 4; ++j) xgc[i][j][r] = constg[cbase + j * 768];
            if (t0 > 0) {
                c[ir] = cbuf[(long)b * DHz + d];
                h[ir] = bf2f(Hbf[((long)b * Tz + (t0 - 1)) * DHz + d]);
            } else { c[ir] = 0.f; h[ir] = 0.f; }
        }

    int bbase[4];
#pragma unroll
    for (int j = 0; j < 4; ++j) {
        int nl = j * 16 + l15;
        bbase[j] = nl * 32 + ((q ^ ((nl >> 1) & 3)) << 3);
    }
    __syncthreads();

    // gate x-contributions for step t0 (blocked layout: 4 coalesced dwordx4)
    float xg[2][4][4];
    {
        const unsigned short* x0 = xW + ((long)t0 * 96 + blockIdx.x) * 8192 + (long)tid * 8;
        int4 c0 = *(const int4*)(x0);
        int4 c1 = *(const int4*)(x0 + 2048);
        int4 c2 = *(const int4*)(x0 + 4096);
        int4 c3 = *(const int4*)(x0 + 6144);
        UNPACK(c0, 0) UNPACK(c1, 1) UNPACK(c2, 2) UNPACK(c3, 3)
    }

    i32x4 pf0, pf1, pf2, pf3;   // loop-carried xW prefetch

    for (int t = t0; t < t1; ++t) {
        if (t > t0) {
            // single-counter wait: all 48 producer waves (this bm,wid) done step t-1
            unsigned tgt = (unsigned)(48 * (t - t0));
            if (lane == 0) {
                while (__hip_atomic_load(cnt, __ATOMIC_RELAXED,
                                         __HIP_MEMORY_SCOPE_AGENT) < tgt)
                    __builtin_amdgcn_s_sleep(1);
            }
            asm volatile("" ::: "memory");   // no hoisting of A-loads above the poll
            asm volatile("s_waitcnt vmcnt(0)" ::: "memory");
            __builtin_amdgcn_sched_barrier(0);
            UNPACK(pf0, 0) UNPACK(pf1, 1) UNPACK(pf2, 2) UNPACK(pf3, 3)
        }

        f32x4 acc[2][4];
        f32x4 zz = {0.f, 0.f, 0.f, 0.f};
#pragma unroll
        for (int i = 0; i < 2; ++i)
#pragma unroll
            for (int j = 0; j < 4; ++j) acc[i][j] = zz;

        if (t > 0) {
            const unsigned short* ap0 = Hbf + ((long)(bm * 128 + wid * 32 + l15) * Tz + (t - 1)) * DHz + q * 8;
            const unsigned short* ap1 = ap0 + (long)16 * Tz * DHz;
#pragma unroll 6
            for (int k0c = 0; k0c < 24; ++k0c) {
                short8 a0 = *(const short8*)(ap0 + k0c * 32);
                short8 a1 = *(const short8*)(ap1 + k0c * 32);
                const unsigned short* bb = sB + k0c * 2048;
#pragma unroll
                for (int j = 0; j < 4; ++j) {
                    short8 bf = *(const short8*)(bb + bbase[j]);
                    acc[0][j] = __builtin_amdgcn_mfma_f32_16x16x32_bf16(a0, bf, acc[0][j], 0, 0, 0);
                    acc[1][j] = __builtin_amdgcn_mfma_f32_16x16x32_bf16(a1, bf, acc[1][j], 0, 0, 0);
                }
            }
        }

        // in-register gate pointwise; h stored write-through at AGENT scope (L3)
#pragma unroll
        for (int i = 0; i < 2; ++i)
#pragma unroll
            for (int r = 0; r < 4; ++r) {
                int ir = i * 4 + r;
                float gi = acc[i][0][r] + xg[i][0][r];
                float gf = acc[i][1][r] + xg[i][1][r];
                float gg = acc[i][2][r] + xg[i][2][r];
                float go = acc[i][3][r] + xg[i][3][r];
                float cn = fsigm(gf) * c[ir] + fsigm(gi) * ftanh(gg);
                float hn = fsigm(go) * ftanh(cn);
                bool upd = t < lenr[ir];
                c[ir] = upd ? cn : c[ir];
                h[ir] = upd ? hn : h[ir];
                __hip_atomic_store(Hbf + ((long)brow[ir] * Tz + t) * DHz + d, f2bf(h[ir]),
                                   __ATOMIC_RELAXED, __HIP_MEMORY_SCOPE_AGENT);
            }

        if (t + 1 < t1) {
            // issue next-step xW loads (asm: younger than the h stores in the vmcnt
            // FIFO, so the counted wait below drains stores but not these)
            const unsigned short* pp = xW + ((long)(t + 1) * 96 + blockIdx.x) * 8192 + (long)tid * 8;
            asm volatile(
                "global_load_dwordx4 %0, %4, off\n\t"
                "global_load_dwordx4 %1, %5, off\n\t"
                "global_load_dwordx4 %2, %6, off\n\t"
                "global_load_dwordx4 %3, %7, off"
                : "=&v"(pf0), "=&v"(pf1), "=&v"(pf2), "=&v"(pf3)
                : "v"(pp), "v"(pp + 2048), "v"(pp + 4096), "v"(pp + 6144)
                : "memory");
            // counted wait: 8 h stores (older) acked at L3; 4 pf loads stay in flight
            asm volatile("s_waitcnt vmcnt(4)" ::: "memory");
            // arrival: one no-return agent atomic per wave (fire and forget)
            if (lane == 0)
                (void)__hip_atomic_fetch_add(cnt, 1u, __ATOMIC_RELAXED,
                                             __HIP_MEMORY_SCOPE_AGENT);
        }
    }
#pragma unroll
    for (int ir = 0; ir < 8; ++ir) cbuf[(long)brow[ir] * DHz + d] = c[ir];
}

// ---------- scores[b,t] = sum_d w[d]*tanh( (H@Wh)[b,t,d] ) ----------
__global__ __launch_bounds__(256) void k_scores(const unsigned short* __restrict__ Hbf,
                                                const unsigned short* __restrict__ Whb,
                                                const float* __restrict__ wv,
                                                float* __restrict__ scores) {
    __shared__ unsigned short sA[128 * 40];
    __shared__ unsigned short sB[128 * 40];
    __shared__ float sred[128];
    int tid = threadIdx.x;
    int n0 = blockIdx.x * 128;
    int m0 = blockIdx.y * 128;
    int wid = tid >> 6, lane = tid & 63, l15 = lane & 15, q = lane >> 4;
    int wm = wid >> 1, wn = wid & 1;

    f32x4 acc[4][4];
    f32x4 zz = {0.f, 0.f, 0.f, 0.f};
#pragma unroll
    for (int i = 0; i < 4; ++i)
#pragma unroll
        for (int j = 0; j < 4; ++j) acc[i][j] = zz;

    int arow = tid >> 1;
    int kp = (tid & 1) * 16;
    const unsigned short* asrc = Hbf + (long)(m0 + arow) * DHz;

    for (int k0 = 0; k0 < DHz; k0 += 32) {
        *(int4*)(sA + arow * 40 + kp) = *(const int4*)(asrc + k0 + kp);
        *(int4*)(sA + arow * 40 + kp + 8) = *(const int4*)(asrc + k0 + kp + 8);
#pragma unroll
        for (int it = 0; it < 2; ++it) {
            int s = tid + it * 256;
            int k = s >> 4;
            int n = (s & 15) * 8;
            int4 v = *(const int4*)(Whb + (long)(k0 + k) * DHz + n0 + n);
            const unsigned short* pv = (const unsigned short*)&v;
#pragma unroll
            for (int e = 0; e < 8; ++e) sB[sboff(n + e, k)] = pv[e];
        }
        __syncthreads();
        short8 af[4], bfr[4];
#pragma unroll
        for (int i = 0; i < 4; ++i)
            af[i] = *(const short8*)(sA + (wm * 64 + i * 16 + l15) * 40 + q * 8);
#pragma unroll
        for (int j = 0; j < 4; ++j) {
            int n = wn * 64 + j * 16 + l15;
            bfr[j] = *(const short8*)(sB + n * 40 + ((q ^ ((n >> 3) & 3)) << 3));
        }
#pragma unroll
        for (int i = 0; i < 4; ++i)
#pragma unroll
            for (int j = 0; j < 4; ++j)
                acc[i][j] = __builtin_amdgcn_mfma_f32_16x16x32_bf16(af[i], bfr[j], acc[i][j], 0, 0, 0);
        __syncthreads();
    }
    if (tid < 128) sred[tid] = 0.f;
    __syncthreads();
#pragma unroll
    for (int i = 0; i < 4; ++i)
#pragma unroll
        for (int r = 0; r < 4; ++r) {
            float sv = 0.f;
#pragma unroll
            for (int j = 0; j < 4; ++j) {
                int n = n0 + wn * 64 + j * 16 + l15;
                sv += ftanh(acc[i][j][r]) * wv[n];
            }
#pragma unroll
            for (int o = 1; o < 16; o <<= 1) sv += __shfl_xor(sv, o, 64);
            if (l15 == 0) atomicAdd(&sred[wm * 64 + i * 16 + q * 4 + r], sv);
        }
    __syncthreads();
    if (tid < 128) atomicAdd(&scores[m0 + tid], sred[tid]);
}

// ---------- masked softmax over T ----------
__global__ void k_softmax(const float* __restrict__ scores, const int* __restrict__ lens,
                          float* __restrict__ alpha) {
    int b = blockIdx.x, t = threadIdx.x;
    int len = lens[b];
    float s = (t < len) ? scores[b * Tz + t] : -1e9f;
    float m = s;
#pragma unroll
    for (int o = 32; o; o >>= 1) m = fmaxf(m, __shfl_xor(m, o, 64));
    __shared__ float rA[2], rB[2];
    if ((t & 63) == 0) rA[t >> 6] = m;
    __syncthreads();
    m = fmaxf(rA[0], rA[1]);
    float e = expf(s - m);
    float sum = e;
#pragma unroll
    for (int o = 32; o; o >>= 1) sum += __shfl_xor(sum, o, 64);
    if ((t & 63) == 0) rB[t >> 6] = sum;
    __syncthreads();
    sum = rB[0] + rB[1];
    alpha[b * Tz + t] = e / sum;
}

// ---------- r[b,d] = sum_t alpha[b,t] * H[b,t,d] ----------
__global__ void k_r(const float* __restrict__ alpha, const unsigned short* __restrict__ Hbf,
                    float* __restrict__ rbuf) {
    int b = blockIdx.x;
    __shared__ float sal[Tz];
    if (threadIdx.x < Tz) sal[threadIdx.x] = alpha[b * Tz + threadIdx.x];
    __syncthreads();
    for (int d = threadIdx.x; d < DHz; d += blockDim.x) {
        float acc = 0.f;
        for (int t = 0; t < Tz; ++t) acc += sal[t] * bf2f(Hbf[((long)b * Tz + t) * DHz + d]);
        rbuf[(long)b * DHz + d] = acc;
    }
}

// ---------- h_star = tanh(r@Wp + H[:, -1, :]@Wx) ----------
__global__ void k_hstar(const float* __restrict__ rbuf, const unsigned short* __restrict__ Hbf,
                        const float* __restrict__ Wp, const float* __restrict__ Wx,
                        float* __restrict__ hst) {
    __shared__ float sA[16][65];
    __shared__ float sB[16][65];
    int bn = blockIdx.x * 64, bm = blockIdx.y * 64;
    int tx = threadIdx.x & 15, ty = threadIdx.x >> 4;
    float acc[4][4] = {};
    for (int src = 0; src < 2; ++src) {
        const float* Bm = src ? Wx : Wp;
        for (int k0 = 0; k0 < DHz; k0 += 16) {
            for (int l = threadIdx.x; l < 64 * 16; l += 256) {
                int mm = l >> 4, kk = l & 15;
                sA[kk][mm] = src ? bf2f(Hbf[((long)(bm + mm) * Tz + (Tz - 1)) * DHz + k0 + kk])
                                 : rbuf[(long)(bm + mm) * DHz + k0 + kk];
            }
            for (int l = threadIdx.x; l < 16 * 64; l += 256) {
                int kk = l >> 6, nn = l & 63;
                sB[kk][nn] = Bm[(long)(k0 + kk) * DHz + bn + nn];
            }
            __syncthreads();
            for (int k = 0; k < 16; ++k) {
                float a0[4], b0[4];
#pragma unroll
                for (int i = 0; i < 4; ++i) a0[i] = sA[k][ty * 4 + i];
#pragma unroll
                for (int j = 0; j < 4; ++j) b0[j] = sB[k][tx * 4 + j];
#pragma unroll
                for (int i = 0; i < 4; ++i)
#pragma unroll
                    for (int j = 0; j < 4; ++j) acc[i][j] += a0[i] * b0[j];
            }
            __syncthreads();
        }
    }
#pragma unroll
    for (int i = 0; i < 4; ++i)
#pragma unroll
        for (int j = 0; j < 4; ++j)
            hst[(long)(bm + ty * 4 + i) * DHz + bn + tx * 4 + j] = ftanh(acc[i][j]);
}

// ---------- logits ----------
__global__ void k_logits(const float* __restrict__ hst, const float* __restrict__ Wl,
                         const float* __restrict__ bl, float* __restrict__ out) {
    int b = blockIdx.x;
    int lane = threadIdx.x & 63, c = threadIdx.x >> 6;
    float s = 0.f;
    for (int k = lane; k < DHz; k += 64) s += hst[(long)b * DHz + k] * Wl[k * 3 + c];
#pragma unroll
    for (int o = 32; o; o >>= 1) s += __shfl_xor(s, o, 64);
    if (lane == 0) out[b * 3 + c] = s + bl[c];
}

extern "C" void kernel_launch(void* const* d_in, const int* in_sizes, int n_in,
                              void* d_out, int out_size, void* d_ws, size_t ws_size,
                              hipStream_t stream) {
    (void)in_sizes; (void)n_in; (void)out_size; (void)ws_size;
    const int*   sent   = (const int*)d_in[0];
    const int*   target = (const int*)d_in[1];
    const int*   lens   = (const int*)d_in[2];
    const float* emb    = (const float*)d_in[3];
    const float* temb   = (const float*)d_in[4];
    const float* W_ih   = (const float*)d_in[5];
    const float* W_hh   = (const float*)d_in[6];
    const float* b_lstm = (const float*)d_in[7];
    const float* Wh     = (const float*)d_in[8];
    const float* wv     = (const float*)d_in[10];
    const float* Wp     = (const float*)d_in[11];
    const float* Wx     = (const float*)d_in[12];
    const float* W_lin  = (const float*)d_in[13];
    const float* b_lin  = (const float*)d_in[14];
    float* out = (float*)d_out;

    char* ws = (char*)d_ws;
    size_t off = 0;
    auto alloc = [&](size_t bytes) -> void* {
        void* p = ws + off;
        off = (off + bytes + 255) & ~(size_t)255;
        return p;
    };
    unsigned short* xW   = (unsigned short*)alloc((size_t)32768 * G4z * 2);
    unsigned short* Hbf  = (unsigned short*)alloc((size_t)Bz * Tz * DHz * 2);
    unsigned short* Wihb = (unsigned short*)alloc((size_t)DWz * G4z * 2);
    unsigned short* WhhP = (unsigned short*)alloc((size_t)48 * 6144 * 16);
    unsigned short* Whb  = (unsigned short*)alloc((size_t)DHz * DHz * 2);
    float* tx     = (float*)alloc((size_t)Bz * DWz * 4);
    float* constg = (float*)alloc((size_t)Bz * G4z * 4);
    float* cbuf   = (float*)alloc((size_t)Bz * DHz * 4);
    float* scores = (float*)alloc((size_t)Bz * Tz * 4);
    float* alpha  = (float*)alloc((size_t)Bz * Tz * 4);
    float* rbuf   = (float*)alloc((size_t)Bz * DHz * 4);
    float* hst    = (float*)alloc((size_t)Bz * DHz * 4);
    unsigned* bar = (unsigned*)alloc(4096);   // 8 arrival counters, 128B apart

    k_cvt4<<<1024, 256, 0, stream>>>(W_ih, Wihb, DWz * G4z / 4);
    k_cvt4<<<512, 256, 0, stream>>>(Wh, Whb, DHz * DHz / 4);
    k_prep_whh<<<1152, 256, 0, stream>>>(W_hh, WhhP);
    k_prep_tx<<<Bz, 256, 0, stream>>>(target, temb, tx);
    hipMemsetAsync(scores, 0, (size_t)Bz * Tz * 4, stream);
    hipMemsetAsync(bar, 0, 4096, stream);

    k_gemm_f32_bias<<<dim3(48, 4), 256, 0, stream>>>(tx, W_ih + (size_t)DWz * G4z, b_lstm,
                                                     constg, Bz, G4z, DWz, DWz, G4z);
    k_gemm_x<<<dim3(24, 256), 256, 0, stream>>>(emb, sent, Wihb, xW);

    hipFuncSetAttribute((const void*)k_lstm_all,
                        hipFuncAttributeMaxDynamicSharedMemorySize, 98304);
    int t0v = 0, t1v = Tz;
    const unsigned short* xWp = xW;
    const float* cgp = constg;
    const unsigned short* whp = WhhP;
    unsigned short* hbp = Hbf;
    float* cbp = cbuf;
    const int* lnp = lens;
    unsigned* barp = bar;
    void* kargs[] = {&t0v, &t1v, &xWp, &cgp, &whp, &hbp, &cbp, &lnp, &barp};
    hipError_t ce = hipLaunchCooperativeKernel(reinterpret_cast<void*>(k_lstm_all),
                                               dim3(NBLK), dim3(256), kargs, 98304, stream);
    if (ce != hipSuccess) {
        for (int t = 0; t < Tz; ++t)
            k_lstm_all<<<NBLK, 256, 98304, stream>>>(t, t + 1, xW, constg, WhhP, Hbf, cbuf, lens, bar);
    }

    k_scores<<<dim3(6, 256), 256, 0, stream>>>(Hbf, Whb, wv, scores);
    k_softmax<<<Bz, 128, 0, stream>>>(scores, lens, alpha);
    k_r<<<Bz, 256, 0, stream>>>(alpha, Hbf, rbuf);
    k_hstar<<<dim3(12, 4), 256, 0, stream>>>(rbuf, Hbf, Wp, Wx, hst);
    k_logits<<<Bz, 192, 0, stream>>>(hst, W_lin, b_lin, out);
}

// Round 6
// 2552.265 us; speedup vs baseline: 1.1117x; 1.1117x over previous
//
#include <hip/hip_runtime.h>
#include <stdint.h>

#define Bz 256
#define Tz 128
#define DWz 768
#define DHz 768
#define G4z 3072
#define NBLK 96
#define VOCABz 50000   // problem constant (reference: VOCAB = 50000)

typedef __attribute__((ext_vector_type(8))) short short8;
typedef __attribute__((ext_vector_type(4))) float f32x4;
typedef __attribute__((ext_vector_type(4))) int i32x4;

__device__ __forceinline__ unsigned short f2bf(float x) {
    union { float f; unsigned int u; } v; v.f = x;
    unsigned int u = v.u;
    return (unsigned short)((u + 0x7fffu + ((u >> 16) & 1u)) >> 16);
}
__device__ __forceinline__ float bf2f(unsigned short h) {
    union { unsigned int u; float f; } v; v.u = ((unsigned int)h) << 16;
    return v.f;
}
// fast transcendentals: v_exp_f32 + v_rcp_f32 (1-ulp class, fine vs bf16 floor)
__device__ __forceinline__ float fsigm(float x) {
    return __builtin_amdgcn_rcpf(1.0f + __builtin_amdgcn_exp2f(x * -1.4426950408889634f));
}
__device__ __forceinline__ float ftanh(float x) {
    x = fminf(fmaxf(x, -15.0f), 15.0f);           // keep e finite: no inf -> NaN
    float e = __builtin_amdgcn_exp2f(x * -2.8853900817779268f);
    return (1.0f - e) * __builtin_amdgcn_rcpf(1.0f + e);
}
__device__ __forceinline__ int sboff(int n, int k) {
    return n * 40 + ((((k >> 3) ^ ((n >> 3) & 3))) << 3) + (k & 7);
}

// ---------- fp32 -> bf16 bulk convert ----------
__global__ void k_cvt4(const float* __restrict__ src, unsigned short* __restrict__ dst, int n4) {
    int i = blockIdx.x * blockDim.x + threadIdx.x;
    int st = gridDim.x * blockDim.x;
    for (; i < n4; i += st) {
        float4 v = ((const float4*)src)[i];
        ushort4 o;
        o.x = f2bf(v.x); o.y = f2bf(v.y); o.z = f2bf(v.z); o.w = f2bf(v.w);
        ((ushort4*)dst)[i] = o;
    }
}

// ---------- gather aspect embedding ----------
__global__ void k_prep_tx(const int* __restrict__ target, const float* __restrict__ temb,
                          float* __restrict__ tx) {
    int b = blockIdx.x;
    long row = (long)target[b] * DWz;
    for (int d = threadIdx.x; d < DWz; d += blockDim.x)
        tx[b * DWz + d] = temb[row + d];
}

// ---------- Whh -> pre-swizzled bf16 blobs (coalesced reads via LDS transpose) ----
// Same output layout as r0-r4: id = dblk*6144 + k0c*256 + slot, 8 bf16 per id.
// Block (dblk,k0c) loads its 32x64 fp32 source tile coalesced (float4 x2/thread),
// stages in LDS, emits in consumer-swizzled order.
__global__ __launch_bounds__(256) void k_prep_whh(const float* __restrict__ Whh,
                                                  unsigned short* __restrict__ WhhP) {
    __shared__ float sT[32][65];
    int bid = blockIdx.x;            // [0, 1152)
    int dblk = bid / 24;
    int k0c = bid - dblk * 24;
    int tid = threadIdx.x;

    {   // load 32 rows x 64 cols (4 gate groups of 16), coalesced
        int kk = tid >> 3;           // 0..31
        int seg = tid & 7;           // 0..7
        const float* src = Whh + (long)(k0c * 32 + kk) * G4z
                         + (seg >> 1) * 768 + dblk * 16 + (seg & 1) * 8;
        float4 v0 = *(const float4*)src;
        float4 v1 = *(const float4*)(src + 4);
        int cl = seg * 8;
        sT[kk][cl + 0] = v0.x; sT[kk][cl + 1] = v0.y; sT[kk][cl + 2] = v0.z; sT[kk][cl + 3] = v0.w;
        sT[kk][cl + 4] = v1.x; sT[kk][cl + 5] = v1.y; sT[kk][cl + 6] = v1.z; sT[kk][cl + 7] = v1.w;
    }
    __syncthreads();
    {   // emit in consumer order
        int nl = tid >> 2, cc = tid & 3;
        int q8 = cc ^ ((nl >> 1) & 3);
        int clv = (nl >> 4) * 16 + (nl & 15);
        alignas(16) unsigned short o[8];
#pragma unroll
        for (int e = 0; e < 8; ++e) o[e] = f2bf(sT[q8 * 8 + e][clv]);
        *(int4*)(WhhP + (long)(dblk * 6144 + k0c * 256 + tid) * 8) = *(const int4*)o;
    }
}

// ---------- generic fp32 tiled GEMM with bias (for const_gates) ----------
__global__ void k_gemm_f32_bias(const float* __restrict__ A, const float* __restrict__ Bm,
                                const float* __restrict__ bias, float* __restrict__ C,
                                int M, int N, int K, int lda, int ldb) {
    __shared__ float sA[16][65];
    __shared__ float sB[16][65];
    int bn = blockIdx.x * 64, bm = blockIdx.y * 64;
    int tx = threadIdx.x & 15, ty = threadIdx.x >> 4;
    float acc[4][4] = {};
    for (int k0 = 0; k0 < K; k0 += 16) {
        for (int l = threadIdx.x; l < 64 * 16; l += 256) {
            int m = l >> 4, k = l & 15;
            sA[k][m] = A[(long)(bm + m) * lda + k0 + k];
        }
        for (int l = threadIdx.x; l < 16 * 64; l += 256) {
            int k = l >> 6, n = l & 63;
            sB[k][n] = Bm[(long)(k0 + k) * ldb + bn + n];
        }
        __syncthreads();
        for (int k = 0; k < 16; ++k) {
            float a0[4], b0[4];
#pragma unroll
            for (int i = 0; i < 4; ++i) a0[i] = sA[k][ty * 4 + i];
#pragma unroll
            for (int j = 0; j < 4; ++j) b0[j] = sB[k][tx * 4 + j];
#pragma unroll
            for (int i = 0; i < 4; ++i)
#pragma unroll
                for (int j = 0; j < 4; ++j) acc[i][j] += a0[i] * b0[j];
        }
        __syncthreads();
    }
#pragma unroll
    for (int i = 0; i < 4; ++i)
#pragma unroll
        for (int j = 0; j < 4; ++j) {
            int m = bm + ty * 4 + i, n = bn + tx * 4 + j;
            C[(long)m * N + n] = acc[i][j] + bias[n];
        }
}

// ---------- xW = emb[sent] @ W_ih[:768]  (bf16 MFMA) ----------
// Output written in the LSTM-blocked layout:
//   offset(ushort) = ((t*96 + blk)*4 + gate)*2048 + tid*8 + e
// A path: if ebb, emb is pre-converted bf16 (2 x int4 loads, no VALU convert);
// else fp32 + inline f2bf (fallback when workspace can't fit embb).
__global__ __launch_bounds__(256) void k_gemm_x(const float* __restrict__ emb,
                                                const unsigned short* __restrict__ embb,
                                                int ebb,
                                                const int* __restrict__ sent,
                                                const unsigned short* __restrict__ Wb,
                                                unsigned short* __restrict__ xW) {
    __shared__ unsigned short sA[128 * 40];
    __shared__ unsigned short sB[128 * 40];
    int tid = threadIdx.x;
    int n0 = blockIdx.x * 128;
    int m0 = blockIdx.y * 128;
    int wid = tid >> 6, lane = tid & 63, l15 = lane & 15, q = lane >> 4;
    int wm = wid >> 1, wn = wid & 1;

    int arow = tid >> 1;
    int kp = (tid & 1) * 16;
    int m = m0 + arow;
    int tt = m >> 8;
    int bb = m & 255;
    long gbase = (long)sent[bb * Tz + tt] * DWz;

    f32x4 acc[4][4];
    f32x4 zz = {0.f, 0.f, 0.f, 0.f};
#pragma unroll
    for (int i = 0; i < 4; ++i)
#pragma unroll
        for (int j = 0; j < 4; ++j) acc[i][j] = zz;

    for (int k0 = 0; k0 < DWz; k0 += 32) {
        if (ebb) {
            const unsigned short* src = embb + gbase + k0 + kp;
            *(int4*)(sA + arow * 40 + kp) = *(const int4*)src;
            *(int4*)(sA + arow * 40 + kp + 8) = *(const int4*)(src + 8);
        } else {
            const float* src = emb + gbase + k0 + kp;
            alignas(16) unsigned short tmp[16];
#pragma unroll
            for (int it = 0; it < 4; ++it) {
                float4 v = ((const float4*)src)[it];
                tmp[it * 4 + 0] = f2bf(v.x); tmp[it * 4 + 1] = f2bf(v.y);
                tmp[it * 4 + 2] = f2bf(v.z); tmp[it * 4 + 3] = f2bf(v.w);
            }
            *(int4*)(sA + arow * 40 + kp) = *(const int4*)tmp;
            *(int4*)(sA + arow * 40 + kp + 8) = *(const int4*)(tmp + 8);
        }
#pragma unroll
        for (int it = 0; it < 2; ++it) {
            int s = tid + it * 256;
            int k = s >> 4;
            int n = (s & 15) * 8;
            int4 v = *(const int4*)(Wb + (long)(k0 + k) * G4z + n0 + n);
            const unsigned short* pv = (const unsigned short*)&v;
#pragma unroll
            for (int e = 0; e < 8; ++e) sB[sboff(n + e, k)] = pv[e];
        }
        __syncthreads();
        short8 af[4], bfr[4];
#pragma unroll
        for (int i = 0; i < 4; ++i)
            af[i] = *(const short8*)(sA + (wm * 64 + i * 16 + l15) * 40 + q * 8);
#pragma unroll
        for (int j = 0; j < 4; ++j) {
            int n = wn * 64 + j * 16 + l15;
            bfr[j] = *(const short8*)(sB + n * 40 + ((q ^ ((n >> 3) & 3)) << 3));
        }
#pragma unroll
        for (int i = 0; i < 4; ++i)
#pragma unroll
            for (int j = 0; j < 4; ++j)
                acc[i][j] = __builtin_amdgcn_mfma_f32_16x16x32_bf16(af[i], bfr[j], acc[i][j], 0, 0, 0);
        __syncthreads();
    }
    // blocked-layout epilogue: 8 dense dwordx4 stores per thread
#pragma unroll
    for (int j = 0; j < 4; ++j) {
        int n = n0 + wn * 64 + j * 16 + l15;         // column (gate*768 + d)
        int g = n / 768;
        int dblk = (n - g * 768) >> 4;
#pragma unroll
        for (int ip = 0; ip < 2; ++ip) {
            int row = m0 + wm * 64 + ip * 32;        // covers i4 = ip*2, ip*2+1
            int t = row >> 8;
            int bq = (row & 255) + q * 4;
            int blk = dblk * 2 + (bq >> 7);
            int tidd = ((bq & 127) >> 5) * 64 + q * 16 + l15;
            alignas(16) unsigned short o[8];
#pragma unroll
            for (int r = 0; r < 4; ++r) {
                o[r]     = f2bf(acc[ip * 2][j][r]);      // e = 0*4+r
                o[4 + r] = f2bf(acc[ip * 2 + 1][j][r]);  // e = 1*4+r
            }
            *(int4*)(xW + (((long)t * 96 + blk) * 4 + g) * 2048 + (long)tidd * 8) = *(const int4*)o;
        }
    }
}

// ---------- persistent LSTM, barrier-free wave-level dataflow, AGENT scope ----------
// Round-3 scheme (measured best): flags[bm][wid][dblk] on 128B-spaced single-writer
// lines, written once per step per producer wave after a counted vmcnt(4) drain;
// consumers 48-lane-gather-poll their flag group. (Round-4's single atomic counter
// regressed: RMW chain on one hot line serializes arrivals and the poll loads
// queue behind the line lock.)
#define UNPACK(PF, G)                                                        \
    {                                                                        \
        const unsigned short* ch_ = (const unsigned short*)&(PF);            \
        _Pragma("unroll")                                                    \
        for (int i_ = 0; i_ < 2; ++i_)                                       \
            _Pragma("unroll")                                                \
            for (int r_ = 0; r_ < 4; ++r_)                                   \
                xg[i_][G][r_] = bf2f(ch_[i_ * 4 + r_]) + xgc[i_][G][r_];     \
    }

__global__ __launch_bounds__(256, 1) void k_lstm_all(int t0, int t1,
        const unsigned short* __restrict__ xW, const float* __restrict__ constg,
        const unsigned short* __restrict__ WhhP, unsigned short* __restrict__ Hbf,
        float* __restrict__ cbuf, const int* __restrict__ lens,
        unsigned* __restrict__ bar) {
    extern __shared__ unsigned short sB[];   // 96 KB
    int tid = threadIdx.x;
    int bm = blockIdx.x & 1;
    int dblk = blockIdx.x >> 1;
    int d0 = dblk * 16;
    int lane = tid & 63, wid = tid >> 6;
    int l15 = lane & 15, q = lane >> 4;
    int d = d0 + l15;
    // flags[bm][wid][dblk] at 128B spacing: group base + dblk*32 u32
    unsigned* flg = bar + ((bm * 4 + wid) * 48) * 32;

    {   // stage pre-swizzled B once
        const int4* src = (const int4*)WhhP + (long)dblk * 6144;
        for (int s = tid; s < 6144; s += 256) ((int4*)sB)[s] = src[s];
    }

    int brow[8];
    int lenr[8];
    float c[8], h[8];
    float xgc[2][4][4];   // step-invariant gate constants, register-resident
#pragma unroll
    for (int i = 0; i < 2; ++i)
#pragma unroll
        for (int r = 0; r < 4; ++r) {
            int ir = i * 4 + r;
            int b = bm * 128 + wid * 32 + i * 16 + q * 4 + r;
            brow[ir] = b;
            lenr[ir] = lens[b];
            long cbase = (long)b * G4z + d;
#pragma unroll
            for (int j = 0; j < 4; ++j) xgc[i][j][r] = constg[cbase + j * 768];
            if (t0 > 0) {
                c[ir] = cbuf[(long)b * DHz + d];
                h[ir] = bf2f(Hbf[((long)b * Tz + (t0 - 1)) * DHz + d]);
            } else { c[ir] = 0.f; h[ir] = 0.f; }
        }

    int bbase[4];
#pragma unroll
    for (int j = 0; j < 4; ++j) {
        int nl = j * 16 + l15;
        bbase[j] = nl * 32 + ((q ^ ((nl >> 1) & 3)) << 3);
    }
    __syncthreads();

    // gate x-contributions for step t0 (blocked layout: 4 coalesced dwordx4)
    float xg[2][4][4];
    {
        const unsigned short* x0 = xW + ((long)t0 * 96 + blockIdx.x) * 8192 + (long)tid * 8;
        int4 c0 = *(const int4*)(x0);
        int4 c1 = *(const int4*)(x0 + 2048);
        int4 c2 = *(const int4*)(x0 + 4096);
        int4 c3 = *(const int4*)(x0 + 6144);
        UNPACK(c0, 0) UNPACK(c1, 1) UNPACK(c2, 2) UNPACK(c3, 3)
    }

    i32x4 pf0, pf1, pf2, pf3;   // loop-carried xW prefetch

    for (int t = t0; t < t1; ++t) {
        if (t > t0) {
            // wave-local wait: all 48 producer waves (this wid) done with step t-1
            unsigned tgt = (unsigned)t;
            const unsigned* fp = flg + lane * 32;
            while (true) {
                unsigned v = (lane < 48)
                    ? __hip_atomic_load(fp, __ATOMIC_RELAXED, __HIP_MEMORY_SCOPE_AGENT)
                    : tgt;
                if (__all(v >= tgt)) break;
                __builtin_amdgcn_s_sleep(1);
            }
            asm volatile("s_waitcnt vmcnt(0)" ::: "memory");
            __builtin_amdgcn_sched_barrier(0);
            UNPACK(pf0, 0) UNPACK(pf1, 1) UNPACK(pf2, 2) UNPACK(pf3, 3)
        }

        f32x4 acc[2][4];
        f32x4 zz = {0.f, 0.f, 0.f, 0.f};
#pragma unroll
        for (int i = 0; i < 2; ++i)
#pragma unroll
            for (int j = 0; j < 4; ++j) acc[i][j] = zz;

        if (t > 0) {
            const unsigned short* ap0 = Hbf + ((long)(bm * 128 + wid * 32 + l15) * Tz + (t - 1)) * DHz + q * 8;
            const unsigned short* ap1 = ap0 + (long)16 * Tz * DHz;
#pragma unroll 6
            for (int k0c = 0; k0c < 24; ++k0c) {
                short8 a0 = *(const short8*)(ap0 + k0c * 32);
                short8 a1 = *(const short8*)(ap1 + k0c * 32);
                const unsigned short* bb = sB + k0c * 2048;
#pragma unroll
                for (int j = 0; j < 4; ++j) {
                    short8 bf = *(const short8*)(bb + bbase[j]);
                    acc[0][j] = __builtin_amdgcn_mfma_f32_16x16x32_bf16(a0, bf, acc[0][j], 0, 0, 0);
                    acc[1][j] = __builtin_amdgcn_mfma_f32_16x16x32_bf16(a1, bf, acc[1][j], 0, 0, 0);
                }
            }
        }

        // in-register gate pointwise; h stored write-through at AGENT scope (L3)
#pragma unroll
        for (int i = 0; i < 2; ++i)
#pragma unroll
            for (int r = 0; r < 4; ++r) {
                int ir = i * 4 + r;
                float gi = acc[i][0][r] + xg[i][0][r];
                float gf = acc[i][1][r] + xg[i][1][r];
                float gg = acc[i][2][r] + xg[i][2][r];
                float go = acc[i][3][r] + xg[i][3][r];
                float cn = fsigm(gf) * c[ir] + fsigm(gi) * ftanh(gg);
                float hn = fsigm(go) * ftanh(cn);
                bool upd = t < lenr[ir];
                c[ir] = upd ? cn : c[ir];
                h[ir] = upd ? hn : h[ir];
                __hip_atomic_store(Hbf + ((long)brow[ir] * Tz + t) * DHz + d, f2bf(h[ir]),
                                   __ATOMIC_RELAXED, __HIP_MEMORY_SCOPE_AGENT);
            }

        if (t + 1 < t1) {
            // issue next-step xW loads (asm: younger than the h stores in the vmcnt
            // FIFO, so the counted wait below drains stores but not these)
            const unsigned short* pp = xW + ((long)(t + 1) * 96 + blockIdx.x) * 8192 + (long)tid * 8;
            asm volatile(
                "global_load_dwordx4 %0, %4, off\n\t"
                "global_load_dwordx4 %1, %5, off\n\t"
                "global_load_dwordx4 %2, %6, off\n\t"
                "global_load_dwordx4 %3, %7, off"
                : "=&v"(pf0), "=&v"(pf1), "=&v"(pf2), "=&v"(pf3)
                : "v"(pp), "v"(pp + 2048), "v"(pp + 4096), "v"(pp + 6144)
                : "memory");
            // counted wait: 8 h stores (older) acked at L3; 4 pf loads stay in flight
            asm volatile("s_waitcnt vmcnt(4)" ::: "memory");
            if (lane == 0)
                __hip_atomic_store(flg + dblk * 32, (unsigned)(t + 1),
                                   __ATOMIC_RELAXED, __HIP_MEMORY_SCOPE_AGENT);
        }
    }
#pragma unroll
    for (int ir = 0; ir < 8; ++ir) cbuf[(long)brow[ir] * DHz + d] = c[ir];
}

// ---------- scores[b,t] = sum_d w[d]*tanh( (H@Wh)[b,t,d] ) ----------
__global__ __launch_bounds__(256) void k_scores(const unsigned short* __restrict__ Hbf,
                                                const unsigned short* __restrict__ Whb,
                                                const float* __restrict__ wv,
                                                float* __restrict__ scores) {
    __shared__ unsigned short sA[128 * 40];
    __shared__ unsigned short sB[128 * 40];
    __shared__ float sred[128];
    int tid = threadIdx.x;
    int n0 = blockIdx.x * 128;
    int m0 = blockIdx.y * 128;
    int wid = tid >> 6, lane = tid & 63, l15 = lane & 15, q = lane >> 4;
    int wm = wid >> 1, wn = wid & 1;

    f32x4 acc[4][4];
    f32x4 zz = {0.f, 0.f, 0.f, 0.f};
#pragma unroll
    for (int i = 0; i < 4; ++i)
#pragma unroll
        for (int j = 0; j < 4; ++j) acc[i][j] = zz;

    int arow = tid >> 1;
    int kp = (tid & 1) * 16;
    const unsigned short* asrc = Hbf + (long)(m0 + arow) * DHz;

    for (int k0 = 0; k0 < DHz; k0 += 32) {
        *(int4*)(sA + arow * 40 + kp) = *(const int4*)(asrc + k0 + kp);
        *(int4*)(sA + arow * 40 + kp + 8) = *(const int4*)(asrc + k0 + kp + 8);
#pragma unroll
        for (int it = 0; it < 2; ++it) {
            int s = tid + it * 256;
            int k = s >> 4;
            int n = (s & 15) * 8;
            int4 v = *(const int4*)(Whb + (long)(k0 + k) * DHz + n0 + n);
            const unsigned short* pv = (const unsigned short*)&v;
#pragma unroll
            for (int e = 0; e < 8; ++e) sB[sboff(n + e, k)] = pv[e];
        }
        __syncthreads();
        short8 af[4], bfr[4];
#pragma unroll
        for (int i = 0; i < 4; ++i)
            af[i] = *(const short8*)(sA + (wm * 64 + i * 16 + l15) * 40 + q * 8);
#pragma unroll
        for (int j = 0; j < 4; ++j) {
            int n = wn * 64 + j * 16 + l15;
            bfr[j] = *(const short8*)(sB + n * 40 + ((q ^ ((n >> 3) & 3)) << 3));
        }
#pragma unroll
        for (int i = 0; i < 4; ++i)
#pragma unroll
            for (int j = 0; j < 4; ++j)
                acc[i][j] = __builtin_amdgcn_mfma_f32_16x16x32_bf16(af[i], bfr[j], acc[i][j], 0, 0, 0);
        __syncthreads();
    }
    if (tid < 128) sred[tid] = 0.f;
    __syncthreads();
#pragma unroll
    for (int i = 0; i < 4; ++i)
#pragma unroll
        for (int r = 0; r < 4; ++r) {
            float sv = 0.f;
#pragma unroll
            for (int j = 0; j < 4; ++j) {
                int n = n0 + wn * 64 + j * 16 + l15;
                sv += ftanh(acc[i][j][r]) * wv[n];
            }
#pragma unroll
            for (int o = 1; o < 16; o <<= 1) sv += __shfl_xor(sv, o, 64);
            if (l15 == 0) atomicAdd(&sred[wm * 64 + i * 16 + q * 4 + r], sv);
        }
    __syncthreads();
    if (tid < 128) atomicAdd(&scores[m0 + tid], sred[tid]);
}

// ---------- masked softmax over T ----------
__global__ void k_softmax(const float* __restrict__ scores, const int* __restrict__ lens,
                          float* __restrict__ alpha) {
    int b = blockIdx.x, t = threadIdx.x;
    int len = lens[b];
    float s = (t < len) ? scores[b * Tz + t] : -1e9f;
    float m = s;
#pragma unroll
    for (int o = 32; o; o >>= 1) m = fmaxf(m, __shfl_xor(m, o, 64));
    __shared__ float rA[2], rB[2];
    if ((t & 63) == 0) rA[t >> 6] = m;
    __syncthreads();
    m = fmaxf(rA[0], rA[1]);
    float e = expf(s - m);
    float sum = e;
#pragma unroll
    for (int o = 32; o; o >>= 1) sum += __shfl_xor(sum, o, 64);
    if ((t & 63) == 0) rB[t >> 6] = sum;
    __syncthreads();
    sum = rB[0] + rB[1];
    alpha[b * Tz + t] = e / sum;
}

// ---------- r[b,d] = sum_t alpha[b,t] * H[b,t,d]  (coalesced int4 rows) ----------
__global__ __launch_bounds__(128) void k_r(const float* __restrict__ alpha,
                                           const unsigned short* __restrict__ Hbf,
                                           float* __restrict__ rbuf) {
    int b = blockIdx.x;
    int tid = threadIdx.x;
    __shared__ float sal[Tz];
    if (tid < Tz) sal[tid] = alpha[b * Tz + tid];
    __syncthreads();
    if (tid < 96) {
        const unsigned short* hp = Hbf + (long)b * Tz * DHz + tid * 8;
        float acc[8] = {};
        for (int t = 0; t < Tz; ++t) {
            short8 v = *(const short8*)(hp + (long)t * DHz);
            float a = sal[t];
            const unsigned short* pv = (const unsigned short*)&v;
#pragma unroll
            for (int e = 0; e < 8; ++e) acc[e] += a * bf2f(pv[e]);
        }
        float* rp = rbuf + (long)b * DHz + tid * 8;
#pragma unroll
        for (int e = 0; e < 8; ++e) rp[e] = acc[e];
    }
}

// ---------- h_star = tanh(r@Wp + H[:, -1, :]@Wx) ----------
__global__ void k_hstar(const float* __restrict__ rbuf, const unsigned short* __restrict__ Hbf,
                        const float* __restrict__ Wp, const float* __restrict__ Wx,
                        float* __restrict__ hst) {
    __shared__ float sA[16][65];
    __shared__ float sB[16][65];
    int bn = blockIdx.x * 64, bm = blockIdx.y * 64;
    int tx = threadIdx.x & 15, ty = threadIdx.x >> 4;
    float acc[4][4] = {};
    for (int src = 0; src < 2; ++src) {
        const float* Bm = src ? Wx : Wp;
        for (int k0 = 0; k0 < DHz; k0 += 16) {
            for (int l = threadIdx.x; l < 64 * 16; l += 256) {
                int mm = l >> 4, kk = l & 15;
                sA[kk][mm] = src ? bf2f(Hbf[((long)(bm + mm) * Tz + (Tz - 1)) * DHz + k0 + kk])
                                 : rbuf[(long)(bm + mm) * DHz + k0 + kk];
            }
            for (int l = threadIdx.x; l < 16 * 64; l += 256) {
                int kk = l >> 6, nn = l & 63;
                sB[kk][nn] = Bm[(long)(k0 + kk) * DHz + bn + nn];
            }
            __syncthreads();
            for (int k = 0; k < 16; ++k) {
                float a0[4], b0[4];
#pragma unroll
                for (int i = 0; i < 4; ++i) a0[i] = sA[k][ty * 4 + i];
#pragma unroll
                for (int j = 0; j < 4; ++j) b0[j] = sB[k][tx * 4 + j];
#pragma unroll
                for (int i = 0; i < 4; ++i)
#pragma unroll
                    for (int j = 0; j < 4; ++j) acc[i][j] += a0[i] * b0[j];
            }
            __syncthreads();
        }
    }
#pragma unroll
    for (int i = 0; i < 4; ++i)
#pragma unroll
        for (int j = 0; j < 4; ++j)
            hst[(long)(bm + ty * 4 + i) * DHz + bn + tx * 4 + j] = ftanh(acc[i][j]);
}

// ---------- logits ----------
__global__ void k_logits(const float* __restrict__ hst, const float* __restrict__ Wl,
                         const float* __restrict__ bl, float* __restrict__ out) {
    int b = blockIdx.x;
    int lane = threadIdx.x & 63, c = threadIdx.x >> 6;
    float s = 0.f;
    for (int k = lane; k < DHz; k += 64) s += hst[(long)b * DHz + k] * Wl[k * 3 + c];
#pragma unroll
    for (int o = 32; o; o >>= 1) s += __shfl_xor(s, o, 64);
    if (lane == 0) out[b * 3 + c] = s + bl[c];
}

extern "C" void kernel_launch(void* const* d_in, const int* in_sizes, int n_in,
                              void* d_out, int out_size, void* d_ws, size_t ws_size,
                              hipStream_t stream) {
    (void)in_sizes; (void)n_in; (void)out_size;
    const int*   sent   = (const int*)d_in[0];
    const int*   target = (const int*)d_in[1];
    const int*   lens   = (const int*)d_in[2];
    const float* emb    = (const float*)d_in[3];
    const float* temb   = (const float*)d_in[4];
    const float* W_ih   = (const float*)d_in[5];
    const float* W_hh   = (const float*)d_in[6];
    const float* b_lstm = (const float*)d_in[7];
    const float* Wh     = (const float*)d_in[8];
    const float* wv     = (const float*)d_in[10];
    const float* Wp     = (const float*)d_in[11];
    const float* Wx     = (const float*)d_in[12];
    const float* W_lin  = (const float*)d_in[13];
    const float* b_lin  = (const float*)d_in[14];
    float* out = (float*)d_out;

    char* ws = (char*)d_ws;
    size_t off = 0;
    auto alloc = [&](size_t bytes) -> void* {
        void* p = ws + off;
        off = (off + bytes + 255) & ~(size_t)255;
        return p;
    };
    unsigned short* xW   = (unsigned short*)alloc((size_t)32768 * G4z * 2);
    unsigned short* Hbf  = (unsigned short*)alloc((size_t)Bz * Tz * DHz * 2);
    unsigned short* Wihb = (unsigned short*)alloc((size_t)DWz * G4z * 2);
    unsigned short* WhhP = (unsigned short*)alloc((size_t)48 * 6144 * 16);
    unsigned short* Whb  = (unsigned short*)alloc((size_t)DHz * DHz * 2);
    float* tx     = (float*)alloc((size_t)Bz * DWz * 4);
    float* constg = (float*)alloc((size_t)Bz * G4z * 4);
    float* cbuf   = (float*)alloc((size_t)Bz * DHz * 4);
    float* scores = (float*)alloc((size_t)Bz * Tz * 4);
    float* alpha  = (float*)alloc((size_t)Bz * Tz * 4);
    float* rbuf   = (float*)alloc((size_t)Bz * DHz * 4);
    float* hst    = (float*)alloc((size_t)Bz * DHz * 4);
    unsigned* bar = (unsigned*)alloc(65536);   // flags: 8 groups x 48 slots x 128B

    // bf16 emb (pre-converted once). VOCABz is the problem constant (round-5 bug:
    // deriving vocab from in_sizes[3] assumed bytes, but the harness passes element
    // counts -> embb covered only 1/4 of the vocab -> garbage A-tiles).
    size_t embb_bytes = (size_t)VOCABz * DWz * 2;
    unsigned short* embb = (unsigned short*)alloc(embb_bytes);
    int ebb = (off <= ws_size) ? 1 : 0;

    k_cvt4<<<1024, 256, 0, stream>>>(W_ih, Wihb, DWz * G4z / 4);
    k_cvt4<<<512, 256, 0, stream>>>(Wh, Whb, DHz * DHz / 4);
    if (ebb) k_cvt4<<<4096, 256, 0, stream>>>(emb, embb, VOCABz * DWz / 4);
    k_prep_whh<<<1152, 256, 0, stream>>>(W_hh, WhhP);
    k_prep_tx<<<Bz, 256, 0, stream>>>(target, temb, tx);
    hipMemsetAsync(scores, 0, (size_t)Bz * Tz * 4, stream);
    hipMemsetAsync(bar, 0, 65536, stream);

    k_gemm_f32_bias<<<dim3(48, 4), 256, 0, stream>>>(tx, W_ih + (size_t)DWz * G4z, b_lstm,
                                                     constg, Bz, G4z, DWz, DWz, G4z);
    k_gemm_x<<<dim3(24, 256), 256, 0, stream>>>(emb, embb, ebb, sent, Wihb, xW);

    hipFuncSetAttribute((const void*)k_lstm_all,
                        hipFuncAttributeMaxDynamicSharedMemorySize, 98304);
    int t0v = 0, t1v = Tz;
    const unsigned short* xWp = xW;
    const float* cgp = constg;
    const unsigned short* whp = WhhP;
    unsigned short* hbp = Hbf;
    float* cbp = cbuf;
    const int* lnp = lens;
    unsigned* barp = bar;
    void* kargs[] = {&t0v, &t1v, &xWp, &cgp, &whp, &hbp, &cbp, &lnp, &barp};
    hipError_t ce = hipLaunchCooperativeKernel(reinterpret_cast<void*>(k_lstm_all),
                                               dim3(NBLK), dim3(256), kargs, 98304, stream);
    if (ce != hipSuccess) {
        for (int t = 0; t < Tz; ++t)
            k_lstm_all<<<NBLK, 256, 98304, stream>>>(t, t + 1, xW, constg, WhhP, Hbf, cbuf, lens, bar);
    }

    k_scores<<<dim3(6, 256), 256, 0, stream>>>(Hbf, Whb, wv, scores);
    k_softmax<<<Bz, 128, 0, stream>>>(scores, lens, alpha);
    k_r<<<Bz, 128, 0, stream>>>(alpha, Hbf, rbuf);
    k_hstar<<<dim3(12, 4), 256, 0, stream>>>(rbuf, Hbf, Wp, Wx, hst);
    k_logits<<<Bz, 192, 0, stream>>>(hst, W_lin, b_lin, out);
}

// Round 7
// 2485.635 us; speedup vs baseline: 1.1415x; 1.0268x over previous
//
#include <hip/hip_runtime.h>
#include <stdint.h>

#define Bz 256
#define Tz 128
#define DWz 768
#define DHz 768
#define G4z 3072
#define NBLK 96
#define VOCABz 50000   // problem constant (reference: VOCAB = 50000)

typedef __attribute__((ext_vector_type(8))) short short8;
typedef __attribute__((ext_vector_type(4))) float f32x4;
typedef __attribute__((ext_vector_type(4))) int i32x4;

__device__ __forceinline__ unsigned short f2bf(float x) {
    union { float f; unsigned int u; } v; v.f = x;
    unsigned int u = v.u;
    return (unsigned short)((u + 0x7fffu + ((u >> 16) & 1u)) >> 16);
}
__device__ __forceinline__ float bf2f(unsigned short h) {
    union { unsigned int u; float f; } v; v.u = ((unsigned int)h) << 16;
    return v.f;
}
// fast transcendentals: v_exp_f32 + v_rcp_f32 (1-ulp class, fine vs bf16 floor)
__device__ __forceinline__ float fsigm(float x) {
    return __builtin_amdgcn_rcpf(1.0f + __builtin_amdgcn_exp2f(x * -1.4426950408889634f));
}
__device__ __forceinline__ float ftanh(float x) {
    x = fminf(fmaxf(x, -15.0f), 15.0f);           // keep e finite: no inf -> NaN
    float e = __builtin_amdgcn_exp2f(x * -2.8853900817779268f);
    return (1.0f - e) * __builtin_amdgcn_rcpf(1.0f + e);
}
__device__ __forceinline__ int sboff(int n, int k) {
    return n * 40 + ((((k >> 3) ^ ((n >> 3) & 3))) << 3) + (k & 7);
}

// ---------- fp32 -> bf16 bulk convert ----------
__global__ void k_cvt4(const float* __restrict__ src, unsigned short* __restrict__ dst, int n4) {
    int i = blockIdx.x * blockDim.x + threadIdx.x;
    int st = gridDim.x * blockDim.x;
    for (; i < n4; i += st) {
        float4 v = ((const float4*)src)[i];
        ushort4 o;
        o.x = f2bf(v.x); o.y = f2bf(v.y); o.z = f2bf(v.z); o.w = f2bf(v.w);
        ((ushort4*)dst)[i] = o;
    }
}

// ---------- gather aspect embedding ----------
__global__ void k_prep_tx(const int* __restrict__ target, const float* __restrict__ temb,
                          float* __restrict__ tx) {
    int b = blockIdx.x;
    long row = (long)target[b] * DWz;
    for (int d = threadIdx.x; d < DWz; d += blockDim.x)
        tx[b * DWz + d] = temb[row + d];
}

// ---------- generic B pre-swizzle: W (KxN fp32, N = NT*128) -> 16B chunks in the
// exact sboff LDS layout the MFMA GEMMs read. Chunk (n,kq) of tile (kt,nt) holds
// bf16 W[kt*32 + kq*8 + e][nt*128 + n], e=0..7, stored at out[(kt*NT+nt)*512 + s]
// with s = n*4 + kq. Consumers then stage B as 2x{int4 load + int4 ds_write}
// instead of 2x{int4 load + 16 scalar swizzle stores}.
__global__ __launch_bounds__(256) void k_prep_wswz(const float* __restrict__ W,
                                                   unsigned short* __restrict__ out, int NT) {
    __shared__ float sT[32][132];
    int bid = blockIdx.x;
    int kt = bid / NT, nt = bid - kt * NT;
    int tid = threadIdx.x;
    int ldn = NT * 128;
    {   // coalesced 32x128 fp32 tile load
        int r = tid >> 3;            // 0..31
        int cb = (tid & 7) * 16;     // 0..112
        const float* src = W + (long)(kt * 32 + r) * ldn + nt * 128 + cb;
#pragma unroll
        for (int u = 0; u < 4; ++u) {
            float4 v = ((const float4*)src)[u];
            sT[r][cb + u * 4 + 0] = v.x; sT[r][cb + u * 4 + 1] = v.y;
            sT[r][cb + u * 4 + 2] = v.z; sT[r][cb + u * 4 + 3] = v.w;
        }
    }
    __syncthreads();
#pragma unroll
    for (int it = 0; it < 2; ++it) {
        int s = tid + it * 256;
        int n = s >> 2, kq = s & 3;
        alignas(16) unsigned short o[8];
#pragma unroll
        for (int e = 0; e < 8; ++e) o[e] = f2bf(sT[kq * 8 + e][n]);
        *(int4*)(out + ((long)bid * 512 + s) * 8) = *(const int4*)o;
    }
}

// ---------- Whh -> pre-swizzled bf16 blobs (coalesced reads via LDS transpose) ----
__global__ __launch_bounds__(256) void k_prep_whh(const float* __restrict__ Whh,
                                                  unsigned short* __restrict__ WhhP) {
    __shared__ float sT[32][65];
    int bid = blockIdx.x;            // [0, 1152)
    int dblk = bid / 24;
    int k0c = bid - dblk * 24;
    int tid = threadIdx.x;

    {   // load 32 rows x 64 cols (4 gate groups of 16), coalesced
        int kk = tid >> 3;           // 0..31
        int seg = tid & 7;           // 0..7
        const float* src = Whh + (long)(k0c * 32 + kk) * G4z
                         + (seg >> 1) * 768 + dblk * 16 + (seg & 1) * 8;
        float4 v0 = *(const float4*)src;
        float4 v1 = *(const float4*)(src + 4);
        int cl = seg * 8;
        sT[kk][cl + 0] = v0.x; sT[kk][cl + 1] = v0.y; sT[kk][cl + 2] = v0.z; sT[kk][cl + 3] = v0.w;
        sT[kk][cl + 4] = v1.x; sT[kk][cl + 5] = v1.y; sT[kk][cl + 6] = v1.z; sT[kk][cl + 7] = v1.w;
    }
    __syncthreads();
    {   // emit in consumer order
        int nl = tid >> 2, cc = tid & 3;
        int q8 = cc ^ ((nl >> 1) & 3);
        int clv = (nl >> 4) * 16 + (nl & 15);
        alignas(16) unsigned short o[8];
#pragma unroll
        for (int e = 0; e < 8; ++e) o[e] = f2bf(sT[q8 * 8 + e][clv]);
        *(int4*)(WhhP + (long)(dblk * 6144 + k0c * 256 + tid) * 8) = *(const int4*)o;
    }
}

// ---------- generic fp32 tiled GEMM with bias (for const_gates) ----------
__global__ void k_gemm_f32_bias(const float* __restrict__ A, const float* __restrict__ Bm,
                                const float* __restrict__ bias, float* __restrict__ C,
                                int M, int N, int K, int lda, int ldb) {
    __shared__ float sA[16][65];
    __shared__ float sB[16][65];
    int bn = blockIdx.x * 64, bm = blockIdx.y * 64;
    int tx = threadIdx.x & 15, ty = threadIdx.x >> 4;
    float acc[4][4] = {};
    for (int k0 = 0; k0 < K; k0 += 16) {
        for (int l = threadIdx.x; l < 64 * 16; l += 256) {
            int m = l >> 4, k = l & 15;
            sA[k][m] = A[(long)(bm + m) * lda + k0 + k];
        }
        for (int l = threadIdx.x; l < 16 * 64; l += 256) {
            int k = l >> 6, n = l & 63;
            sB[k][n] = Bm[(long)(k0 + k) * ldb + bn + n];
        }
        __syncthreads();
        for (int k = 0; k < 16; ++k) {
            float a0[4], b0[4];
#pragma unroll
            for (int i = 0; i < 4; ++i) a0[i] = sA[k][ty * 4 + i];
#pragma unroll
            for (int j = 0; j < 4; ++j) b0[j] = sB[k][tx * 4 + j];
#pragma unroll
            for (int i = 0; i < 4; ++i)
#pragma unroll
                for (int j = 0; j < 4; ++j) acc[i][j] += a0[i] * b0[j];
        }
        __syncthreads();
    }
#pragma unroll
    for (int i = 0; i < 4; ++i)
#pragma unroll
        for (int j = 0; j < 4; ++j) {
            int m = bm + ty * 4 + i, n = bn + tx * 4 + j;
            C[(long)m * N + n] = acc[i][j] + bias[n];
        }
}

// ---------- xW = emb[sent] @ W_ih[:768]  (bf16 MFMA, pre-swizzled B) ----------
// Output written in the LSTM-blocked layout:
//   offset(ushort) = ((t*96 + blk)*4 + gate)*2048 + tid*8 + e
__global__ __launch_bounds__(256) void k_gemm_x(const float* __restrict__ emb,
                                                const unsigned short* __restrict__ embb,
                                                int ebb,
                                                const int* __restrict__ sent,
                                                const unsigned short* __restrict__ WbP,
                                                unsigned short* __restrict__ xW) {
    __shared__ unsigned short sA[128 * 40];
    __shared__ unsigned short sB[128 * 40];
    int tid = threadIdx.x;
    int n0 = blockIdx.x * 128;
    int m0 = blockIdx.y * 128;
    int wid = tid >> 6, lane = tid & 63, l15 = lane & 15, q = lane >> 4;
    int wm = wid >> 1, wn = wid & 1;

    int arow = tid >> 1;
    int kp = (tid & 1) * 16;
    int m = m0 + arow;
    int tt = m >> 8;
    int bb = m & 255;
    long gbase = (long)sent[bb * Tz + tt] * DWz;

    // this thread's two B chunks: LDS dest fixed across k-tiles
    int s0 = tid, s1 = tid + 256;
    int bd0 = (s0 >> 2) * 40 + (((s0 & 3) ^ (((s0 >> 2) >> 3) & 3)) << 3);
    int bd1 = (s1 >> 2) * 40 + (((s1 & 3) ^ (((s1 >> 2) >> 3) & 3)) << 3);

    f32x4 acc[4][4];
    f32x4 zz = {0.f, 0.f, 0.f, 0.f};
#pragma unroll
    for (int i = 0; i < 4; ++i)
#pragma unroll
        for (int j = 0; j < 4; ++j) acc[i][j] = zz;

    for (int k0 = 0; k0 < DWz; k0 += 32) {
        if (ebb) {
            const unsigned short* src = embb + gbase + k0 + kp;
            *(int4*)(sA + arow * 40 + kp) = *(const int4*)src;
            *(int4*)(sA + arow * 40 + kp + 8) = *(const int4*)(src + 8);
        } else {
            const float* src = emb + gbase + k0 + kp;
            alignas(16) unsigned short tmp[16];
#pragma unroll
            for (int it = 0; it < 4; ++it) {
                float4 v = ((const float4*)src)[it];
                tmp[it * 4 + 0] = f2bf(v.x); tmp[it * 4 + 1] = f2bf(v.y);
                tmp[it * 4 + 2] = f2bf(v.z); tmp[it * 4 + 3] = f2bf(v.w);
            }
            *(int4*)(sA + arow * 40 + kp) = *(const int4*)tmp;
            *(int4*)(sA + arow * 40 + kp + 8) = *(const int4*)(tmp + 8);
        }
        {   // B stage: pre-swizzled chunks, 2x (int4 load + int4 ds_write)
            const int4* wsrc = (const int4*)WbP
                + ((long)((k0 >> 5) * 24 + (n0 >> 7))) * 512 + tid;
            int4 v0 = wsrc[0];
            int4 v1 = wsrc[256];
            *(int4*)(sB + bd0) = v0;
            *(int4*)(sB + bd1) = v1;
        }
        __syncthreads();
        short8 af[4], bfr[4];
#pragma unroll
        for (int i = 0; i < 4; ++i)
            af[i] = *(const short8*)(sA + (wm * 64 + i * 16 + l15) * 40 + q * 8);
#pragma unroll
        for (int j = 0; j < 4; ++j) {
            int n = wn * 64 + j * 16 + l15;
            bfr[j] = *(const short8*)(sB + n * 40 + ((q ^ ((n >> 3) & 3)) << 3));
        }
#pragma unroll
        for (int i = 0; i < 4; ++i)
#pragma unroll
            for (int j = 0; j < 4; ++j)
                acc[i][j] = __builtin_amdgcn_mfma_f32_16x16x32_bf16(af[i], bfr[j], acc[i][j], 0, 0, 0);
        __syncthreads();
    }
    // blocked-layout epilogue: 8 dense dwordx4 stores per thread
#pragma unroll
    for (int j = 0; j < 4; ++j) {
        int n = n0 + wn * 64 + j * 16 + l15;         // column (gate*768 + d)
        int g = n / 768;
        int dblk = (n - g * 768) >> 4;
#pragma unroll
        for (int ip = 0; ip < 2; ++ip) {
            int row = m0 + wm * 64 + ip * 32;        // covers i4 = ip*2, ip*2+1
            int t = row >> 8;
            int bq = (row & 255) + q * 4;
            int blk = dblk * 2 + (bq >> 7);
            int tidd = ((bq & 127) >> 5) * 64 + q * 16 + l15;
            alignas(16) unsigned short o[8];
#pragma unroll
            for (int r = 0; r < 4; ++r) {
                o[r]     = f2bf(acc[ip * 2][j][r]);      // e = 0*4+r
                o[4 + r] = f2bf(acc[ip * 2 + 1][j][r]);  // e = 1*4+r
            }
            *(int4*)(xW + (((long)t * 96 + blk) * 4 + g) * 2048 + (long)tidd * 8) = *(const int4*)o;
        }
    }
}

// ---------- persistent LSTM, barrier-free wave-level dataflow, AGENT scope ----------
// Round-3 scheme (measured best): flags[bm][wid][dblk] on 128B-spaced single-writer
// lines, written once per step per producer wave after a counted vmcnt(4) drain;
// consumers 48-lane-gather-poll their flag group. (Round-4's single atomic counter
// regressed; two-level s_barrier scheme also slower. Do not churn this further.)
#define UNPACK(PF, G)                                                        \
    {                                                                        \
        const unsigned short* ch_ = (const unsigned short*)&(PF);            \
        _Pragma("unroll")                                                    \
        for (int i_ = 0; i_ < 2; ++i_)                                       \
            _Pragma("unroll")                                                \
            for (int r_ = 0; r_ < 4; ++r_)                                   \
                xg[i_][G][r_] = bf2f(ch_[i_ * 4 + r_]) + xgc[i_][G][r_];     \
    }

__global__ __launch_bounds__(256, 1) void k_lstm_all(int t0, int t1,
        const unsigned short* __restrict__ xW, const float* __restrict__ constg,
        const unsigned short* __restrict__ WhhP, unsigned short* __restrict__ Hbf,
        float* __restrict__ cbuf, const int* __restrict__ lens,
        unsigned* __restrict__ bar) {
    extern __shared__ unsigned short sB[];   // 96 KB
    int tid = threadIdx.x;
    int bm = blockIdx.x & 1;
    int dblk = blockIdx.x >> 1;
    int d0 = dblk * 16;
    int lane = tid & 63, wid = tid >> 6;
    int l15 = lane & 15, q = lane >> 4;
    int d = d0 + l15;
    // flags[bm][wid][dblk] at 128B spacing: group base + dblk*32 u32
    unsigned* flg = bar + ((bm * 4 + wid) * 48) * 32;

    {   // stage pre-swizzled B once
        const int4* src = (const int4*)WhhP + (long)dblk * 6144;
        for (int s = tid; s < 6144; s += 256) ((int4*)sB)[s] = src[s];
    }

    int brow[8];
    int lenr[8];
    float c[8], h[8];
    float xgc[2][4][4];   // step-invariant gate constants, register-resident
#pragma unroll
    for (int i = 0; i < 2; ++i)
#pragma unroll
        for (int r = 0; r < 4; ++r) {
            int ir = i * 4 + r;
            int b = bm * 128 + wid * 32 + i * 16 + q * 4 + r;
            brow[ir] = b;
            lenr[ir] = lens[b];
            long cbase = (long)b * G4z + d;
#pragma unroll
            for (int j = 0; j < 4; ++j) xgc[i][j][r] = constg[cbase + j * 768];
            if (t0 > 0) {
                c[ir] = cbuf[(long)b * DHz + d];
                h[ir] = bf2f(Hbf[((long)b * Tz + (t0 - 1)) * DHz + d]);
            } else { c[ir] = 0.f; h[ir] = 0.f; }
        }

    int bbase[4];
#pragma unroll
    for (int j = 0; j < 4; ++j) {
        int nl = j * 16 + l15;
        bbase[j] = nl * 32 + ((q ^ ((nl >> 1) & 3)) << 3);
    }
    __syncthreads();

    // gate x-contributions for step t0 (blocked layout: 4 coalesced dwordx4)
    float xg[2][4][4];
    {
        const unsigned short* x0 = xW + ((long)t0 * 96 + blockIdx.x) * 8192 + (long)tid * 8;
        int4 c0 = *(const int4*)(x0);
        int4 c1 = *(const int4*)(x0 + 2048);
        int4 c2 = *(const int4*)(x0 + 4096);
        int4 c3 = *(const int4*)(x0 + 6144);
        UNPACK(c0, 0) UNPACK(c1, 1) UNPACK(c2, 2) UNPACK(c3, 3)
    }

    i32x4 pf0, pf1, pf2, pf3;   // loop-carried xW prefetch

    for (int t = t0; t < t1; ++t) {
        if (t > t0) {
            // wave-local wait: all 48 producer waves (this wid) done with step t-1
            unsigned tgt = (unsigned)t;
            const unsigned* fp = flg + lane * 32;
            while (true) {
                unsigned v = (lane < 48)
                    ? __hip_atomic_load(fp, __ATOMIC_RELAXED, __HIP_MEMORY_SCOPE_AGENT)
                    : tgt;
                if (__all(v >= tgt)) break;
                __builtin_amdgcn_s_sleep(1);
            }
            asm volatile("s_waitcnt vmcnt(0)" ::: "memory");
            __builtin_amdgcn_sched_barrier(0);
            UNPACK(pf0, 0) UNPACK(pf1, 1) UNPACK(pf2, 2) UNPACK(pf3, 3)
        }

        f32x4 acc[2][4];
        f32x4 zz = {0.f, 0.f, 0.f, 0.f};
#pragma unroll
        for (int i = 0; i < 2; ++i)
#pragma unroll
            for (int j = 0; j < 4; ++j) acc[i][j] = zz;

        if (t > 0) {
            const unsigned short* ap0 = Hbf + ((long)(bm * 128 + wid * 32 + l15) * Tz + (t - 1)) * DHz + q * 8;
            const unsigned short* ap1 = ap0 + (long)16 * Tz * DHz;
#pragma unroll 6
            for (int k0c = 0; k0c < 24; ++k0c) {
                short8 a0 = *(const short8*)(ap0 + k0c * 32);
                short8 a1 = *(const short8*)(ap1 + k0c * 32);
                const unsigned short* bb = sB + k0c * 2048;
#pragma unroll
                for (int j = 0; j < 4; ++j) {
                    short8 bf = *(const short8*)(bb + bbase[j]);
                    acc[0][j] = __builtin_amdgcn_mfma_f32_16x16x32_bf16(a0, bf, acc[0][j], 0, 0, 0);
                    acc[1][j] = __builtin_amdgcn_mfma_f32_16x16x32_bf16(a1, bf, acc[1][j], 0, 0, 0);
                }
            }
        }

        // in-register gate pointwise; h stored write-through at AGENT scope (L3)
#pragma unroll
        for (int i = 0; i < 2; ++i)
#pragma unroll
            for (int r = 0; r < 4; ++r) {
                int ir = i * 4 + r;
                float gi = acc[i][0][r] + xg[i][0][r];
                float gf = acc[i][1][r] + xg[i][1][r];
                float gg = acc[i][2][r] + xg[i][2][r];
                float go = acc[i][3][r] + xg[i][3][r];
                float cn = fsigm(gf) * c[ir] + fsigm(gi) * ftanh(gg);
                float hn = fsigm(go) * ftanh(cn);
                bool upd = t < lenr[ir];
                c[ir] = upd ? cn : c[ir];
                h[ir] = upd ? hn : h[ir];
                __hip_atomic_store(Hbf + ((long)brow[ir] * Tz + t) * DHz + d, f2bf(h[ir]),
                                   __ATOMIC_RELAXED, __HIP_MEMORY_SCOPE_AGENT);
            }

        if (t + 1 < t1) {
            // issue next-step xW loads (asm: younger than the h stores in the vmcnt
            // FIFO, so the counted wait below drains stores but not these)
            const unsigned short* pp = xW + ((long)(t + 1) * 96 + blockIdx.x) * 8192 + (long)tid * 8;
            asm volatile(
                "global_load_dwordx4 %0, %4, off\n\t"
                "global_load_dwordx4 %1, %5, off\n\t"
                "global_load_dwordx4 %2, %6, off\n\t"
                "global_load_dwordx4 %3, %7, off"
                : "=&v"(pf0), "=&v"(pf1), "=&v"(pf2), "=&v"(pf3)
                : "v"(pp), "v"(pp + 2048), "v"(pp + 4096), "v"(pp + 6144)
                : "memory");
            // counted wait: 8 h stores (older) acked at L3; 4 pf loads stay in flight
            asm volatile("s_waitcnt vmcnt(4)" ::: "memory");
            if (lane == 0)
                __hip_atomic_store(flg + dblk * 32, (unsigned)(t + 1),
                                   __ATOMIC_RELAXED, __HIP_MEMORY_SCOPE_AGENT);
        }
    }
#pragma unroll
    for (int ir = 0; ir < 8; ++ir) cbuf[(long)brow[ir] * DHz + d] = c[ir];
}

// ---------- scores[b,t] = sum_d w[d]*tanh( (H@Wh)[b,t,d] )  (pre-swizzled B) ----
__global__ __launch_bounds__(256) void k_scores(const unsigned short* __restrict__ Hbf,
                                                const unsigned short* __restrict__ WbP,
                                                const float* __restrict__ wv,
                                                float* __restrict__ scores) {
    __shared__ unsigned short sA[128 * 40];
    __shared__ unsigned short sB[128 * 40];
    __shared__ float sred[128];
    int tid = threadIdx.x;
    int n0 = blockIdx.x * 128;
    int m0 = blockIdx.y * 128;
    int wid = tid >> 6, lane = tid & 63, l15 = lane & 15, q = lane >> 4;
    int wm = wid >> 1, wn = wid & 1;

    int s0 = tid, s1 = tid + 256;
    int bd0 = (s0 >> 2) * 40 + (((s0 & 3) ^ (((s0 >> 2) >> 3) & 3)) << 3);
    int bd1 = (s1 >> 2) * 40 + (((s1 & 3) ^ (((s1 >> 2) >> 3) & 3)) << 3);

    f32x4 acc[4][4];
    f32x4 zz = {0.f, 0.f, 0.f, 0.f};
#pragma unroll
    for (int i = 0; i < 4; ++i)
#pragma unroll
        for (int j = 0; j < 4; ++j) acc[i][j] = zz;

    int arow = tid >> 1;
    int kp = (tid & 1) * 16;
    const unsigned short* asrc = Hbf + (long)(m0 + arow) * DHz;

    for (int k0 = 0; k0 < DHz; k0 += 32) {
        *(int4*)(sA + arow * 40 + kp) = *(const int4*)(asrc + k0 + kp);
        *(int4*)(sA + arow * 40 + kp + 8) = *(const int4*)(asrc + k0 + kp + 8);
        {
            const int4* wsrc = (const int4*)WbP
                + ((long)((k0 >> 5) * 6 + (n0 >> 7))) * 512 + tid;
            int4 v0 = wsrc[0];
            int4 v1 = wsrc[256];
            *(int4*)(sB + bd0) = v0;
            *(int4*)(sB + bd1) = v1;
        }
        __syncthreads();
        short8 af[4], bfr[4];
#pragma unroll
        for (int i = 0; i < 4; ++i)
            af[i] = *(const short8*)(sA + (wm * 64 + i * 16 + l15) * 40 + q * 8);
#pragma unroll
        for (int j = 0; j < 4; ++j) {
            int n = wn * 64 + j * 16 + l15;
            bfr[j] = *(const short8*)(sB + n * 40 + ((q ^ ((n >> 3) & 3)) << 3));
        }
#pragma unroll
        for (int i = 0; i < 4; ++i)
#pragma unroll
            for (int j = 0; j < 4; ++j)
                acc[i][j] = __builtin_amdgcn_mfma_f32_16x16x32_bf16(af[i], bfr[j], acc[i][j], 0, 0, 0);
        __syncthreads();
    }
    if (tid < 128) sred[tid] = 0.f;
    __syncthreads();
#pragma unroll
    for (int i = 0; i < 4; ++i)
#pragma unroll
        for (int r = 0; r < 4; ++r) {
            float sv = 0.f;
#pragma unroll
            for (int j = 0; j < 4; ++j) {
                int n = n0 + wn * 64 + j * 16 + l15;
                sv += ftanh(acc[i][j][r]) * wv[n];
            }
#pragma unroll
            for (int o = 1; o < 16; o <<= 1) sv += __shfl_xor(sv, o, 64);
            if (l15 == 0) atomicAdd(&sred[wm * 64 + i * 16 + q * 4 + r], sv);
        }
    __syncthreads();
    if (tid < 128) atomicAdd(&scores[m0 + tid], sred[tid]);
}

// ---------- masked softmax over T ----------
__global__ void k_softmax(const float* __restrict__ scores, const int* __restrict__ lens,
                          float* __restrict__ alpha) {
    int b = blockIdx.x, t = threadIdx.x;
    int len = lens[b];
    float s = (t < len) ? scores[b * Tz + t] : -1e9f;
    float m = s;
#pragma unroll
    for (int o = 32; o; o >>= 1) m = fmaxf(m, __shfl_xor(m, o, 64));
    __shared__ float rA[2], rB[2];
    if ((t & 63) == 0) rA[t >> 6] = m;
    __syncthreads();
    m = fmaxf(rA[0], rA[1]);
    float e = expf(s - m);
    float sum = e;
#pragma unroll
    for (int o = 32; o; o >>= 1) sum += __shfl_xor(sum, o, 64);
    if ((t & 63) == 0) rB[t >> 6] = sum;
    __syncthreads();
    sum = rB[0] + rB[1];
    alpha[b * Tz + t] = e / sum;
}

// ---------- r[b,d] = sum_t alpha[b,t] * H[b,t,d]  (coalesced int4 rows) ----------
__global__ __launch_bounds__(128) void k_r(const float* __restrict__ alpha,
                                           const unsigned short* __restrict__ Hbf,
                                           float* __restrict__ rbuf) {
    int b = blockIdx.x;
    int tid = threadIdx.x;
    __shared__ float sal[Tz];
    if (tid < Tz) sal[tid] = alpha[b * Tz + tid];
    __syncthreads();
    if (tid < 96) {
        const unsigned short* hp = Hbf + (long)b * Tz * DHz + tid * 8;
        float acc[8] = {};
        for (int t = 0; t < Tz; ++t) {
            short8 v = *(const short8*)(hp + (long)t * DHz);
            float a = sal[t];
            const unsigned short* pv = (const unsigned short*)&v;
#pragma unroll
            for (int e = 0; e < 8; ++e) acc[e] += a * bf2f(pv[e]);
        }
        float* rp = rbuf + (long)b * DHz + tid * 8;
#pragma unroll
        for (int e = 0; e < 8; ++e) rp[e] = acc[e];
    }
}

// ---------- h_star = tanh(r@Wp + H[:, -1, :]@Wx) ----------
__global__ void k_hstar(const float* __restrict__ rbuf, const unsigned short* __restrict__ Hbf,
                        const float* __restrict__ Wp, const float* __restrict__ Wx,
                        float* __restrict__ hst) {
    __shared__ float sA[16][65];
    __shared__ float sB[16][65];
    int bn = blockIdx.x * 64, bm = blockIdx.y * 64;
    int tx = threadIdx.x & 15, ty = threadIdx.x >> 4;
    float acc[4][4] = {};
    for (int src = 0; src < 2; ++src) {
        const float* Bm = src ? Wx : Wp;
        for (int k0 = 0; k0 < DHz; k0 += 16) {
            for (int l = threadIdx.x; l < 64 * 16; l += 256) {
                int mm = l >> 4, kk = l & 15;
                sA[kk][mm] = src ? bf2f(Hbf[((long)(bm + mm) * Tz + (Tz - 1)) * DHz + k0 + kk])
                                 : rbuf[(long)(bm + mm) * DHz + k0 + kk];
            }
            for (int l = threadIdx.x; l < 16 * 64; l += 256) {
                int kk = l >> 6, nn = l & 63;
                sB[kk][nn] = Bm[(long)(k0 + kk) * DHz + bn + nn];
            }
            __syncthreads();
            for (int k = 0; k < 16; ++k) {
                float a0[4], b0[4];
#pragma unroll
                for (int i = 0; i < 4; ++i) a0[i] = sA[k][ty * 4 + i];
#pragma unroll
                for (int j = 0; j < 4; ++j) b0[j] = sB[k][tx * 4 + j];
#pragma unroll
                for (int i = 0; i < 4; ++i)
#pragma unroll
                    for (int j = 0; j < 4; ++j) acc[i][j] += a0[i] * b0[j];
            }
            __syncthreads();
        }
    }
#pragma unroll
    for (int i = 0; i < 4; ++i)
#pragma unroll
        for (int j = 0; j < 4; ++j)
            hst[(long)(bm + ty * 4 + i) * DHz + bn + tx * 4 + j] = ftanh(acc[i][j]);
}

// ---------- logits ----------
__global__ void k_logits(const float* __restrict__ hst, const float* __restrict__ Wl,
                         const float* __restrict__ bl, float* __restrict__ out) {
    int b = blockIdx.x;
    int lane = threadIdx.x & 63, c = threadIdx.x >> 6;
    float s = 0.f;
    for (int k = lane; k < DHz; k += 64) s += hst[(long)b * DHz + k] * Wl[k * 3 + c];
#pragma unroll
    for (int o = 32; o; o >>= 1) s += __shfl_xor(s, o, 64);
    if (lane == 0) out[b * 3 + c] = s + bl[c];
}

extern "C" void kernel_launch(void* const* d_in, const int* in_sizes, int n_in,
                              void* d_out, int out_size, void* d_ws, size_t ws_size,
                              hipStream_t stream) {
    (void)in_sizes; (void)n_in; (void)out_size;
    const int*   sent   = (const int*)d_in[0];
    const int*   target = (const int*)d_in[1];
    const int*   lens   = (const int*)d_in[2];
    const float* emb    = (const float*)d_in[3];
    const float* temb   = (const float*)d_in[4];
    const float* W_ih   = (const float*)d_in[5];
    const float* W_hh   = (const float*)d_in[6];
    const float* b_lstm = (const float*)d_in[7];
    const float* Wh     = (const float*)d_in[8];
    const float* wv     = (const float*)d_in[10];
    const float* Wp     = (const float*)d_in[11];
    const float* Wx     = (const float*)d_in[12];
    const float* W_lin  = (const float*)d_in[13];
    const float* b_lin  = (const float*)d_in[14];
    float* out = (float*)d_out;

    char* ws = (char*)d_ws;
    size_t off = 0;
    auto alloc = [&](size_t bytes) -> void* {
        void* p = ws + off;
        off = (off + bytes + 255) & ~(size_t)255;
        return p;
    };
    unsigned short* xW    = (unsigned short*)alloc((size_t)32768 * G4z * 2);
    unsigned short* Hbf   = (unsigned short*)alloc((size_t)Bz * Tz * DHz * 2);
    unsigned short* WihbP = (unsigned short*)alloc((size_t)24 * 24 * 512 * 16);
    unsigned short* WhhP  = (unsigned short*)alloc((size_t)48 * 6144 * 16);
    unsigned short* WhbP  = (unsigned short*)alloc((size_t)24 * 6 * 512 * 16);
    float* tx     = (float*)alloc((size_t)Bz * DWz * 4);
    float* constg = (float*)alloc((size_t)Bz * G4z * 4);
    float* cbuf   = (float*)alloc((size_t)Bz * DHz * 4);
    float* scores = (float*)alloc((size_t)Bz * Tz * 4);
    float* alpha  = (float*)alloc((size_t)Bz * Tz * 4);
    float* rbuf   = (float*)alloc((size_t)Bz * DHz * 4);
    float* hst    = (float*)alloc((size_t)Bz * DHz * 4);
    unsigned* bar = (unsigned*)alloc(65536);   // flags: 8 groups x 48 slots x 128B

    // bf16 emb (pre-converted once); VOCABz is the problem constant
    size_t embb_bytes = (size_t)VOCABz * DWz * 2;
    unsigned short* embb = (unsigned short*)alloc(embb_bytes);
    int ebb = (off <= ws_size) ? 1 : 0;

    if (ebb) k_cvt4<<<4096, 256, 0, stream>>>(emb, embb, VOCABz * DWz / 4);
    k_prep_wswz<<<576, 256, 0, stream>>>(W_ih, WihbP, 24);   // W_ih[:768] @ N=3072
    k_prep_wswz<<<144, 256, 0, stream>>>(Wh, WhbP, 6);       // Wh @ N=768
    k_prep_whh<<<1152, 256, 0, stream>>>(W_hh, WhhP);
    k_prep_tx<<<Bz, 256, 0, stream>>>(target, temb, tx);
    hipMemsetAsync(scores, 0, (size_t)Bz * Tz * 4, stream);
    hipMemsetAsync(bar, 0, 65536, stream);

    k_gemm_f32_bias<<<dim3(48, 4), 256, 0, stream>>>(tx, W_ih + (size_t)DWz * G4z, b_lstm,
                                                     constg, Bz, G4z, DWz, DWz, G4z);
    k_gemm_x<<<dim3(24, 256), 256, 0, stream>>>(emb, embb, ebb, sent, WihbP, xW);

    hipFuncSetAttribute((const void*)k_lstm_all,
                        hipFuncAttributeMaxDynamicSharedMemorySize, 98304);
    int t0v = 0, t1v = Tz;
    const unsigned short* xWp = xW;
    const float* cgp = constg;
    const unsigned short* whp = WhhP;
    unsigned short* hbp = Hbf;
    float* cbp = cbuf;
    const int* lnp = lens;
    unsigned* barp = bar;
    void* kargs[] = {&t0v, &t1v, &xWp, &cgp, &whp, &hbp, &cbp, &lnp, &barp};
    hipError_t ce = hipLaunchCooperativeKernel(reinterpret_cast<void*>(k_lstm_all),
                                               dim3(NBLK), dim3(256), kargs, 98304, stream);
    if (ce != hipSuccess) {
        for (int t = 0; t < Tz; ++t)
            k_lstm_all<<<NBLK, 256, 98304, stream>>>(t, t + 1, xW, constg, WhhP, Hbf, cbuf, lens, bar);
    }

    k_scores<<<dim3(6, 256), 256, 0, stream>>>(Hbf, WhbP, wv, scores);
    k_softmax<<<Bz, 128, 0, stream>>>(scores, lens, alpha);
    k_r<<<Bz, 128, 0, stream>>>(alpha, Hbf, rbuf);
    k_hstar<<<dim3(12, 4), 256, 0, stream>>>(rbuf, Hbf, Wp, Wx, hst);
    k_logits<<<Bz, 192, 0, stream>>>(hst, W_lin, b_lin, out);
}

// Round 8
// 2320.101 us; speedup vs baseline: 1.2229x; 1.0713x over previous
//
#include <hip/hip_runtime.h>
#include <stdint.h>

#define Bz 256
#define Tz 128
#define DWz 768
#define DHz 768
#define G4z 3072
#define NBLK 96
#define NGRID 256
#define VOCABz 50000   // problem constant (reference: VOCAB = 50000)

typedef __attribute__((ext_vector_type(8))) short short8;
typedef __attribute__((ext_vector_type(4))) float f32x4;
typedef __attribute__((ext_vector_type(4))) int i32x4;

__device__ __forceinline__ unsigned short f2bf(float x) {
    union { float f; unsigned int u; } v; v.f = x;
    unsigned int u = v.u;
    return (unsigned short)((u + 0x7fffu + ((u >> 16) & 1u)) >> 16);
}
__device__ __forceinline__ float bf2f(unsigned short h) {
    union { unsigned int u; float f; } v; v.u = ((unsigned int)h) << 16;
    return v.f;
}
// fast transcendentals: v_exp_f32 + v_rcp_f32 (1-ulp class, fine vs bf16 floor)
__device__ __forceinline__ float fsigm(float x) {
    return __builtin_amdgcn_rcpf(1.0f + __builtin_amdgcn_exp2f(x * -1.4426950408889634f));
}
__device__ __forceinline__ float ftanh(float x) {
    x = fminf(fmaxf(x, -15.0f), 15.0f);           // keep e finite: no inf -> NaN
    float e = __builtin_amdgcn_exp2f(x * -2.8853900817779268f);
    return (1.0f - e) * __builtin_amdgcn_rcpf(1.0f + e);
}

// ---------- fp32 -> bf16 bulk convert ----------
__global__ void k_cvt4(const float* __restrict__ src, unsigned short* __restrict__ dst, int n4) {
    int i = blockIdx.x * blockDim.x + threadIdx.x;
    int st = gridDim.x * blockDim.x;
    for (; i < n4; i += st) {
        float4 v = ((const float4*)src)[i];
        ushort4 o;
        o.x = f2bf(v.x); o.y = f2bf(v.y); o.z = f2bf(v.z); o.w = f2bf(v.w);
        ((ushort4*)dst)[i] = o;
    }
}

// ---------- gather aspect embedding ----------
__global__ void k_prep_tx(const int* __restrict__ target, const float* __restrict__ temb,
                          float* __restrict__ tx) {
    int b = blockIdx.x;
    long row = (long)target[b] * DWz;
    for (int d = threadIdx.x; d < DWz; d += blockDim.x)
        tx[b * DWz + d] = temb[row + d];
}

// ---------- generic B pre-swizzle (sboff LDS layout chunks) ----------
__global__ __launch_bounds__(256) void k_prep_wswz(const float* __restrict__ W,
                                                   unsigned short* __restrict__ out, int NT) {
    __shared__ float sT[32][132];
    int bid = blockIdx.x;
    int kt = bid / NT, nt = bid - kt * NT;
    int tid = threadIdx.x;
    int ldn = NT * 128;
    {
        int r = tid >> 3;
        int cb = (tid & 7) * 16;
        const float* src = W + (long)(kt * 32 + r) * ldn + nt * 128 + cb;
#pragma unroll
        for (int u = 0; u < 4; ++u) {
            float4 v = ((const float4*)src)[u];
            sT[r][cb + u * 4 + 0] = v.x; sT[r][cb + u * 4 + 1] = v.y;
            sT[r][cb + u * 4 + 2] = v.z; sT[r][cb + u * 4 + 3] = v.w;
        }
    }
    __syncthreads();
#pragma unroll
    for (int it = 0; it < 2; ++it) {
        int s = tid + it * 256;
        int n = s >> 2, kq = s & 3;
        alignas(16) unsigned short o[8];
#pragma unroll
        for (int e = 0; e < 8; ++e) o[e] = f2bf(sT[kq * 8 + e][n]);
        *(int4*)(out + ((long)bid * 512 + s) * 8) = *(const int4*)o;
    }
}

// ---------- Whh -> pre-swizzled bf16 blobs (coalesced reads via LDS transpose) ----
__global__ __launch_bounds__(256) void k_prep_whh(const float* __restrict__ Whh,
                                                  unsigned short* __restrict__ WhhP) {
    __shared__ float sT[32][65];
    int bid = blockIdx.x;            // [0, 1152)
    int dblk = bid / 24;
    int k0c = bid - dblk * 24;
    int tid = threadIdx.x;
    {
        int kk = tid >> 3;
        int seg = tid & 7;
        const float* src = Whh + (long)(k0c * 32 + kk) * G4z
                         + (seg >> 1) * 768 + dblk * 16 + (seg & 1) * 8;
        float4 v0 = *(const float4*)src;
        float4 v1 = *(const float4*)(src + 4);
        int cl = seg * 8;
        sT[kk][cl + 0] = v0.x; sT[kk][cl + 1] = v0.y; sT[kk][cl + 2] = v0.z; sT[kk][cl + 3] = v0.w;
        sT[kk][cl + 4] = v1.x; sT[kk][cl + 5] = v1.y; sT[kk][cl + 6] = v1.z; sT[kk][cl + 7] = v1.w;
    }
    __syncthreads();
    {
        int nl = tid >> 2, cc = tid & 3;
        int q8 = cc ^ ((nl >> 1) & 3);
        int clv = (nl >> 4) * 16 + (nl & 15);
        alignas(16) unsigned short o[8];
#pragma unroll
        for (int e = 0; e < 8; ++e) o[e] = f2bf(sT[q8 * 8 + e][clv]);
        *(int4*)(WhhP + (long)(dblk * 6144 + k0c * 256 + tid) * 8) = *(const int4*)o;
    }
}

// ---------- generic fp32 tiled GEMM with bias (for const_gates) ----------
__global__ void k_gemm_f32_bias(const float* __restrict__ A, const float* __restrict__ Bm,
                                const float* __restrict__ bias, float* __restrict__ C,
                                int M, int N, int K, int lda, int ldb) {
    __shared__ float sA[16][65];
    __shared__ float sB[16][65];
    int bn = blockIdx.x * 64, bm = blockIdx.y * 64;
    int tx = threadIdx.x & 15, ty = threadIdx.x >> 4;
    float acc[4][4] = {};
    for (int k0 = 0; k0 < K; k0 += 16) {
        for (int l = threadIdx.x; l < 64 * 16; l += 256) {
            int m = l >> 4, k = l & 15;
            sA[k][m] = A[(long)(bm + m) * lda + k0 + k];
        }
        for (int l = threadIdx.x; l < 16 * 64; l += 256) {
            int k = l >> 6, n = l & 63;
            sB[k][n] = Bm[(long)(k0 + k) * ldb + bn + n];
        }
        __syncthreads();
        for (int k = 0; k < 16; ++k) {
            float a0[4], b0[4];
#pragma unroll
            for (int i = 0; i < 4; ++i) a0[i] = sA[k][ty * 4 + i];
#pragma unroll
            for (int j = 0; j < 4; ++j) b0[j] = sB[k][tx * 4 + j];
#pragma unroll
            for (int i = 0; i < 4; ++i)
#pragma unroll
                for (int j = 0; j < 4; ++j) acc[i][j] += a0[i] * b0[j];
        }
        __syncthreads();
    }
#pragma unroll
    for (int i = 0; i < 4; ++i)
#pragma unroll
        for (int j = 0; j < 4; ++j) {
            int m = bm + ty * 4 + i, n = bn + tx * 4 + j;
            C[(long)m * N + n] = acc[i][j] + bias[n];
        }
}

// ---------- standalone xW GEMM (fallback path only; kernel boundary = coherent) ----
__global__ __launch_bounds__(256) void k_gemm_x(const float* __restrict__ emb,
                                                const unsigned short* __restrict__ embb,
                                                int ebb,
                                                const int* __restrict__ sent,
                                                const unsigned short* __restrict__ WbP,
                                                unsigned short* __restrict__ xW) {
    __shared__ unsigned short sA[128 * 40];
    __shared__ unsigned short sB[128 * 40];
    int tid = threadIdx.x;
    int n0 = blockIdx.x * 128;
    int m0 = blockIdx.y * 128;
    int wid = tid >> 6, lane = tid & 63, l15 = lane & 15, q = lane >> 4;
    int wm = wid >> 1, wn = wid & 1;
    int arow = tid >> 1;
    int kp = (tid & 1) * 16;
    int m = m0 + arow;
    int tt = m >> 8;
    int bb = m & 255;
    long gbase = (long)sent[bb * Tz + tt] * DWz;
    int s0 = tid, s1 = tid + 256;
    int bd0 = (s0 >> 2) * 40 + (((s0 & 3) ^ (((s0 >> 2) >> 3) & 3)) << 3);
    int bd1 = (s1 >> 2) * 40 + (((s1 & 3) ^ (((s1 >> 2) >> 3) & 3)) << 3);

    f32x4 acc[4][4];
    f32x4 zz = {0.f, 0.f, 0.f, 0.f};
#pragma unroll
    for (int i = 0; i < 4; ++i)
#pragma unroll
        for (int j = 0; j < 4; ++j) acc[i][j] = zz;

    for (int k0 = 0; k0 < DWz; k0 += 32) {
        if (ebb) {
            const unsigned short* src = embb + gbase + k0 + kp;
            *(int4*)(sA + arow * 40 + kp) = *(const int4*)src;
            *(int4*)(sA + arow * 40 + kp + 8) = *(const int4*)(src + 8);
        } else {
            const float* src = emb + gbase + k0 + kp;
            alignas(16) unsigned short tmp[16];
#pragma unroll
            for (int it = 0; it < 4; ++it) {
                float4 v = ((const float4*)src)[it];
                tmp[it * 4 + 0] = f2bf(v.x); tmp[it * 4 + 1] = f2bf(v.y);
                tmp[it * 4 + 2] = f2bf(v.z); tmp[it * 4 + 3] = f2bf(v.w);
            }
            *(int4*)(sA + arow * 40 + kp) = *(const int4*)tmp;
            *(int4*)(sA + arow * 40 + kp + 8) = *(const int4*)(tmp + 8);
        }
        {
            const int4* wsrc = (const int4*)WbP
                + ((long)((k0 >> 5) * 24 + (n0 >> 7))) * 512 + tid;
            int4 v0 = wsrc[0];
            int4 v1 = wsrc[256];
            *(int4*)(sB + bd0) = v0;
            *(int4*)(sB + bd1) = v1;
        }
        __syncthreads();
        short8 af[4], bfr[4];
#pragma unroll
        for (int i = 0; i < 4; ++i)
            af[i] = *(const short8*)(sA + (wm * 64 + i * 16 + l15) * 40 + q * 8);
#pragma unroll
        for (int j = 0; j < 4; ++j) {
            int n = wn * 64 + j * 16 + l15;
            bfr[j] = *(const short8*)(sB + n * 40 + ((q ^ ((n >> 3) & 3)) << 3));
        }
#pragma unroll
        for (int i = 0; i < 4; ++i)
#pragma unroll
            for (int j = 0; j < 4; ++j)
                acc[i][j] = __builtin_amdgcn_mfma_f32_16x16x32_bf16(af[i], bfr[j], acc[i][j], 0, 0, 0);
        __syncthreads();
    }
#pragma unroll
    for (int j = 0; j < 4; ++j) {
        int n = n0 + wn * 64 + j * 16 + l15;
        int gt = n / 768;
        int dblk = (n - gt * 768) >> 4;
#pragma unroll
        for (int ip = 0; ip < 2; ++ip) {
            int row = m0 + wm * 64 + ip * 32;
            int t = row >> 8;
            int bq = (row & 255) + q * 4;
            int blk = dblk * 2 + (bq >> 7);
            int tidd = ((bq & 127) >> 5) * 64 + q * 16 + l15;
            alignas(16) unsigned short o[8];
#pragma unroll
            for (int r = 0; r < 4; ++r) {
                o[r]     = f2bf(acc[ip * 2][j][r]);
                o[4 + r] = f2bf(acc[ip * 2 + 1][j][r]);
            }
            *(int4*)(xW + (((long)t * 96 + blk) * 4 + gt) * 2048 + (long)tidd * 8) = *(const int4*)o;
        }
    }
}

// ---------- fused persistent kernel: LSTM (blocks 0..95) + xW producer (96..255) ----
// LSTM part: round-3 wave-dataflow scheme, UNCHANGED (measured local optimum).
// Producer part: 160 blocks loop over the 6144 gemm_x tiles in t-ascending order
// (tile g -> my=g/24, t=my>>1; 48 tiles per t). xW stores are agent-scope atomic
// u64 (write-through to L3 -- no kernel boundary to flush producer L2). After a
// tile's stores drain, one thread bumps xwcnt[t]. LSTM waves poll xwcnt[t+1]>=48
// before issuing the xW prefetch; producers run ~5x faster than consumption so
// the poll is instant-pass after a ~one-tile ramp. 160 previously-idle CUs now
// hide the entire xW GEMM under the LSTM's critical path.
#define UNPACK(PF, G)                                                        \
    {                                                                        \
        const unsigned short* ch_ = (const unsigned short*)&(PF);            \
        _Pragma("unroll")                                                    \
        for (int i_ = 0; i_ < 2; ++i_)                                       \
            _Pragma("unroll")                                                \
            for (int r_ = 0; r_ < 4; ++r_)                                   \
                xg[i_][G][r_] = bf2f(ch_[i_ * 4 + r_]) + xgc[i_][G][r_];     \
    }

__global__ __launch_bounds__(256, 1) void k_lstm_all(int t0, int t1,
        unsigned short* __restrict__ xW, const float* __restrict__ constg,
        const unsigned short* __restrict__ WhhP, unsigned short* __restrict__ Hbf,
        float* __restrict__ cbuf, const int* __restrict__ lens,
        unsigned* __restrict__ bar, unsigned* __restrict__ xwcnt, int waitxw,
        const float* __restrict__ emb, const unsigned short* __restrict__ embb,
        int ebb, const int* __restrict__ sent,
        const unsigned short* __restrict__ WihbP, int nprod) {
    extern __shared__ unsigned short sB[];   // 96 KB dynamic
    int bid = blockIdx.x;
    int tid = threadIdx.x;
    int lane = tid & 63, wid = tid >> 6;
    int l15 = lane & 15, q = lane >> 4;

    if (bid >= NBLK) {
        // ---------------- producer: xW tiles ----------------
        unsigned short* psA = sB;          // 128*40 ushorts
        unsigned short* psB = sB + 5120;   // 128*40 ushorts
        int wm = wid >> 1, wn = wid & 1;
        int arow = tid >> 1;
        int kp = (tid & 1) * 16;
        int s0 = tid, s1 = tid + 256;
        int bd0 = (s0 >> 2) * 40 + (((s0 & 3) ^ (((s0 >> 2) >> 3) & 3)) << 3);
        int bd1 = (s1 >> 2) * 40 + (((s1 & 3) ^ (((s1 >> 2) >> 3) & 3)) << 3);

        for (int g = bid - NBLK; g < 6144; g += nprod) {
            int my = g / 24, nx = g - (g / 24) * 24;
            int m0 = my * 128, n0 = nx * 128;
            int m = m0 + arow;
            int tt = m >> 8, bb2 = m & 255;
            long gbase = (long)sent[bb2 * Tz + tt] * DWz;

            f32x4 acc[4][4];
            f32x4 zz = {0.f, 0.f, 0.f, 0.f};
#pragma unroll
            for (int i = 0; i < 4; ++i)
#pragma unroll
                for (int j = 0; j < 4; ++j) acc[i][j] = zz;

            for (int k0 = 0; k0 < DWz; k0 += 32) {
                if (ebb) {
                    const unsigned short* src = embb + gbase + k0 + kp;
                    *(int4*)(psA + arow * 40 + kp) = *(const int4*)src;
                    *(int4*)(psA + arow * 40 + kp + 8) = *(const int4*)(src + 8);
                } else {
                    const float* src = emb + gbase + k0 + kp;
                    alignas(16) unsigned short tmp[16];
#pragma unroll
                    for (int it = 0; it < 4; ++it) {
                        float4 v = ((const float4*)src)[it];
                        tmp[it * 4 + 0] = f2bf(v.x); tmp[it * 4 + 1] = f2bf(v.y);
                        tmp[it * 4 + 2] = f2bf(v.z); tmp[it * 4 + 3] = f2bf(v.w);
                    }
                    *(int4*)(psA + arow * 40 + kp) = *(const int4*)tmp;
                    *(int4*)(psA + arow * 40 + kp + 8) = *(const int4*)(tmp + 8);
                }
                {
                    const int4* wsrc = (const int4*)WihbP
                        + ((long)((k0 >> 5) * 24 + (n0 >> 7))) * 512 + tid;
                    int4 v0 = wsrc[0];
                    int4 v1 = wsrc[256];
                    *(int4*)(psB + bd0) = v0;
                    *(int4*)(psB + bd1) = v1;
                }
                __syncthreads();
                short8 af[4], bfr[4];
#pragma unroll
                for (int i = 0; i < 4; ++i)
                    af[i] = *(const short8*)(psA + (wm * 64 + i * 16 + l15) * 40 + q * 8);
#pragma unroll
                for (int j = 0; j < 4; ++j) {
                    int n = wn * 64 + j * 16 + l15;
                    bfr[j] = *(const short8*)(psB + n * 40 + ((q ^ ((n >> 3) & 3)) << 3));
                }
#pragma unroll
                for (int i = 0; i < 4; ++i)
#pragma unroll
                    for (int j = 0; j < 4; ++j)
                        acc[i][j] = __builtin_amdgcn_mfma_f32_16x16x32_bf16(af[i], bfr[j], acc[i][j], 0, 0, 0);
                __syncthreads();
            }
            // epilogue: agent-scope write-through stores (visible at L3 pre-flag)
#pragma unroll
            for (int j = 0; j < 4; ++j) {
                int n = n0 + wn * 64 + j * 16 + l15;
                int gt = n / 768;
                int dblk2 = (n - gt * 768) >> 4;
#pragma unroll
                for (int ip = 0; ip < 2; ++ip) {
                    int row = m0 + wm * 64 + ip * 32;
                    int t = row >> 8;
                    int bq = (row & 255) + q * 4;
                    int blk = dblk2 * 2 + (bq >> 7);
                    int tidd = ((bq & 127) >> 5) * 64 + q * 16 + l15;
                    alignas(16) unsigned short o[8];
#pragma unroll
                    for (int r = 0; r < 4; ++r) {
                        o[r]     = f2bf(acc[ip * 2][j][r]);
                        o[4 + r] = f2bf(acc[ip * 2 + 1][j][r]);
                    }
                    unsigned long long* dst = (unsigned long long*)
                        (xW + (((long)t * 96 + blk) * 4 + gt) * 2048 + (long)tidd * 8);
                    const unsigned long long* po = (const unsigned long long*)o;
                    __hip_atomic_store(dst, po[0], __ATOMIC_RELAXED, __HIP_MEMORY_SCOPE_AGENT);
                    __hip_atomic_store(dst + 1, po[1], __ATOMIC_RELAXED, __HIP_MEMORY_SCOPE_AGENT);
                }
            }
            asm volatile("s_waitcnt vmcnt(0)" ::: "memory");
            __syncthreads();   // all threads' stores drained before arrival bump
            if (tid == 0)
                (void)__hip_atomic_fetch_add(&xwcnt[(my >> 1) * 32], 1u,
                                             __ATOMIC_RELAXED, __HIP_MEMORY_SCOPE_AGENT);
        }
        return;
    }

    // ---------------- consumer: LSTM ----------------
    int bm = bid & 1;
    int dblk = bid >> 1;
    int d0 = dblk * 16;
    int d = d0 + l15;
    unsigned* flg = bar + ((bm * 4 + wid) * 48) * 32;

    {   // stage pre-swizzled Whh once
        const int4* src = (const int4*)WhhP + (long)dblk * 6144;
        for (int s = tid; s < 6144; s += 256) ((int4*)sB)[s] = src[s];
    }

    int brow[8];
    int lenr[8];
    float c[8], h[8];
    float xgc[2][4][4];
#pragma unroll
    for (int i = 0; i < 2; ++i)
#pragma unroll
        for (int r = 0; r < 4; ++r) {
            int ir = i * 4 + r;
            int b = bm * 128 + wid * 32 + i * 16 + q * 4 + r;
            brow[ir] = b;
            lenr[ir] = lens[b];
            long cbase = (long)b * G4z + d;
#pragma unroll
            for (int j = 0; j < 4; ++j) xgc[i][j][r] = constg[cbase + j * 768];
            if (t0 > 0) {
                c[ir] = cbuf[(long)b * DHz + d];
                h[ir] = bf2f(Hbf[((long)b * Tz + (t0 - 1)) * DHz + d]);
            } else { c[ir] = 0.f; h[ir] = 0.f; }
        }

    int bbase[4];
#pragma unroll
    for (int j = 0; j < 4; ++j) {
        int nl = j * 16 + l15;
        bbase[j] = nl * 32 + ((q ^ ((nl >> 1) & 3)) << 3);
    }
    __syncthreads();

    // wait for xW[t0] production, then load gate x-contributions
    if (waitxw) {
        const unsigned* xc = xwcnt + t0 * 32;
        if (lane == 0)
            while (__hip_atomic_load(xc, __ATOMIC_RELAXED, __HIP_MEMORY_SCOPE_AGENT) < 48u)
                __builtin_amdgcn_s_sleep(1);
        asm volatile("" ::: "memory");
    }
    float xg[2][4][4];
    {
        const unsigned short* x0 = xW + ((long)t0 * 96 + bid) * 8192 + (long)tid * 8;
        int4 c0 = *(const int4*)(x0);
        int4 c1 = *(const int4*)(x0 + 2048);
        int4 c2 = *(const int4*)(x0 + 4096);
        int4 c3 = *(const int4*)(x0 + 6144);
        UNPACK(c0, 0) UNPACK(c1, 1) UNPACK(c2, 2) UNPACK(c3, 3)
    }

    i32x4 pf0, pf1, pf2, pf3;

    for (int t = t0; t < t1; ++t) {
        if (t > t0) {
            unsigned tgt = (unsigned)t;
            const unsigned* fp = flg + lane * 32;
            while (true) {
                unsigned v = (lane < 48)
                    ? __hip_atomic_load(fp, __ATOMIC_RELAXED, __HIP_MEMORY_SCOPE_AGENT)
                    : tgt;
                if (__all(v >= tgt)) break;
                __builtin_amdgcn_s_sleep(1);
            }
            asm volatile("s_waitcnt vmcnt(0)" ::: "memory");
            __builtin_amdgcn_sched_barrier(0);
            UNPACK(pf0, 0) UNPACK(pf1, 1) UNPACK(pf2, 2) UNPACK(pf3, 3)
        }

        f32x4 acc[2][4];
        f32x4 zz = {0.f, 0.f, 0.f, 0.f};
#pragma unroll
        for (int i = 0; i < 2; ++i)
#pragma unroll
            for (int j = 0; j < 4; ++j) acc[i][j] = zz;

        if (t > 0) {
            const unsigned short* ap0 = Hbf + ((long)(bm * 128 + wid * 32 + l15) * Tz + (t - 1)) * DHz + q * 8;
            const unsigned short* ap1 = ap0 + (long)16 * Tz * DHz;
#pragma unroll 6
            for (int k0c = 0; k0c < 24; ++k0c) {
                short8 a0 = *(const short8*)(ap0 + k0c * 32);
                short8 a1 = *(const short8*)(ap1 + k0c * 32);
                const unsigned short* bb = sB + k0c * 2048;
#pragma unroll
                for (int j = 0; j < 4; ++j) {
                    short8 bf = *(const short8*)(bb + bbase[j]);
                    acc[0][j] = __builtin_amdgcn_mfma_f32_16x16x32_bf16(a0, bf, acc[0][j], 0, 0, 0);
                    acc[1][j] = __builtin_amdgcn_mfma_f32_16x16x32_bf16(a1, bf, acc[1][j], 0, 0, 0);
                }
            }
        }

#pragma unroll
        for (int i = 0; i < 2; ++i)
#pragma unroll
            for (int r = 0; r < 4; ++r) {
                int ir = i * 4 + r;
                float gi = acc[i][0][r] + xg[i][0][r];
                float gf = acc[i][1][r] + xg[i][1][r];
                float gg = acc[i][2][r] + xg[i][2][r];
                float go = acc[i][3][r] + xg[i][3][r];
                float cn = fsigm(gf) * c[ir] + fsigm(gi) * ftanh(gg);
                float hn = fsigm(go) * ftanh(cn);
                bool upd = t < lenr[ir];
                c[ir] = upd ? cn : c[ir];
                h[ir] = upd ? hn : h[ir];
                __hip_atomic_store(Hbf + ((long)brow[ir] * Tz + t) * DHz + d, f2bf(h[ir]),
                                   __ATOMIC_RELAXED, __HIP_MEMORY_SCOPE_AGENT);
            }

        if (t + 1 < t1) {
            // ensure xW[t+1] is produced (instant-pass once producers are ahead;
            // poll overlaps the h-store drain)
            if (waitxw) {
                const unsigned* xc = xwcnt + (t + 1) * 32;
                if (lane == 0)
                    while (__hip_atomic_load(xc, __ATOMIC_RELAXED, __HIP_MEMORY_SCOPE_AGENT) < 48u)
                        __builtin_amdgcn_s_sleep(1);
                asm volatile("" ::: "memory");
            }
            const unsigned short* pp = xW + ((long)(t + 1) * 96 + bid) * 8192 + (long)tid * 8;
            asm volatile(
                "global_load_dwordx4 %0, %4, off\n\t"
                "global_load_dwordx4 %1, %5, off\n\t"
                "global_load_dwordx4 %2, %6, off\n\t"
                "global_load_dwordx4 %3, %7, off"
                : "=&v"(pf0), "=&v"(pf1), "=&v"(pf2), "=&v"(pf3)
                : "v"(pp), "v"(pp + 2048), "v"(pp + 4096), "v"(pp + 6144)
                : "memory");
            asm volatile("s_waitcnt vmcnt(4)" ::: "memory");
            if (lane == 0)
                __hip_atomic_store(flg + dblk * 32, (unsigned)(t + 1),
                                   __ATOMIC_RELAXED, __HIP_MEMORY_SCOPE_AGENT);
        }
    }
#pragma unroll
    for (int ir = 0; ir < 8; ++ir) cbuf[(long)brow[ir] * DHz + d] = c[ir];
}

// ---------- scores[b,t] = sum_d w[d]*tanh( (H@Wh)[b,t,d] )  (pre-swizzled B) ----
__global__ __launch_bounds__(256) void k_scores(const unsigned short* __restrict__ Hbf,
                                                const unsigned short* __restrict__ WbP,
                                                const float* __restrict__ wv,
                                                float* __restrict__ scores) {
    __shared__ unsigned short sA[128 * 40];
    __shared__ unsigned short sB[128 * 40];
    __shared__ float sred[128];
    int tid = threadIdx.x;
    int n0 = blockIdx.x * 128;
    int m0 = blockIdx.y * 128;
    int wid = tid >> 6, lane = tid & 63, l15 = lane & 15, q = lane >> 4;
    int wm = wid >> 1, wn = wid & 1;

    int s0 = tid, s1 = tid + 256;
    int bd0 = (s0 >> 2) * 40 + (((s0 & 3) ^ (((s0 >> 2) >> 3) & 3)) << 3);
    int bd1 = (s1 >> 2) * 40 + (((s1 & 3) ^ (((s1 >> 2) >> 3) & 3)) << 3);

    f32x4 acc[4][4];
    f32x4 zz = {0.f, 0.f, 0.f, 0.f};
#pragma unroll
    for (int i = 0; i < 4; ++i)
#pragma unroll
        for (int j = 0; j < 4; ++j) acc[i][j] = zz;

    int arow = tid >> 1;
    int kp = (tid & 1) * 16;
    const unsigned short* asrc = Hbf + (long)(m0 + arow) * DHz;

    for (int k0 = 0; k0 < DHz; k0 += 32) {
        *(int4*)(sA + arow * 40 + kp) = *(const int4*)(asrc + k0 + kp);
        *(int4*)(sA + arow * 40 + kp + 8) = *(const int4*)(asrc + k0 + kp + 8);
        {
            const int4* wsrc = (const int4*)WbP
                + ((long)((k0 >> 5) * 6 + (n0 >> 7))) * 512 + tid;
            int4 v0 = wsrc[0];
            int4 v1 = wsrc[256];
            *(int4*)(sB + bd0) = v0;
            *(int4*)(sB + bd1) = v1;
        }
        __syncthreads();
        short8 af[4], bfr[4];
#pragma unroll
        for (int i = 0; i < 4; ++i)
            af[i] = *(const short8*)(sA + (wm * 64 + i * 16 + l15) * 40 + q * 8);
#pragma unroll
        for (int j = 0; j < 4; ++j) {
            int n = wn * 64 + j * 16 + l15;
            bfr[j] = *(const short8*)(sB + n * 40 + ((q ^ ((n >> 3) & 3)) << 3));
        }
#pragma unroll
        for (int i = 0; i < 4; ++i)
#pragma unroll
            for (int j = 0; j < 4; ++j)
                acc[i][j] = __builtin_amdgcn_mfma_f32_16x16x32_bf16(af[i], bfr[j], acc[i][j], 0, 0, 0);
        __syncthreads();
    }
    if (tid < 128) sred[tid] = 0.f;
    __syncthreads();
#pragma unroll
    for (int i = 0; i < 4; ++i)
#pragma unroll
        for (int r = 0; r < 4; ++r) {
            float sv = 0.f;
#pragma unroll
            for (int j = 0; j < 4; ++j) {
                int n = n0 + wn * 64 + j * 16 + l15;
                sv += ftanh(acc[i][j][r]) * wv[n];
            }
#pragma unroll
            for (int o = 1; o < 16; o <<= 1) sv += __shfl_xor(sv, o, 64);
            if (l15 == 0) atomicAdd(&sred[wm * 64 + i * 16 + q * 4 + r], sv);
        }
    __syncthreads();
    if (tid < 128) atomicAdd(&scores[m0 + tid], sred[tid]);
}

// ---------- masked softmax over T ----------
__global__ void k_softmax(const float* __restrict__ scores, const int* __restrict__ lens,
                          float* __restrict__ alpha) {
    int b = blockIdx.x, t = threadIdx.x;
    int len = lens[b];
    float s = (t < len) ? scores[b * Tz + t] : -1e9f;
    float m = s;
#pragma unroll
    for (int o = 32; o; o >>= 1) m = fmaxf(m, __shfl_xor(m, o, 64));
    __shared__ float rA[2], rB[2];
    if ((t & 63) == 0) rA[t >> 6] = m;
    __syncthreads();
    m = fmaxf(rA[0], rA[1]);
    float e = expf(s - m);
    float sum = e;
#pragma unroll
    for (int o = 32; o; o >>= 1) sum += __shfl_xor(sum, o, 64);
    if ((t & 63) == 0) rB[t >> 6] = sum;
    __syncthreads();
    sum = rB[0] + rB[1];
    alpha[b * Tz + t] = e / sum;
}

// ---------- r[b,d] = sum_t alpha[b,t] * H[b,t,d]  (coalesced int4 rows) ----------
__global__ __launch_bounds__(128) void k_r(const float* __restrict__ alpha,
                                           const unsigned short* __restrict__ Hbf,
                                           float* __restrict__ rbuf) {
    int b = blockIdx.x;
    int tid = threadIdx.x;
    __shared__ float sal[Tz];
    if (tid < Tz) sal[tid] = alpha[b * Tz + tid];
    __syncthreads();
    if (tid < 96) {
        const unsigned short* hp = Hbf + (long)b * Tz * DHz + tid * 8;
        float acc[8] = {};
        for (int t = 0; t < Tz; ++t) {
            short8 v = *(const short8*)(hp + (long)t * DHz);
            float a = sal[t];
            const unsigned short* pv = (const unsigned short*)&v;
#pragma unroll
            for (int e = 0; e < 8; ++e) acc[e] += a * bf2f(pv[e]);
        }
        float* rp = rbuf + (long)b * DHz + tid * 8;
#pragma unroll
        for (int e = 0; e < 8; ++e) rp[e] = acc[e];
    }
}

// ---------- h_star = tanh(r@Wp + H[:, -1, :]@Wx) ----------
__global__ void k_hstar(const float* __restrict__ rbuf, const unsigned short* __restrict__ Hbf,
                        const float* __restrict__ Wp, const float* __restrict__ Wx,
                        float* __restrict__ hst) {
    __shared__ float sA[16][65];
    __shared__ float sB[16][65];
    int bn = blockIdx.x * 64, bm = blockIdx.y * 64;
    int tx = threadIdx.x & 15, ty = threadIdx.x >> 4;
    float acc[4][4] = {};
    for (int src = 0; src < 2; ++src) {
        const float* Bm = src ? Wx : Wp;
        for (int k0 = 0; k0 < DHz; k0 += 16) {
            for (int l = threadIdx.x; l < 64 * 16; l += 256) {
                int mm = l >> 4, kk = l & 15;
                sA[kk][mm] = src ? bf2f(Hbf[((long)(bm + mm) * Tz + (Tz - 1)) * DHz + k0 + kk])
                                 : rbuf[(long)(bm + mm) * DHz + k0 + kk];
            }
            for (int l = threadIdx.x; l < 16 * 64; l += 256) {
                int kk = l >> 6, nn = l & 63;
                sB[kk][nn] = Bm[(long)(k0 + kk) * DHz + bn + nn];
            }
            __syncthreads();
            for (int k = 0; k < 16; ++k) {
                float a0[4], b0[4];
#pragma unroll
                for (int i = 0; i < 4; ++i) a0[i] = sA[k][ty * 4 + i];
#pragma unroll
                for (int j = 0; j < 4; ++j) b0[j] = sB[k][tx * 4 + j];
#pragma unroll
                for (int i = 0; i < 4; ++i)
#pragma unroll
                    for (int j = 0; j < 4; ++j) acc[i][j] += a0[i] * b0[j];
            }
            __syncthreads();
        }
    }
#pragma unroll
    for (int i = 0; i < 4; ++i)
#pragma unroll
        for (int j = 0; j < 4; ++j)
            hst[(long)(bm + ty * 4 + i) * DHz + bn + tx * 4 + j] = ftanh(acc[i][j]);
}

// ---------- logits ----------
__global__ void k_logits(const float* __restrict__ hst, const float* __restrict__ Wl,
                         const float* __restrict__ bl, float* __restrict__ out) {
    int b = blockIdx.x;
    int lane = threadIdx.x & 63, c = threadIdx.x >> 6;
    float s = 0.f;
    for (int k = lane; k < DHz; k += 64) s += hst[(long)b * DHz + k] * Wl[k * 3 + c];
#pragma unroll
    for (int o = 32; o; o >>= 1) s += __shfl_xor(s, o, 64);
    if (lane == 0) out[b * 3 + c] = s + bl[c];
}

extern "C" void kernel_launch(void* const* d_in, const int* in_sizes, int n_in,
                              void* d_out, int out_size, void* d_ws, size_t ws_size,
                              hipStream_t stream) {
    (void)in_sizes; (void)n_in; (void)out_size;
    const int*   sent   = (const int*)d_in[0];
    const int*   target = (const int*)d_in[1];
    const int*   lens   = (const int*)d_in[2];
    const float* emb    = (const float*)d_in[3];
    const float* temb   = (const float*)d_in[4];
    const float* W_ih   = (const float*)d_in[5];
    const float* W_hh   = (const float*)d_in[6];
    const float* b_lstm = (const float*)d_in[7];
    const float* Wh     = (const float*)d_in[8];
    const float* wv     = (const float*)d_in[10];
    const float* Wp     = (const float*)d_in[11];
    const float* Wx     = (const float*)d_in[12];
    const float* W_lin  = (const float*)d_in[13];
    const float* b_lin  = (const float*)d_in[14];
    float* out = (float*)d_out;

    char* ws = (char*)d_ws;
    size_t off = 0;
    auto alloc = [&](size_t bytes) -> void* {
        void* p = ws + off;
        off = (off + bytes + 255) & ~(size_t)255;
        return p;
    };
    unsigned short* xW    = (unsigned short*)alloc((size_t)32768 * G4z * 2);
    unsigned short* Hbf   = (unsigned short*)alloc((size_t)Bz * Tz * DHz * 2);
    unsigned short* WihbP = (unsigned short*)alloc((size_t)24 * 24 * 512 * 16);
    unsigned short* WhhP  = (unsigned short*)alloc((size_t)48 * 6144 * 16);
    unsigned short* WhbP  = (unsigned short*)alloc((size_t)24 * 6 * 512 * 16);
    float* tx     = (float*)alloc((size_t)Bz * DWz * 4);
    float* constg = (float*)alloc((size_t)Bz * G4z * 4);
    float* cbuf   = (float*)alloc((size_t)Bz * DHz * 4);
    float* scores = (float*)alloc((size_t)Bz * Tz * 4);
    float* alpha  = (float*)alloc((size_t)Bz * Tz * 4);
    float* rbuf   = (float*)alloc((size_t)Bz * DHz * 4);
    float* hst    = (float*)alloc((size_t)Bz * DHz * 4);
    unsigned* bar = (unsigned*)alloc(65536);    // h flags: 8 groups x 48 x 128B
    unsigned* xwc = (unsigned*)alloc(16384);    // xW arrival counters: 128 x 128B

    size_t embb_bytes = (size_t)VOCABz * DWz * 2;
    unsigned short* embb = (unsigned short*)alloc(embb_bytes);
    int ebb = (off <= ws_size) ? 1 : 0;

    if (ebb) k_cvt4<<<4096, 256, 0, stream>>>(emb, embb, VOCABz * DWz / 4);
    k_prep_wswz<<<576, 256, 0, stream>>>(W_ih, WihbP, 24);   // W_ih[:768] @ N=3072
    k_prep_wswz<<<144, 256, 0, stream>>>(Wh, WhbP, 6);       // Wh @ N=768
    k_prep_whh<<<1152, 256, 0, stream>>>(W_hh, WhhP);
    k_prep_tx<<<Bz, 256, 0, stream>>>(target, temb, tx);
    hipMemsetAsync(scores, 0, (size_t)Bz * Tz * 4, stream);
    hipMemsetAsync(bar, 0, 65536, stream);
    hipMemsetAsync(xwc, 0, 16384, stream);

    k_gemm_f32_bias<<<dim3(48, 4), 256, 0, stream>>>(tx, W_ih + (size_t)DWz * G4z, b_lstm,
                                                     constg, Bz, G4z, DWz, DWz, G4z);

    hipFuncSetAttribute((const void*)k_lstm_all,
                        hipFuncAttributeMaxDynamicSharedMemorySize, 98304);
    int t0v = 0, t1v = Tz, waitv = 1, nprodv = NGRID - NBLK;
    unsigned short* xWp = xW;
    const float* cgp = constg;
    const unsigned short* whp = WhhP;
    unsigned short* hbp = Hbf;
    float* cbp = cbuf;
    const int* lnp = lens;
    unsigned* barp = bar;
    unsigned* xwcp = xwc;
    const float* embp = emb;
    const unsigned short* embbp = embb;
    const int* sentp = sent;
    const unsigned short* wihp = WihbP;
    void* kargs[] = {&t0v, &t1v, &xWp, &cgp, &whp, &hbp, &cbp, &lnp, &barp,
                     &xwcp, &waitv, &embp, &embbp, &ebb, &sentp, &wihp, &nprodv};
    hipError_t ce = hipLaunchCooperativeKernel(reinterpret_cast<void*>(k_lstm_all),
                                               dim3(NGRID), dim3(256), kargs, 98304, stream);
    if (ce != hipSuccess) {
        // fallback: serial gemm_x (kernel boundary = coherent) + per-step LSTM
        k_gemm_x<<<dim3(24, 256), 256, 0, stream>>>(emb, embb, ebb, sent, WihbP, xW);
        for (int t = 0; t < Tz; ++t)
            k_lstm_all<<<NBLK, 256, 98304, stream>>>(t, t + 1, xW, constg, WhhP, Hbf,
                                                     cbuf, lens, bar, xwc, 0,
                                                     emb, embb, ebb, sent, WihbP, 0);
    }

    k_scores<<<dim3(6, 256), 256, 0, stream>>>(Hbf, WhbP, wv, scores);
    k_softmax<<<Bz, 128, 0, stream>>>(scores, lens, alpha);
    k_r<<<Bz, 128, 0, stream>>>(alpha, Hbf, rbuf);
    k_hstar<<<dim3(12, 4), 256, 0, stream>>>(rbuf, Hbf, Wp, Wx, hst);
    k_logits<<<Bz, 192, 0, stream>>>(hst, W_lin, b_lin, out);
}

// Round 9
// 1908.897 us; speedup vs baseline: 1.4864x; 1.2154x over previous
//
#include <hip/hip_runtime.h>
#include <stdint.h>

#define Bz 256
#define Tz 128
#define DWz 768
#define DHz 768
#define G4z 3072
#define NBLK 96
#define NGRID 256

typedef __attribute__((ext_vector_type(8))) short short8;
typedef __attribute__((ext_vector_type(4))) float f32x4;
typedef __attribute__((ext_vector_type(4))) int i32x4;

__device__ __forceinline__ unsigned short f2bf(float x) {
    union { float f; unsigned int u; } v; v.f = x;
    unsigned int u = v.u;
    return (unsigned short)((u + 0x7fffu + ((u >> 16) & 1u)) >> 16);
}
__device__ __forceinline__ float bf2f(unsigned short h) {
    union { unsigned int u; float f; } v; v.u = ((unsigned int)h) << 16;
    return v.f;
}
// fast transcendentals: v_exp_f32 + v_rcp_f32 (1-ulp class, fine vs bf16 floor)
__device__ __forceinline__ float fsigm(float x) {
    return __builtin_amdgcn_rcpf(1.0f + __builtin_amdgcn_exp2f(x * -1.4426950408889634f));
}
__device__ __forceinline__ float ftanh(float x) {
    x = fminf(fmaxf(x, -15.0f), 15.0f);           // keep e finite: no inf -> NaN
    float e = __builtin_amdgcn_exp2f(x * -2.8853900817779268f);
    return (1.0f - e) * __builtin_amdgcn_rcpf(1.0f + e);
}

// ---------- generic B pre-swizzle (sboff LDS layout chunks) ----------
// W (KxN fp32, N = NT*128) -> 16B chunks: chunk s = n*4+kq of tile (kt,nt) holds
// bf16 W[kt*32+kq*8+e][nt*128+n]. Consumers stage B as 2x{int4 load + int4 ds_write}.
__global__ __launch_bounds__(256) void k_prep_wswz(const float* __restrict__ W,
                                                   unsigned short* __restrict__ out, int NT) {
    __shared__ float sT[32][132];
    int bid = blockIdx.x;
    int kt = bid / NT, nt = bid - kt * NT;
    int tid = threadIdx.x;
    int ldn = NT * 128;
    {
        int r = tid >> 3;
        int cb = (tid & 7) * 16;
        const float* src = W + (long)(kt * 32 + r) * ldn + nt * 128 + cb;
#pragma unroll
        for (int u = 0; u < 4; ++u) {
            float4 v = ((const float4*)src)[u];
            sT[r][cb + u * 4 + 0] = v.x; sT[r][cb + u * 4 + 1] = v.y;
            sT[r][cb + u * 4 + 2] = v.z; sT[r][cb + u * 4 + 3] = v.w;
        }
    }
    __syncthreads();
#pragma unroll
    for (int it = 0; it < 2; ++it) {
        int s = tid + it * 256;
        int n = s >> 2, kq = s & 3;
        alignas(16) unsigned short o[8];
#pragma unroll
        for (int e = 0; e < 8; ++e) o[e] = f2bf(sT[kq * 8 + e][n]);
        *(int4*)(out + ((long)bid * 512 + s) * 8) = *(const int4*)o;
    }
}

// ---------- Whh -> pre-swizzled bf16 blobs (coalesced reads via LDS transpose) ----
__global__ __launch_bounds__(256) void k_prep_whh(const float* __restrict__ Whh,
                                                  unsigned short* __restrict__ WhhP) {
    __shared__ float sT[32][65];
    int bid = blockIdx.x;            // [0, 1152)
    int dblk = bid / 24;
    int k0c = bid - dblk * 24;
    int tid = threadIdx.x;
    {
        int kk = tid >> 3;
        int seg = tid & 7;
        const float* src = Whh + (long)(k0c * 32 + kk) * G4z
                         + (seg >> 1) * 768 + dblk * 16 + (seg & 1) * 8;
        float4 v0 = *(const float4*)src;
        float4 v1 = *(const float4*)(src + 4);
        int cl = seg * 8;
        sT[kk][cl + 0] = v0.x; sT[kk][cl + 1] = v0.y; sT[kk][cl + 2] = v0.z; sT[kk][cl + 3] = v0.w;
        sT[kk][cl + 4] = v1.x; sT[kk][cl + 5] = v1.y; sT[kk][cl + 6] = v1.z; sT[kk][cl + 7] = v1.w;
    }
    __syncthreads();
    {
        int nl = tid >> 2, cc = tid & 3;
        int q8 = cc ^ ((nl >> 1) & 3);
        int clv = (nl >> 4) * 16 + (nl & 15);
        alignas(16) unsigned short o[8];
#pragma unroll
        for (int e = 0; e < 8; ++e) o[e] = f2bf(sT[q8 * 8 + e][clv]);
        *(int4*)(WhhP + (long)(dblk * 6144 + k0c * 256 + tid) * 8) = *(const int4*)o;
    }
}

// ---------- constg = temb[target] @ W_ih[768:] + b_lstm  (bf16 MFMA) ----------
// Replaces prep_tx + fp32 SIMD GEMM. A rows gathered from temb via target[b].
__global__ __launch_bounds__(256) void k_gemm_cg(const int* __restrict__ target,
                                                 const float* __restrict__ temb,
                                                 const unsigned short* __restrict__ WbP,
                                                 const float* __restrict__ bias,
                                                 float* __restrict__ C) {
    __shared__ unsigned short sA[128 * 40];
    __shared__ unsigned short sB[128 * 40];
    int tid = threadIdx.x;
    int n0 = blockIdx.x * 128;
    int m0 = blockIdx.y * 128;
    int wid = tid >> 6, lane = tid & 63, l15 = lane & 15, q = lane >> 4;
    int wm = wid >> 1, wn = wid & 1;
    int arow = tid >> 1;
    int kp = (tid & 1) * 16;
    long gbase = (long)target[m0 + arow] * DWz;
    int s0 = tid, s1 = tid + 256;
    int bd0 = (s0 >> 2) * 40 + (((s0 & 3) ^ (((s0 >> 2) >> 3) & 3)) << 3);
    int bd1 = (s1 >> 2) * 40 + (((s1 & 3) ^ (((s1 >> 2) >> 3) & 3)) << 3);

    f32x4 acc[4][4];
    f32x4 zz = {0.f, 0.f, 0.f, 0.f};
#pragma unroll
    for (int i = 0; i < 4; ++i)
#pragma unroll
        for (int j = 0; j < 4; ++j) acc[i][j] = zz;

    for (int k0 = 0; k0 < DWz; k0 += 32) {
        {
            const float* src = temb + gbase + k0 + kp;
            alignas(16) unsigned short tmp[16];
#pragma unroll
            for (int it = 0; it < 4; ++it) {
                float4 v = ((const float4*)src)[it];
                tmp[it * 4 + 0] = f2bf(v.x); tmp[it * 4 + 1] = f2bf(v.y);
                tmp[it * 4 + 2] = f2bf(v.z); tmp[it * 4 + 3] = f2bf(v.w);
            }
            *(int4*)(sA + arow * 40 + kp) = *(const int4*)tmp;
            *(int4*)(sA + arow * 40 + kp + 8) = *(const int4*)(tmp + 8);
        }
        {
            const int4* wsrc = (const int4*)WbP
                + ((long)((k0 >> 5) * 24 + (n0 >> 7))) * 512 + tid;
            int4 v0 = wsrc[0];
            int4 v1 = wsrc[256];
            *(int4*)(sB + bd0) = v0;
            *(int4*)(sB + bd1) = v1;
        }
        __syncthreads();
        short8 af[4], bfr[4];
#pragma unroll
        for (int i = 0; i < 4; ++i)
            af[i] = *(const short8*)(sA + (wm * 64 + i * 16 + l15) * 40 + q * 8);
#pragma unroll
        for (int j = 0; j < 4; ++j) {
            int n = wn * 64 + j * 16 + l15;
            bfr[j] = *(const short8*)(sB + n * 40 + ((q ^ ((n >> 3) & 3)) << 3));
        }
#pragma unroll
        for (int i = 0; i < 4; ++i)
#pragma unroll
            for (int j = 0; j < 4; ++j)
                acc[i][j] = __builtin_amdgcn_mfma_f32_16x16x32_bf16(af[i], bfr[j], acc[i][j], 0, 0, 0);
        __syncthreads();
    }
#pragma unroll
    for (int i = 0; i < 4; ++i)
#pragma unroll
        for (int j = 0; j < 4; ++j) {
            int col = n0 + wn * 64 + j * 16 + l15;
            float bv = bias[col];
#pragma unroll
            for (int r = 0; r < 4; ++r) {
                int row = m0 + wm * 64 + i * 16 + q * 4 + r;
                C[(long)row * G4z + col] = acc[i][j][r] + bv;
            }
        }
}

// ---------- standalone xW GEMM (fallback path only; kernel boundary = coherent) ----
__global__ __launch_bounds__(256) void k_gemm_x(const float* __restrict__ emb,
                                                const int* __restrict__ sent,
                                                const unsigned short* __restrict__ WbP,
                                                unsigned short* __restrict__ xW) {
    __shared__ unsigned short sA[128 * 40];
    __shared__ unsigned short sB[128 * 40];
    int tid = threadIdx.x;
    int n0 = blockIdx.x * 128;
    int m0 = blockIdx.y * 128;
    int wid = tid >> 6, lane = tid & 63, l15 = lane & 15, q = lane >> 4;
    int wm = wid >> 1, wn = wid & 1;
    int arow = tid >> 1;
    int kp = (tid & 1) * 16;
    int m = m0 + arow;
    int tt = m >> 8;
    int bb = m & 255;
    long gbase = (long)sent[bb * Tz + tt] * DWz;
    int s0 = tid, s1 = tid + 256;
    int bd0 = (s0 >> 2) * 40 + (((s0 & 3) ^ (((s0 >> 2) >> 3) & 3)) << 3);
    int bd1 = (s1 >> 2) * 40 + (((s1 & 3) ^ (((s1 >> 2) >> 3) & 3)) << 3);

    f32x4 acc[4][4];
    f32x4 zz = {0.f, 0.f, 0.f, 0.f};
#pragma unroll
    for (int i = 0; i < 4; ++i)
#pragma unroll
        for (int j = 0; j < 4; ++j) acc[i][j] = zz;

    for (int k0 = 0; k0 < DWz; k0 += 32) {
        {
            const float* src = emb + gbase + k0 + kp;
            alignas(16) unsigned short tmp[16];
#pragma unroll
            for (int it = 0; it < 4; ++it) {
                float4 v = ((const float4*)src)[it];
                tmp[it * 4 + 0] = f2bf(v.x); tmp[it * 4 + 1] = f2bf(v.y);
                tmp[it * 4 + 2] = f2bf(v.z); tmp[it * 4 + 3] = f2bf(v.w);
            }
            *(int4*)(sA + arow * 40 + kp) = *(const int4*)tmp;
            *(int4*)(sA + arow * 40 + kp + 8) = *(const int4*)(tmp + 8);
        }
        {
            const int4* wsrc = (const int4*)WbP
                + ((long)((k0 >> 5) * 24 + (n0 >> 7))) * 512 + tid;
            int4 v0 = wsrc[0];
            int4 v1 = wsrc[256];
            *(int4*)(sB + bd0) = v0;
            *(int4*)(sB + bd1) = v1;
        }
        __syncthreads();
        short8 af[4], bfr[4];
#pragma unroll
        for (int i = 0; i < 4; ++i)
            af[i] = *(const short8*)(sA + (wm * 64 + i * 16 + l15) * 40 + q * 8);
#pragma unroll
        for (int j = 0; j < 4; ++j) {
            int n = wn * 64 + j * 16 + l15;
            bfr[j] = *(const short8*)(sB + n * 40 + ((q ^ ((n >> 3) & 3)) << 3));
        }
#pragma unroll
        for (int i = 0; i < 4; ++i)
#pragma unroll
            for (int j = 0; j < 4; ++j)
                acc[i][j] = __builtin_amdgcn_mfma_f32_16x16x32_bf16(af[i], bfr[j], acc[i][j], 0, 0, 0);
        __syncthreads();
    }
#pragma unroll
    for (int j = 0; j < 4; ++j) {
        int n = n0 + wn * 64 + j * 16 + l15;
        int gt = n / 768;
        int dblk = (n - gt * 768) >> 4;
#pragma unroll
        for (int ip = 0; ip < 2; ++ip) {
            int row = m0 + wm * 64 + ip * 32;
            int t = row >> 8;
            int bq = (row & 255) + q * 4;
            int blk = dblk * 2 + (bq >> 7);
            int tidd = ((bq & 127) >> 5) * 64 + q * 16 + l15;
            alignas(16) unsigned short o[8];
#pragma unroll
            for (int r = 0; r < 4; ++r) {
                o[r]     = f2bf(acc[ip * 2][j][r]);
                o[4 + r] = f2bf(acc[ip * 2 + 1][j][r]);
            }
            *(int4*)(xW + (((long)t * 96 + blk) * 4 + gt) * 2048 + (long)tidd * 8) = *(const int4*)o;
        }
    }
}

// ---------- fused persistent kernel: LSTM (blocks 0..95) + xW producer (96..255) ----
// LSTM part: round-3 wave-dataflow scheme, UNCHANGED (measured local optimum).
// Producer part: 160 blocks loop over the 6144 gemm_x tiles in t-ascending order;
// xW stores are agent-scope atomic u64 (write-through to L3); per-t arrival
// counters gate the consumers' xW prefetch. Producers use the fp32 emb path
// (embb pre-convert dropped: producers have ~750us slack, the serial cvt did not).
#define UNPACK(PF, G)                                                        \
    {                                                                        \
        const unsigned short* ch_ = (const unsigned short*)&(PF);            \
        _Pragma("unroll")                                                    \
        for (int i_ = 0; i_ < 2; ++i_)                                       \
            _Pragma("unroll")                                                \
            for (int r_ = 0; r_ < 4; ++r_)                                   \
                xg[i_][G][r_] = bf2f(ch_[i_ * 4 + r_]) + xgc[i_][G][r_];     \
    }

__global__ __launch_bounds__(256, 1) void k_lstm_all(int t0, int t1,
        unsigned short* __restrict__ xW, const float* __restrict__ constg,
        const unsigned short* __restrict__ WhhP, unsigned short* __restrict__ Hbf,
        float* __restrict__ cbuf, const int* __restrict__ lens,
        unsigned* __restrict__ bar, unsigned* __restrict__ xwcnt, int waitxw,
        const float* __restrict__ emb, const int* __restrict__ sent,
        const unsigned short* __restrict__ WihbP, int nprod) {
    extern __shared__ unsigned short sB[];   // 96 KB dynamic
    int bid = blockIdx.x;
    int tid = threadIdx.x;
    int lane = tid & 63, wid = tid >> 6;
    int l15 = lane & 15, q = lane >> 4;

    if (bid >= NBLK) {
        // ---------------- producer: xW tiles ----------------
        unsigned short* psA = sB;
        unsigned short* psB = sB + 5120;
        int wm = wid >> 1, wn = wid & 1;
        int arow = tid >> 1;
        int kp = (tid & 1) * 16;
        int s0 = tid, s1 = tid + 256;
        int bd0 = (s0 >> 2) * 40 + (((s0 & 3) ^ (((s0 >> 2) >> 3) & 3)) << 3);
        int bd1 = (s1 >> 2) * 40 + (((s1 & 3) ^ (((s1 >> 2) >> 3) & 3)) << 3);

        for (int g = bid - NBLK; g < 6144; g += nprod) {
            int my = g / 24, nx = g - (g / 24) * 24;
            int m0 = my * 128, n0 = nx * 128;
            int m = m0 + arow;
            int tt = m >> 8, bb2 = m & 255;
            long gbase = (long)sent[bb2 * Tz + tt] * DWz;

            f32x4 acc[4][4];
            f32x4 zz = {0.f, 0.f, 0.f, 0.f};
#pragma unroll
            for (int i = 0; i < 4; ++i)
#pragma unroll
                for (int j = 0; j < 4; ++j) acc[i][j] = zz;

            for (int k0 = 0; k0 < DWz; k0 += 32) {
                {
                    const float* src = emb + gbase + k0 + kp;
                    alignas(16) unsigned short tmp[16];
#pragma unroll
                    for (int it = 0; it < 4; ++it) {
                        float4 v = ((const float4*)src)[it];
                        tmp[it * 4 + 0] = f2bf(v.x); tmp[it * 4 + 1] = f2bf(v.y);
                        tmp[it * 4 + 2] = f2bf(v.z); tmp[it * 4 + 3] = f2bf(v.w);
                    }
                    *(int4*)(psA + arow * 40 + kp) = *(const int4*)tmp;
                    *(int4*)(psA + arow * 40 + kp + 8) = *(const int4*)(tmp + 8);
                }
                {
                    const int4* wsrc = (const int4*)WihbP
                        + ((long)((k0 >> 5) * 24 + (n0 >> 7))) * 512 + tid;
                    int4 v0 = wsrc[0];
                    int4 v1 = wsrc[256];
                    *(int4*)(psB + bd0) = v0;
                    *(int4*)(psB + bd1) = v1;
                }
                __syncthreads();
                short8 af[4], bfr[4];
#pragma unroll
                for (int i = 0; i < 4; ++i)
                    af[i] = *(const short8*)(psA + (wm * 64 + i * 16 + l15) * 40 + q * 8);
#pragma unroll
                for (int j = 0; j < 4; ++j) {
                    int n = wn * 64 + j * 16 + l15;
                    bfr[j] = *(const short8*)(psB + n * 40 + ((q ^ ((n >> 3) & 3)) << 3));
                }
#pragma unroll
                for (int i = 0; i < 4; ++i)
#pragma unroll
                    for (int j = 0; j < 4; ++j)
                        acc[i][j] = __builtin_amdgcn_mfma_f32_16x16x32_bf16(af[i], bfr[j], acc[i][j], 0, 0, 0);
                __syncthreads();
            }
            // epilogue: agent-scope write-through stores (visible at L3 pre-flag)
#pragma unroll
            for (int j = 0; j < 4; ++j) {
                int n = n0 + wn * 64 + j * 16 + l15;
                int gt = n / 768;
                int dblk2 = (n - gt * 768) >> 4;
#pragma unroll
                for (int ip = 0; ip < 2; ++ip) {
                    int row = m0 + wm * 64 + ip * 32;
                    int t = row >> 8;
                    int bq = (row & 255) + q * 4;
                    int blk = dblk2 * 2 + (bq >> 7);
                    int tidd = ((bq & 127) >> 5) * 64 + q * 16 + l15;
                    alignas(16) unsigned short o[8];
#pragma unroll
                    for (int r = 0; r < 4; ++r) {
                        o[r]     = f2bf(acc[ip * 2][j][r]);
                        o[4 + r] = f2bf(acc[ip * 2 + 1][j][r]);
                    }
                    unsigned long long* dst = (unsigned long long*)
                        (xW + (((long)t * 96 + blk) * 4 + gt) * 2048 + (long)tidd * 8);
                    const unsigned long long* po = (const unsigned long long*)o;
                    __hip_atomic_store(dst, po[0], __ATOMIC_RELAXED, __HIP_MEMORY_SCOPE_AGENT);
                    __hip_atomic_store(dst + 1, po[1], __ATOMIC_RELAXED, __HIP_MEMORY_SCOPE_AGENT);
                }
            }
            asm volatile("s_waitcnt vmcnt(0)" ::: "memory");
            __syncthreads();   // all threads' stores drained before arrival bump
            if (tid == 0)
                (void)__hip_atomic_fetch_add(&xwcnt[(my >> 1) * 32], 1u,
                                             __ATOMIC_RELAXED, __HIP_MEMORY_SCOPE_AGENT);
        }
        return;
    }

    // ---------------- consumer: LSTM ----------------
    int bm = bid & 1;
    int dblk = bid >> 1;
    int d0 = dblk * 16;
    int d = d0 + l15;
    unsigned* flg = bar + ((bm * 4 + wid) * 48) * 32;

    {   // stage pre-swizzled Whh once
        const int4* src = (const int4*)WhhP + (long)dblk * 6144;
        for (int s = tid; s < 6144; s += 256) ((int4*)sB)[s] = src[s];
    }

    int brow[8];
    int lenr[8];
    float c[8], h[8];
    float xgc[2][4][4];
#pragma unroll
    for (int i = 0; i < 2; ++i)
#pragma unroll
        for (int r = 0; r < 4; ++r) {
            int ir = i * 4 + r;
            int b = bm * 128 + wid * 32 + i * 16 + q * 4 + r;
            brow[ir] = b;
            lenr[ir] = lens[b];
            long cbase = (long)b * G4z + d;
#pragma unroll
            for (int j = 0; j < 4; ++j) xgc[i][j][r] = constg[cbase + j * 768];
            if (t0 > 0) {
                c[ir] = cbuf[(long)b * DHz + d];
                h[ir] = bf2f(Hbf[((long)b * Tz + (t0 - 1)) * DHz + d]);
            } else { c[ir] = 0.f; h[ir] = 0.f; }
        }

    int bbase[4];
#pragma unroll
    for (int j = 0; j < 4; ++j) {
        int nl = j * 16 + l15;
        bbase[j] = nl * 32 + ((q ^ ((nl >> 1) & 3)) << 3);
    }
    __syncthreads();

    // wait for xW[t0] production, then load gate x-contributions
    if (waitxw) {
        const unsigned* xc = xwcnt + t0 * 32;
        if (lane == 0)
            while (__hip_atomic_load(xc, __ATOMIC_RELAXED, __HIP_MEMORY_SCOPE_AGENT) < 48u)
                __builtin_amdgcn_s_sleep(1);
        asm volatile("" ::: "memory");
    }
    float xg[2][4][4];
    {
        const unsigned short* x0 = xW + ((long)t0 * 96 + bid) * 8192 + (long)tid * 8;
        int4 c0 = *(const int4*)(x0);
        int4 c1 = *(const int4*)(x0 + 2048);
        int4 c2 = *(const int4*)(x0 + 4096);
        int4 c3 = *(const int4*)(x0 + 6144);
        UNPACK(c0, 0) UNPACK(c1, 1) UNPACK(c2, 2) UNPACK(c3, 3)
    }

    i32x4 pf0, pf1, pf2, pf3;

    for (int t = t0; t < t1; ++t) {
        if (t > t0) {
            unsigned tgt = (unsigned)t;
            const unsigned* fp = flg + lane * 32;
            while (true) {
                unsigned v = (lane < 48)
                    ? __hip_atomic_load(fp, __ATOMIC_RELAXED, __HIP_MEMORY_SCOPE_AGENT)
                    : tgt;
                if (__all(v >= tgt)) break;
                __builtin_amdgcn_s_sleep(1);
            }
            asm volatile("s_waitcnt vmcnt(0)" ::: "memory");
            __builtin_amdgcn_sched_barrier(0);
            UNPACK(pf0, 0) UNPACK(pf1, 1) UNPACK(pf2, 2) UNPACK(pf3, 3)
        }

        f32x4 acc[2][4];
        f32x4 zz = {0.f, 0.f, 0.f, 0.f};
#pragma unroll
        for (int i = 0; i < 2; ++i)
#pragma unroll
            for (int j = 0; j < 4; ++j) acc[i][j] = zz;

        if (t > 0) {
            const unsigned short* ap0 = Hbf + ((long)(bm * 128 + wid * 32 + l15) * Tz + (t - 1)) * DHz + q * 8;
            const unsigned short* ap1 = ap0 + (long)16 * Tz * DHz;
#pragma unroll 6
            for (int k0c = 0; k0c < 24; ++k0c) {
                short8 a0 = *(const short8*)(ap0 + k0c * 32);
                short8 a1 = *(const short8*)(ap1 + k0c * 32);
                const unsigned short* bb = sB + k0c * 2048;
#pragma unroll
                for (int j = 0; j < 4; ++j) {
                    short8 bf = *(const short8*)(bb + bbase[j]);
                    acc[0][j] = __builtin_amdgcn_mfma_f32_16x16x32_bf16(a0, bf, acc[0][j], 0, 0, 0);
                    acc[1][j] = __builtin_amdgcn_mfma_f32_16x16x32_bf16(a1, bf, acc[1][j], 0, 0, 0);
                }
            }
        }

#pragma unroll
        for (int i = 0; i < 2; ++i)
#pragma unroll
            for (int r = 0; r < 4; ++r) {
                int ir = i * 4 + r;
                float gi = acc[i][0][r] + xg[i][0][r];
                float gf = acc[i][1][r] + xg[i][1][r];
                float gg = acc[i][2][r] + xg[i][2][r];
                float go = acc[i][3][r] + xg[i][3][r];
                float cn = fsigm(gf) * c[ir] + fsigm(gi) * ftanh(gg);
                float hn = fsigm(go) * ftanh(cn);
                bool upd = t < lenr[ir];
                c[ir] = upd ? cn : c[ir];
                h[ir] = upd ? hn : h[ir];
                __hip_atomic_store(Hbf + ((long)brow[ir] * Tz + t) * DHz + d, f2bf(h[ir]),
                                   __ATOMIC_RELAXED, __HIP_MEMORY_SCOPE_AGENT);
            }

        if (t + 1 < t1) {
            if (waitxw) {
                const unsigned* xc = xwcnt + (t + 1) * 32;
                if (lane == 0)
                    while (__hip_atomic_load(xc, __ATOMIC_RELAXED, __HIP_MEMORY_SCOPE_AGENT) < 48u)
                        __builtin_amdgcn_s_sleep(1);
                asm volatile("" ::: "memory");
            }
            const unsigned short* pp = xW + ((long)(t + 1) * 96 + bid) * 8192 + (long)tid * 8;
            asm volatile(
                "global_load_dwordx4 %0, %4, off\n\t"
                "global_load_dwordx4 %1, %5, off\n\t"
                "global_load_dwordx4 %2, %6, off\n\t"
                "global_load_dwordx4 %3, %7, off"
                : "=&v"(pf0), "=&v"(pf1), "=&v"(pf2), "=&v"(pf3)
                : "v"(pp), "v"(pp + 2048), "v"(pp + 4096), "v"(pp + 6144)
                : "memory");
            asm volatile("s_waitcnt vmcnt(4)" ::: "memory");
            if (lane == 0)
                __hip_atomic_store(flg + dblk * 32, (unsigned)(t + 1),
                                   __ATOMIC_RELAXED, __HIP_MEMORY_SCOPE_AGENT);
        }
    }
#pragma unroll
    for (int ir = 0; ir < 8; ++ir) cbuf[(long)brow[ir] * DHz + d] = c[ir];
}

// ---------- scores[b,t] = sum_d w[d]*tanh( (H@Wh)[b,t,d] )  (pre-swizzled B) ----
__global__ __launch_bounds__(256) void k_scores(const unsigned short* __restrict__ Hbf,
                                                const unsigned short* __restrict__ WbP,
                                                const float* __restrict__ wv,
                                                float* __restrict__ scores) {
    __shared__ unsigned short sA[128 * 40];
    __shared__ unsigned short sB[128 * 40];
    __shared__ float sred[128];
    int tid = threadIdx.x;
    int n0 = blockIdx.x * 128;
    int m0 = blockIdx.y * 128;
    int wid = tid >> 6, lane = tid & 63, l15 = lane & 15, q = lane >> 4;
    int wm = wid >> 1, wn = wid & 1;

    int s0 = tid, s1 = tid + 256;
    int bd0 = (s0 >> 2) * 40 + (((s0 & 3) ^ (((s0 >> 2) >> 3) & 3)) << 3);
    int bd1 = (s1 >> 2) * 40 + (((s1 & 3) ^ (((s1 >> 2) >> 3) & 3)) << 3);

    f32x4 acc[4][4];
    f32x4 zz = {0.f, 0.f, 0.f, 0.f};
#pragma unroll
    for (int i = 0; i < 4; ++i)
#pragma unroll
        for (int j = 0; j < 4; ++j) acc[i][j] = zz;

    int arow = tid >> 1;
    int kp = (tid & 1) * 16;
    const unsigned short* asrc = Hbf + (long)(m0 + arow) * DHz;

    for (int k0 = 0; k0 < DHz; k0 += 32) {
        *(int4*)(sA + arow * 40 + kp) = *(const int4*)(asrc + k0 + kp);
        *(int4*)(sA + arow * 40 + kp + 8) = *(const int4*)(asrc + k0 + kp + 8);
        {
            const int4* wsrc = (const int4*)WbP
                + ((long)((k0 >> 5) * 6 + (n0 >> 7))) * 512 + tid;
            int4 v0 = wsrc[0];
            int4 v1 = wsrc[256];
            *(int4*)(sB + bd0) = v0;
            *(int4*)(sB + bd1) = v1;
        }
        __syncthreads();
        short8 af[4], bfr[4];
#pragma unroll
        for (int i = 0; i < 4; ++i)
            af[i] = *(const short8*)(sA + (wm * 64 + i * 16 + l15) * 40 + q * 8);
#pragma unroll
        for (int j = 0; j < 4; ++j) {
            int n = wn * 64 + j * 16 + l15;
            bfr[j] = *(const short8*)(sB + n * 40 + ((q ^ ((n >> 3) & 3)) << 3));
        }
#pragma unroll
        for (int i = 0; i < 4; ++i)
#pragma unroll
            for (int j = 0; j < 4; ++j)
                acc[i][j] = __builtin_amdgcn_mfma_f32_16x16x32_bf16(af[i], bfr[j], acc[i][j], 0, 0, 0);
        __syncthreads();
    }
    if (tid < 128) sred[tid] = 0.f;
    __syncthreads();
#pragma unroll
    for (int i = 0; i < 4; ++i)
#pragma unroll
        for (int r = 0; r < 4; ++r) {
            float sv = 0.f;
#pragma unroll
            for (int j = 0; j < 4; ++j) {
                int n = n0 + wn * 64 + j * 16 + l15;
                sv += ftanh(acc[i][j][r]) * wv[n];
            }
#pragma unroll
            for (int o = 1; o < 16; o <<= 1) sv += __shfl_xor(sv, o, 64);
            if (l15 == 0) atomicAdd(&sred[wm * 64 + i * 16 + q * 4 + r], sv);
        }
    __syncthreads();
    if (tid < 128) atomicAdd(&scores[m0 + tid], sred[tid]);
}

// ---------- fused masked softmax + r = alpha @ H (per-b block) ----------
__global__ __launch_bounds__(128) void k_attn(const float* __restrict__ scores,
                                              const int* __restrict__ lens,
                                              const unsigned short* __restrict__ Hbf,
                                              float* __restrict__ rbuf) {
    int b = blockIdx.x, t = threadIdx.x;
    __shared__ float sal[Tz];
    __shared__ float rA[2], rB[2];
    int len = lens[b];
    float s = (t < len) ? scores[b * Tz + t] : -1e9f;
    float m = s;
#pragma unroll
    for (int o = 32; o; o >>= 1) m = fmaxf(m, __shfl_xor(m, o, 64));
    if ((t & 63) == 0) rA[t >> 6] = m;
    __syncthreads();
    m = fmaxf(rA[0], rA[1]);
    float e = expf(s - m);
    float sum = e;
#pragma unroll
    for (int o = 32; o; o >>= 1) sum += __shfl_xor(sum, o, 64);
    if ((t & 63) == 0) rB[t >> 6] = sum;
    __syncthreads();
    sum = rB[0] + rB[1];
    sal[t] = e / sum;
    __syncthreads();
    if (t < 96) {
        const unsigned short* hp = Hbf + (long)b * Tz * DHz + t * 8;
        float acc[8] = {};
        for (int tt = 0; tt < Tz; ++tt) {
            short8 v = *(const short8*)(hp + (long)tt * DHz);
            float a = sal[tt];
            const unsigned short* pv = (const unsigned short*)&v;
#pragma unroll
            for (int e2 = 0; e2 < 8; ++e2) acc[e2] += a * bf2f(pv[e2]);
        }
        float* rp = rbuf + (long)b * DHz + t * 8;
#pragma unroll
        for (int e2 = 0; e2 < 8; ++e2) rp[e2] = acc[e2];
    }
}

// ---------- h_star = tanh([r | H_last] @ [Wp; Wx])  (bf16 MFMA, K=1536) ----------
__global__ __launch_bounds__(256) void k_hstar(const float* __restrict__ rbuf,
                                               const unsigned short* __restrict__ Hbf,
                                               const unsigned short* __restrict__ WbP,
                                               float* __restrict__ hst) {
    __shared__ unsigned short sA[128 * 40];
    __shared__ unsigned short sB[128 * 40];
    int tid = threadIdx.x;
    int n0 = blockIdx.x * 128;
    int m0 = blockIdx.y * 128;
    int wid = tid >> 6, lane = tid & 63, l15 = lane & 15, q = lane >> 4;
    int wm = wid >> 1, wn = wid & 1;
    int arow = tid >> 1;
    int kp = (tid & 1) * 16;
    int s0 = tid, s1 = tid + 256;
    int bd0 = (s0 >> 2) * 40 + (((s0 & 3) ^ (((s0 >> 2) >> 3) & 3)) << 3);
    int bd1 = (s1 >> 2) * 40 + (((s1 & 3) ^ (((s1 >> 2) >> 3) & 3)) << 3);

    f32x4 acc[4][4];
    f32x4 zz = {0.f, 0.f, 0.f, 0.f};
#pragma unroll
    for (int i = 0; i < 4; ++i)
#pragma unroll
        for (int j = 0; j < 4; ++j) acc[i][j] = zz;

    for (int k0 = 0; k0 < 2 * DHz; k0 += 32) {
        if (k0 < DHz) {
            const float* src = rbuf + (long)(m0 + arow) * DHz + k0 + kp;
            alignas(16) unsigned short tmp[16];
#pragma unroll
            for (int it = 0; it < 4; ++it) {
                float4 v = ((const float4*)src)[it];
                tmp[it * 4 + 0] = f2bf(v.x); tmp[it * 4 + 1] = f2bf(v.y);
                tmp[it * 4 + 2] = f2bf(v.z); tmp[it * 4 + 3] = f2bf(v.w);
            }
            *(int4*)(sA + arow * 40 + kp) = *(const int4*)tmp;
            *(int4*)(sA + arow * 40 + kp + 8) = *(const int4*)(tmp + 8);
        } else {
            const unsigned short* src = Hbf + ((long)(m0 + arow) * Tz + (Tz - 1)) * DHz
                                      + (k0 - DHz) + kp;
            *(int4*)(sA + arow * 40 + kp) = *(const int4*)src;
            *(int4*)(sA + arow * 40 + kp + 8) = *(const int4*)(src + 8);
        }
        {
            const int4* wsrc = (const int4*)WbP
                + ((long)((k0 >> 5) * 6 + (n0 >> 7))) * 512 + tid;
            int4 v0 = wsrc[0];
            int4 v1 = wsrc[256];
            *(int4*)(sB + bd0) = v0;
            *(int4*)(sB + bd1) = v1;
        }
        __syncthreads();
        short8 af[4], bfr[4];
#pragma unroll
        for (int i = 0; i < 4; ++i)
            af[i] = *(const short8*)(sA + (wm * 64 + i * 16 + l15) * 40 + q * 8);
#pragma unroll
        for (int j = 0; j < 4; ++j) {
            int n = wn * 64 + j * 16 + l15;
            bfr[j] = *(const short8*)(sB + n * 40 + ((q ^ ((n >> 3) & 3)) << 3));
        }
#pragma unroll
        for (int i = 0; i < 4; ++i)
#pragma unroll
            for (int j = 0; j < 4; ++j)
                acc[i][j] = __builtin_amdgcn_mfma_f32_16x16x32_bf16(af[i], bfr[j], acc[i][j], 0, 0, 0);
        __syncthreads();
    }
#pragma unroll
    for (int i = 0; i < 4; ++i)
#pragma unroll
        for (int j = 0; j < 4; ++j) {
            int col = n0 + wn * 64 + j * 16 + l15;
#pragma unroll
            for (int r = 0; r < 4; ++r) {
                int row = m0 + wm * 64 + i * 16 + q * 4 + r;
                hst[(long)row * DHz + col] = ftanh(acc[i][j][r]);
            }
        }
}

// ---------- logits ----------
__global__ void k_logits(const float* __restrict__ hst, const float* __restrict__ Wl,
                         const float* __restrict__ bl, float* __restrict__ out) {
    int b = blockIdx.x;
    int lane = threadIdx.x & 63, c = threadIdx.x >> 6;
    float s = 0.f;
    for (int k = lane; k < DHz; k += 64) s += hst[(long)b * DHz + k] * Wl[k * 3 + c];
#pragma unroll
    for (int o = 32; o; o >>= 1) s += __shfl_xor(s, o, 64);
    if (lane == 0) out[b * 3 + c] = s + bl[c];
}

extern "C" void kernel_launch(void* const* d_in, const int* in_sizes, int n_in,
                              void* d_out, int out_size, void* d_ws, size_t ws_size,
                              hipStream_t stream) {
    (void)in_sizes; (void)n_in; (void)out_size; (void)ws_size;
    const int*   sent   = (const int*)d_in[0];
    const int*   target = (const int*)d_in[1];
    const int*   lens   = (const int*)d_in[2];
    const float* emb    = (const float*)d_in[3];
    const float* temb   = (const float*)d_in[4];
    const float* W_ih   = (const float*)d_in[5];
    const float* W_hh   = (const float*)d_in[6];
    const float* b_lstm = (const float*)d_in[7];
    const float* Wh     = (const float*)d_in[8];
    const float* wv     = (const float*)d_in[10];
    const float* Wp     = (const float*)d_in[11];
    const float* Wx     = (const float*)d_in[12];
    const float* W_lin  = (const float*)d_in[13];
    const float* b_lin  = (const float*)d_in[14];
    float* out = (float*)d_out;

    char* ws = (char*)d_ws;
    size_t off = 0;
    auto alloc = [&](size_t bytes) -> void* {
        void* p = ws + off;
        off = (off + bytes + 255) & ~(size_t)255;
        return p;
    };
    unsigned short* xW    = (unsigned short*)alloc((size_t)32768 * G4z * 2);
    unsigned short* Hbf   = (unsigned short*)alloc((size_t)Bz * Tz * DHz * 2);
    unsigned short* WihbP = (unsigned short*)alloc((size_t)24 * 24 * 512 * 16);
    unsigned short* Wih2P = (unsigned short*)alloc((size_t)24 * 24 * 512 * 16);
    unsigned short* WhhP  = (unsigned short*)alloc((size_t)48 * 6144 * 16);
    unsigned short* WhbP  = (unsigned short*)alloc((size_t)24 * 6 * 512 * 16);
    unsigned short* WpxP  = (unsigned short*)alloc((size_t)48 * 6 * 512 * 16);
    float* constg = (float*)alloc((size_t)Bz * G4z * 4);
    float* cbuf   = (float*)alloc((size_t)Bz * DHz * 4);
    float* scores = (float*)alloc((size_t)Bz * Tz * 4);
    float* rbuf   = (float*)alloc((size_t)Bz * DHz * 4);
    float* hst    = (float*)alloc((size_t)Bz * DHz * 4);
    unsigned* bar = (unsigned*)alloc(65536);    // h flags: 8 groups x 48 x 128B
    unsigned* xwc = (unsigned*)alloc(16384);    // xW arrival counters: 128 x 128B

    k_prep_wswz<<<576, 256, 0, stream>>>(W_ih, WihbP, 24);                      // W_ih[:768]
    k_prep_wswz<<<576, 256, 0, stream>>>(W_ih + (size_t)DWz * G4z, Wih2P, 24);  // W_ih[768:]
    k_prep_wswz<<<144, 256, 0, stream>>>(Wh, WhbP, 6);
    k_prep_wswz<<<144, 256, 0, stream>>>(Wp, WpxP, 6);
    k_prep_wswz<<<144, 256, 0, stream>>>(Wx, WpxP + (size_t)144 * 512 * 8, 6);
    k_prep_whh<<<1152, 256, 0, stream>>>(W_hh, WhhP);
    hipMemsetAsync(scores, 0, (size_t)Bz * Tz * 4, stream);
    hipMemsetAsync(bar, 0, 65536, stream);
    hipMemsetAsync(xwc, 0, 16384, stream);

    k_gemm_cg<<<dim3(24, 2), 256, 0, stream>>>(target, temb, Wih2P, b_lstm, constg);

    hipFuncSetAttribute((const void*)k_lstm_all,
                        hipFuncAttributeMaxDynamicSharedMemorySize, 98304);
    int t0v = 0, t1v = Tz, waitv = 1, nprodv = NGRID - NBLK;
    unsigned short* xWp = xW;
    const float* cgp = constg;
    const unsigned short* whp = WhhP;
    unsigned short* hbp = Hbf;
    float* cbp = cbuf;
    const int* lnp = lens;
    unsigned* barp = bar;
    unsigned* xwcp = xwc;
    const float* embp = emb;
    const int* sentp = sent;
    const unsigned short* wihp = WihbP;
    void* kargs[] = {&t0v, &t1v, &xWp, &cgp, &whp, &hbp, &cbp, &lnp, &barp,
                     &xwcp, &waitv, &embp, &sentp, &wihp, &nprodv};
    hipError_t ce = hipLaunchCooperativeKernel(reinterpret_cast<void*>(k_lstm_all),
                                               dim3(NGRID), dim3(256), kargs, 98304, stream);
    if (ce != hipSuccess) {
        // fallback: serial gemm_x (kernel boundary = coherent) + per-step LSTM
        k_gemm_x<<<dim3(24, 256), 256, 0, stream>>>(emb, sent, WihbP, xW);
        for (int t = 0; t < Tz; ++t)
            k_lstm_all<<<NBLK, 256, 98304, stream>>>(t, t + 1, xW, constg, WhhP, Hbf,
                                                     cbuf, lens, bar, xwc, 0,
                                                     emb, sent, WihbP, 0);
    }

    k_scores<<<dim3(6, 256), 256, 0, stream>>>(Hbf, WhbP, wv, scores);
    k_attn<<<Bz, 128, 0, stream>>>(scores, lens, Hbf, rbuf);
    k_hstar<<<dim3(6, 2), 256, 0, stream>>>(rbuf, Hbf, WpxP, hst);
    k_logits<<<Bz, 192, 0, stream>>>(hst, W_lin, b_lin, out);
}

// Round 10
// 1858.430 us; speedup vs baseline: 1.5268x; 1.0272x over previous
//
#include <hip/hip_runtime.h>
#include <stdint.h>

#define Bz 256
#define Tz 128
#define DWz 768
#define DHz 768
#define G4z 3072
#define NBLK 96
#define NGRID 256

typedef __attribute__((ext_vector_type(8))) short short8;
typedef __attribute__((ext_vector_type(4))) float f32x4;
typedef __attribute__((ext_vector_type(4))) int i32x4;

__device__ __forceinline__ unsigned short f2bf(float x) {
    union { float f; unsigned int u; } v; v.f = x;
    unsigned int u = v.u;
    return (unsigned short)((u + 0x7fffu + ((u >> 16) & 1u)) >> 16);
}
__device__ __forceinline__ float bf2f(unsigned short h) {
    union { unsigned int u; float f; } v; v.u = ((unsigned int)h) << 16;
    return v.f;
}
// fast transcendentals: v_exp_f32 + v_rcp_f32 (1-ulp class, fine vs bf16 floor)
__device__ __forceinline__ float fsigm(float x) {
    return __builtin_amdgcn_rcpf(1.0f + __builtin_amdgcn_exp2f(x * -1.4426950408889634f));
}
__device__ __forceinline__ float ftanh(float x) {
    x = fminf(fmaxf(x, -15.0f), 15.0f);           // keep e finite: no inf -> NaN
    float e = __builtin_amdgcn_exp2f(x * -2.8853900817779268f);
    return (1.0f - e) * __builtin_amdgcn_rcpf(1.0f + e);
}

// ---------- all weight pre-swizzles in ONE launch (block-range dispatch) ----------
// W (KxN fp32, N = NT*128) -> 16B chunks: chunk s = n*4+kq of tile (kt,nt) holds
// bf16 W[kt*32+kq*8+e][nt*128+n]. Consumers stage B as 2x{int4 load + int4 ds_write}.
__global__ __launch_bounds__(256) void k_prep_all(const float* __restrict__ W_ih,
                                                  const float* __restrict__ Wh,
                                                  const float* __restrict__ Wp,
                                                  const float* __restrict__ Wx,
                                                  unsigned short* __restrict__ WihbP,
                                                  unsigned short* __restrict__ Wih2P,
                                                  unsigned short* __restrict__ WhbP,
                                                  unsigned short* __restrict__ WpxP) {
    __shared__ float sT[32][132];
    int bid = blockIdx.x;
    const float* W; unsigned short* out; int NT, rb;
    if (bid < 576)       { W = W_ih;                        out = WihbP; NT = 24; rb = bid; }
    else if (bid < 1152) { W = W_ih + (size_t)DWz * G4z;    out = Wih2P; NT = 24; rb = bid - 576; }
    else if (bid < 1296) { W = Wh;                          out = WhbP;  NT = 6;  rb = bid - 1152; }
    else if (bid < 1440) { W = Wp;                          out = WpxP;  NT = 6;  rb = bid - 1296; }
    else                 { W = Wx; out = WpxP + (size_t)144 * 512 * 8;   NT = 6;  rb = bid - 1440; }
    int kt = rb / NT, nt = rb - kt * NT;
    int tid = threadIdx.x;
    int ldn = NT * 128;
    {
        int r = tid >> 3;
        int cb = (tid & 7) * 16;
        const float* src = W + (long)(kt * 32 + r) * ldn + nt * 128 + cb;
#pragma unroll
        for (int u = 0; u < 4; ++u) {
            float4 v = ((const float4*)src)[u];
            sT[r][cb + u * 4 + 0] = v.x; sT[r][cb + u * 4 + 1] = v.y;
            sT[r][cb + u * 4 + 2] = v.z; sT[r][cb + u * 4 + 3] = v.w;
        }
    }
    __syncthreads();
#pragma unroll
    for (int it = 0; it < 2; ++it) {
        int s = tid + it * 256;
        int n = s >> 2, kq = s & 3;
        alignas(16) unsigned short o[8];
#pragma unroll
        for (int e = 0; e < 8; ++e) o[e] = f2bf(sT[kq * 8 + e][n]);
        *(int4*)(out + ((long)rb * 512 + s) * 8) = *(const int4*)o;
    }
}

// ---------- Whh -> pre-swizzled bf16 blobs (coalesced reads via LDS transpose) ----
__global__ __launch_bounds__(256) void k_prep_whh(const float* __restrict__ Whh,
                                                  unsigned short* __restrict__ WhhP) {
    __shared__ float sT[32][65];
    int bid = blockIdx.x;            // [0, 1152)
    int dblk = bid / 24;
    int k0c = bid - dblk * 24;
    int tid = threadIdx.x;
    {
        int kk = tid >> 3;
        int seg = tid & 7;
        const float* src = Whh + (long)(k0c * 32 + kk) * G4z
                         + (seg >> 1) * 768 + dblk * 16 + (seg & 1) * 8;
        float4 v0 = *(const float4*)src;
        float4 v1 = *(const float4*)(src + 4);
        int cl = seg * 8;
        sT[kk][cl + 0] = v0.x; sT[kk][cl + 1] = v0.y; sT[kk][cl + 2] = v0.z; sT[kk][cl + 3] = v0.w;
        sT[kk][cl + 4] = v1.x; sT[kk][cl + 5] = v1.y; sT[kk][cl + 6] = v1.z; sT[kk][cl + 7] = v1.w;
    }
    __syncthreads();
    {
        int nl = tid >> 2, cc = tid & 3;
        int q8 = cc ^ ((nl >> 1) & 3);
        int clv = (nl >> 4) * 16 + (nl & 15);
        alignas(16) unsigned short o[8];
#pragma unroll
        for (int e = 0; e < 8; ++e) o[e] = f2bf(sT[q8 * 8 + e][clv]);
        *(int4*)(WhhP + (long)(dblk * 6144 + k0c * 256 + tid) * 8) = *(const int4*)o;
    }
}

// ---------- constg = temb[target] @ W_ih[768:] + b_lstm  (bf16 MFMA) ----------
__global__ __launch_bounds__(256) void k_gemm_cg(const int* __restrict__ target,
                                                 const float* __restrict__ temb,
                                                 const unsigned short* __restrict__ WbP,
                                                 const float* __restrict__ bias,
                                                 float* __restrict__ C) {
    __shared__ unsigned short sA[128 * 40];
    __shared__ unsigned short sB[128 * 40];
    int tid = threadIdx.x;
    int n0 = blockIdx.x * 128;
    int m0 = blockIdx.y * 128;
    int wid = tid >> 6, lane = tid & 63, l15 = lane & 15, q = lane >> 4;
    int wm = wid >> 1, wn = wid & 1;
    int arow = tid >> 1;
    int kp = (tid & 1) * 16;
    long gbase = (long)target[m0 + arow] * DWz;
    int s0 = tid, s1 = tid + 256;
    int bd0 = (s0 >> 2) * 40 + (((s0 & 3) ^ (((s0 >> 2) >> 3) & 3)) << 3);
    int bd1 = (s1 >> 2) * 40 + (((s1 & 3) ^ (((s1 >> 2) >> 3) & 3)) << 3);

    f32x4 acc[4][4];
    f32x4 zz = {0.f, 0.f, 0.f, 0.f};
#pragma unroll
    for (int i = 0; i < 4; ++i)
#pragma unroll
        for (int j = 0; j < 4; ++j) acc[i][j] = zz;

    for (int k0 = 0; k0 < DWz; k0 += 32) {
        {
            const float* src = temb + gbase + k0 + kp;
            alignas(16) unsigned short tmp[16];
#pragma unroll
            for (int it = 0; it < 4; ++it) {
                float4 v = ((const float4*)src)[it];
                tmp[it * 4 + 0] = f2bf(v.x); tmp[it * 4 + 1] = f2bf(v.y);
                tmp[it * 4 + 2] = f2bf(v.z); tmp[it * 4 + 3] = f2bf(v.w);
            }
            *(int4*)(sA + arow * 40 + kp) = *(const int4*)tmp;
            *(int4*)(sA + arow * 40 + kp + 8) = *(const int4*)(tmp + 8);
        }
        {
            const int4* wsrc = (const int4*)WbP
                + ((long)((k0 >> 5) * 24 + (n0 >> 7))) * 512 + tid;
            int4 v0 = wsrc[0];
            int4 v1 = wsrc[256];
            *(int4*)(sB + bd0) = v0;
            *(int4*)(sB + bd1) = v1;
        }
        __syncthreads();
        short8 af[4], bfr[4];
#pragma unroll
        for (int i = 0; i < 4; ++i)
            af[i] = *(const short8*)(sA + (wm * 64 + i * 16 + l15) * 40 + q * 8);
#pragma unroll
        for (int j = 0; j < 4; ++j) {
            int n = wn * 64 + j * 16 + l15;
            bfr[j] = *(const short8*)(sB + n * 40 + ((q ^ ((n >> 3) & 3)) << 3));
        }
#pragma unroll
        for (int i = 0; i < 4; ++i)
#pragma unroll
            for (int j = 0; j < 4; ++j)
                acc[i][j] = __builtin_amdgcn_mfma_f32_16x16x32_bf16(af[i], bfr[j], acc[i][j], 0, 0, 0);
        __syncthreads();
    }
#pragma unroll
    for (int i = 0; i < 4; ++i)
#pragma unroll
        for (int j = 0; j < 4; ++j) {
            int col = n0 + wn * 64 + j * 16 + l15;
            float bv = bias[col];
#pragma unroll
            for (int r = 0; r < 4; ++r) {
                int row = m0 + wm * 64 + i * 16 + q * 4 + r;
                C[(long)row * G4z + col] = acc[i][j][r] + bv;
            }
        }
}

// ---------- standalone xW GEMM (fallback path only; kernel boundary = coherent) ----
__global__ __launch_bounds__(256) void k_gemm_x(const float* __restrict__ emb,
                                                const int* __restrict__ sent,
                                                const unsigned short* __restrict__ WbP,
                                                unsigned short* __restrict__ xW) {
    __shared__ unsigned short sA[128 * 40];
    __shared__ unsigned short sB[128 * 40];
    int tid = threadIdx.x;
    int n0 = blockIdx.x * 128;
    int m0 = blockIdx.y * 128;
    int wid = tid >> 6, lane = tid & 63, l15 = lane & 15, q = lane >> 4;
    int wm = wid >> 1, wn = wid & 1;
    int arow = tid >> 1;
    int kp = (tid & 1) * 16;
    int m = m0 + arow;
    int tt = m >> 8;
    int bb = m & 255;
    long gbase = (long)sent[bb * Tz + tt] * DWz;
    int s0 = tid, s1 = tid + 256;
    int bd0 = (s0 >> 2) * 40 + (((s0 & 3) ^ (((s0 >> 2) >> 3) & 3)) << 3);
    int bd1 = (s1 >> 2) * 40 + (((s1 & 3) ^ (((s1 >> 2) >> 3) & 3)) << 3);

    f32x4 acc[4][4];
    f32x4 zz = {0.f, 0.f, 0.f, 0.f};
#pragma unroll
    for (int i = 0; i < 4; ++i)
#pragma unroll
        for (int j = 0; j < 4; ++j) acc[i][j] = zz;

    for (int k0 = 0; k0 < DWz; k0 += 32) {
        {
            const float* src = emb + gbase + k0 + kp;
            alignas(16) unsigned short tmp[16];
#pragma unroll
            for (int it = 0; it < 4; ++it) {
                float4 v = ((const float4*)src)[it];
                tmp[it * 4 + 0] = f2bf(v.x); tmp[it * 4 + 1] = f2bf(v.y);
                tmp[it * 4 + 2] = f2bf(v.z); tmp[it * 4 + 3] = f2bf(v.w);
            }
            *(int4*)(sA + arow * 40 + kp) = *(const int4*)tmp;
            *(int4*)(sA + arow * 40 + kp + 8) = *(const int4*)(tmp + 8);
        }
        {
            const int4* wsrc = (const int4*)WbP
                + ((long)((k0 >> 5) * 24 + (n0 >> 7))) * 512 + tid;
            int4 v0 = wsrc[0];
            int4 v1 = wsrc[256];
            *(int4*)(sB + bd0) = v0;
            *(int4*)(sB + bd1) = v1;
        }
        __syncthreads();
        short8 af[4], bfr[4];
#pragma unroll
        for (int i = 0; i < 4; ++i)
            af[i] = *(const short8*)(sA + (wm * 64 + i * 16 + l15) * 40 + q * 8);
#pragma unroll
        for (int j = 0; j < 4; ++j) {
            int n = wn * 64 + j * 16 + l15;
            bfr[j] = *(const short8*)(sB + n * 40 + ((q ^ ((n >> 3) & 3)) << 3));
        }
#pragma unroll
        for (int i = 0; i < 4; ++i)
#pragma unroll
            for (int j = 0; j < 4; ++j)
                acc[i][j] = __builtin_amdgcn_mfma_f32_16x16x32_bf16(af[i], bfr[j], acc[i][j], 0, 0, 0);
        __syncthreads();
    }
#pragma unroll
    for (int j = 0; j < 4; ++j) {
        int n = n0 + wn * 64 + j * 16 + l15;
        int gt = n / 768;
        int dblk = (n - gt * 768) >> 4;
#pragma unroll
        for (int ip = 0; ip < 2; ++ip) {
            int row = m0 + wm * 64 + ip * 32;
            int t = row >> 8;
            int bq = (row & 255) + q * 4;
            int blk = dblk * 2 + (bq >> 7);
            int tidd = ((bq & 127) >> 5) * 64 + q * 16 + l15;
            alignas(16) unsigned short o[8];
#pragma unroll
            for (int r = 0; r < 4; ++r) {
                o[r]     = f2bf(acc[ip * 2][j][r]);
                o[4 + r] = f2bf(acc[ip * 2 + 1][j][r]);
            }
            *(int4*)(xW + (((long)t * 96 + blk) * 4 + gt) * 2048 + (long)tidd * 8) = *(const int4*)o;
        }
    }
}

// ---------- fused persistent kernel ----------
// Blocks 0..95: LSTM (round-3 wave-dataflow, UNCHANGED except post-loop flag=t1
// publish). Blocks 96..255: (a) xW tiles in t-order, agent write-through +
// per-t arrival counters; (b) after xW, SCORE tiles: for step t compute
// scores[b,t] += w.tanh(h(t)@Wh) gated on the bm-group's h-flags >= t+1
// (producers lag the LSTM frontier, so polls mostly pass; long-sleep backoff
// keeps flag-line traffic negligible). This hides k_scores' serial time inside
// the producers' ~1ms idle tail.
#define UNPACK(PF, G)                                                        \
    {                                                                        \
        const unsigned short* ch_ = (const unsigned short*)&(PF);            \
        _Pragma("unroll")                                                    \
        for (int i_ = 0; i_ < 2; ++i_)                                       \
            _Pragma("unroll")                                                \
            for (int r_ = 0; r_ < 4; ++r_)                                   \
                xg[i_][G][r_] = bf2f(ch_[i_ * 4 + r_]) + xgc[i_][G][r_];     \
    }

__global__ __launch_bounds__(256, 1) void k_lstm_all(int t0, int t1,
        unsigned short* __restrict__ xW, const float* __restrict__ constg,
        const unsigned short* __restrict__ WhhP, unsigned short* __restrict__ Hbf,
        float* __restrict__ cbuf, const int* __restrict__ lens,
        unsigned* __restrict__ bar, unsigned* __restrict__ xwcnt, int waitxw,
        const float* __restrict__ emb, const int* __restrict__ sent,
        const unsigned short* __restrict__ WihbP, int nprod,
        const unsigned short* __restrict__ WhbP, const float* __restrict__ wv,
        float* __restrict__ scores) {
    extern __shared__ unsigned short sB[];   // 96 KB dynamic
    int bid = blockIdx.x;
    int tid = threadIdx.x;
    int lane = tid & 63, wid = tid >> 6;
    int l15 = lane & 15, q = lane >> 4;

    if (bid >= NBLK) {
        // ---------------- producer ----------------
        unsigned short* psA = sB;
        unsigned short* psB = sB + 5120;
        float* sred = (float*)(sB + 10240);
        int wm = wid >> 1, wn = wid & 1;
        int arow = tid >> 1;
        int kp = (tid & 1) * 16;
        int s0 = tid, s1 = tid + 256;
        int bd0 = (s0 >> 2) * 40 + (((s0 & 3) ^ (((s0 >> 2) >> 3) & 3)) << 3);
        int bd1 = (s1 >> 2) * 40 + (((s1 & 3) ^ (((s1 >> 2) >> 3) & 3)) << 3);

        // ---- phase (a): xW tiles ----
        for (int g = bid - NBLK; g < 6144; g += nprod) {
            int my = g / 24, nx = g - (g / 24) * 24;
            int m0 = my * 128, n0 = nx * 128;
            int m = m0 + arow;
            int tt = m >> 8, bb2 = m & 255;
            long gbase = (long)sent[bb2 * Tz + tt] * DWz;

            f32x4 acc[4][4];
            f32x4 zz = {0.f, 0.f, 0.f, 0.f};
#pragma unroll
            for (int i = 0; i < 4; ++i)
#pragma unroll
                for (int j = 0; j < 4; ++j) acc[i][j] = zz;

            for (int k0 = 0; k0 < DWz; k0 += 32) {
                {
                    const float* src = emb + gbase + k0 + kp;
                    alignas(16) unsigned short tmp[16];
#pragma unroll
                    for (int it = 0; it < 4; ++it) {
                        float4 v = ((const float4*)src)[it];
                        tmp[it * 4 + 0] = f2bf(v.x); tmp[it * 4 + 1] = f2bf(v.y);
                        tmp[it * 4 + 2] = f2bf(v.z); tmp[it * 4 + 3] = f2bf(v.w);
                    }
                    *(int4*)(psA + arow * 40 + kp) = *(const int4*)tmp;
                    *(int4*)(psA + arow * 40 + kp + 8) = *(const int4*)(tmp + 8);
                }
                {
                    const int4* wsrc = (const int4*)WihbP
                        + ((long)((k0 >> 5) * 24 + (n0 >> 7))) * 512 + tid;
                    int4 v0 = wsrc[0];
                    int4 v1 = wsrc[256];
                    *(int4*)(psB + bd0) = v0;
                    *(int4*)(psB + bd1) = v1;
                }
                __syncthreads();
                short8 af[4], bfr[4];
#pragma unroll
                for (int i = 0; i < 4; ++i)
                    af[i] = *(const short8*)(psA + (wm * 64 + i * 16 + l15) * 40 + q * 8);
#pragma unroll
                for (int j = 0; j < 4; ++j) {
                    int n = wn * 64 + j * 16 + l15;
                    bfr[j] = *(const short8*)(psB + n * 40 + ((q ^ ((n >> 3) & 3)) << 3));
                }
#pragma unroll
                for (int i = 0; i < 4; ++i)
#pragma unroll
                    for (int j = 0; j < 4; ++j)
                        acc[i][j] = __builtin_amdgcn_mfma_f32_16x16x32_bf16(af[i], bfr[j], acc[i][j], 0, 0, 0);
                __syncthreads();
            }
#pragma unroll
            for (int j = 0; j < 4; ++j) {
                int n = n0 + wn * 64 + j * 16 + l15;
                int gt = n / 768;
                int dblk2 = (n - gt * 768) >> 4;
#pragma unroll
                for (int ip = 0; ip < 2; ++ip) {
                    int row = m0 + wm * 64 + ip * 32;
                    int t = row >> 8;
                    int bq = (row & 255) + q * 4;
                    int blk = dblk2 * 2 + (bq >> 7);
                    int tidd = ((bq & 127) >> 5) * 64 + q * 16 + l15;
                    alignas(16) unsigned short o[8];
#pragma unroll
                    for (int r = 0; r < 4; ++r) {
                        o[r]     = f2bf(acc[ip * 2][j][r]);
                        o[4 + r] = f2bf(acc[ip * 2 + 1][j][r]);
                    }
                    unsigned long long* dst = (unsigned long long*)
                        (xW + (((long)t * 96 + blk) * 4 + gt) * 2048 + (long)tidd * 8);
                    const unsigned long long* po = (const unsigned long long*)o;
                    __hip_atomic_store(dst, po[0], __ATOMIC_RELAXED, __HIP_MEMORY_SCOPE_AGENT);
                    __hip_atomic_store(dst + 1, po[1], __ATOMIC_RELAXED, __HIP_MEMORY_SCOPE_AGENT);
                }
            }
            asm volatile("s_waitcnt vmcnt(0)" ::: "memory");
            __syncthreads();
            if (tid == 0)
                (void)__hip_atomic_fetch_add(&xwcnt[(my >> 1) * 32], 1u,
                                             __ATOMIC_RELAXED, __HIP_MEMORY_SCOPE_AGENT);
        }

        // ---- phase (b): score tiles (12 per t: 2 m-tiles x 6 n-tiles) ----
        for (int s2 = bid - NBLK; s2 < 1536; s2 += nprod) {
            int t = s2 / 12;
            int rr = s2 - t * 12;
            int mt = rr / 6, nt2 = rr - (rr / 6) * 6;
            int m0 = mt * 128, n0 = nt2 * 128;
            unsigned tgt = (unsigned)(t + 1);
            {   // wave wid confirms flag group (mt, wid); barrier joins all 4
                const unsigned* fp2 = bar + (((mt * 4 + wid) * 48) + lane) * 32;
                while (true) {
                    unsigned v = (lane < 48)
                        ? __hip_atomic_load(fp2, __ATOMIC_RELAXED, __HIP_MEMORY_SCOPE_AGENT)
                        : tgt;
                    if (__all(v >= tgt)) break;
                    __builtin_amdgcn_s_sleep(8);
                }
            }
            __syncthreads();

            f32x4 acc[4][4];
            f32x4 zz = {0.f, 0.f, 0.f, 0.f};
#pragma unroll
            for (int i = 0; i < 4; ++i)
#pragma unroll
                for (int j = 0; j < 4; ++j) acc[i][j] = zz;

            for (int k0 = 0; k0 < DHz; k0 += 32) {
                {   // A: h(t) rows (plain loads; first-touch after flag)
                    const unsigned short* asrc = Hbf
                        + ((long)(m0 + arow) * Tz + t) * DHz + k0 + kp;
                    *(int4*)(psA + arow * 40 + kp) = *(const int4*)asrc;
                    *(int4*)(psA + arow * 40 + kp + 8) = *(const int4*)(asrc + 8);
                }
                {
                    const int4* wsrc = (const int4*)WhbP
                        + ((long)((k0 >> 5) * 6 + nt2)) * 512 + tid;
                    int4 v0 = wsrc[0];
                    int4 v1 = wsrc[256];
                    *(int4*)(psB + bd0) = v0;
                    *(int4*)(psB + bd1) = v1;
                }
                __syncthreads();
                short8 af[4], bfr[4];
#pragma unroll
                for (int i = 0; i < 4; ++i)
                    af[i] = *(const short8*)(psA + (wm * 64 + i * 16 + l15) * 40 + q * 8);
#pragma unroll
                for (int j = 0; j < 4; ++j) {
                    int n = wn * 64 + j * 16 + l15;
                    bfr[j] = *(const short8*)(psB + n * 40 + ((q ^ ((n >> 3) & 3)) << 3));
                }
#pragma unroll
                for (int i = 0; i < 4; ++i)
#pragma unroll
                    for (int j = 0; j < 4; ++j)
                        acc[i][j] = __builtin_amdgcn_mfma_f32_16x16x32_bf16(af[i], bfr[j], acc[i][j], 0, 0, 0);
                __syncthreads();
            }
            if (tid < 128) sred[tid] = 0.f;
            __syncthreads();
#pragma unroll
            for (int i = 0; i < 4; ++i)
#pragma unroll
                for (int r = 0; r < 4; ++r) {
                    float sv = 0.f;
#pragma unroll
                    for (int j = 0; j < 4; ++j) {
                        int n = n0 + wn * 64 + j * 16 + l15;
                        sv += ftanh(acc[i][j][r]) * wv[n];
                    }
#pragma unroll
                    for (int o = 1; o < 16; o <<= 1) sv += __shfl_xor(sv, o, 64);
                    if (l15 == 0) atomicAdd(&sred[wm * 64 + i * 16 + q * 4 + r], sv);
                }
            __syncthreads();
            if (tid < 128)
                atomicAdd(&scores[(long)(m0 + tid) * Tz + t], sred[tid]);
        }
        return;
    }

    // ---------------- consumer: LSTM ----------------
    int bm = bid & 1;
    int dblk = bid >> 1;
    int d0 = dblk * 16;
    int d = d0 + l15;
    unsigned* flg = bar + ((bm * 4 + wid) * 48) * 32;

    {   // stage pre-swizzled Whh once
        const int4* src = (const int4*)WhhP + (long)dblk * 6144;
        for (int s = tid; s < 6144; s += 256) ((int4*)sB)[s] = src[s];
    }

    int brow[8];
    int lenr[8];
    float c[8], h[8];
    float xgc[2][4][4];
#pragma unroll
    for (int i = 0; i < 2; ++i)
#pragma unroll
        for (int r = 0; r < 4; ++r) {
            int ir = i * 4 + r;
            int b = bm * 128 + wid * 32 + i * 16 + q * 4 + r;
            brow[ir] = b;
            lenr[ir] = lens[b];
            long cbase = (long)b * G4z + d;
#pragma unroll
            for (int j = 0; j < 4; ++j) xgc[i][j][r] = constg[cbase + j * 768];
            if (t0 > 0) {
                c[ir] = cbuf[(long)b * DHz + d];
                h[ir] = bf2f(Hbf[((long)b * Tz + (t0 - 1)) * DHz + d]);
            } else { c[ir] = 0.f; h[ir] = 0.f; }
        }

    int bbase[4];
#pragma unroll
    for (int j = 0; j < 4; ++j) {
        int nl = j * 16 + l15;
        bbase[j] = nl * 32 + ((q ^ ((nl >> 1) & 3)) << 3);
    }
    __syncthreads();

    if (waitxw) {
        const unsigned* xc = xwcnt + t0 * 32;
        if (lane == 0)
            while (__hip_atomic_load(xc, __ATOMIC_RELAXED, __HIP_MEMORY_SCOPE_AGENT) < 48u)
                __builtin_amdgcn_s_sleep(1);
        asm volatile("" ::: "memory");
    }
    float xg[2][4][4];
    {
        const unsigned short* x0 = xW + ((long)t0 * 96 + bid) * 8192 + (long)tid * 8;
        int4 c0 = *(const int4*)(x0);
        int4 c1 = *(const int4*)(x0 + 2048);
        int4 c2 = *(const int4*)(x0 + 4096);
        int4 c3 = *(const int4*)(x0 + 6144);
        UNPACK(c0, 0) UNPACK(c1, 1) UNPACK(c2, 2) UNPACK(c3, 3)
    }

    i32x4 pf0, pf1, pf2, pf3;

    for (int t = t0; t < t1; ++t) {
        if (t > t0) {
            unsigned tgt = (unsigned)t;
            const unsigned* fp = flg + lane * 32;
            while (true) {
                unsigned v = (lane < 48)
                    ? __hip_atomic_load(fp, __ATOMIC_RELAXED, __HIP_MEMORY_SCOPE_AGENT)
                    : tgt;
                if (__all(v >= tgt)) break;
                __builtin_amdgcn_s_sleep(1);
            }
            asm volatile("s_waitcnt vmcnt(0)" ::: "memory");
            __builtin_amdgcn_sched_barrier(0);
            UNPACK(pf0, 0) UNPACK(pf1, 1) UNPACK(pf2, 2) UNPACK(pf3, 3)
        }

        f32x4 acc[2][4];
        f32x4 zz = {0.f, 0.f, 0.f, 0.f};
#pragma unroll
        for (int i = 0; i < 2; ++i)
#pragma unroll
            for (int j = 0; j < 4; ++j) acc[i][j] = zz;

        if (t > 0) {
            const unsigned short* ap0 = Hbf + ((long)(bm * 128 + wid * 32 + l15) * Tz + (t - 1)) * DHz + q * 8;
            const unsigned short* ap1 = ap0 + (long)16 * Tz * DHz;
#pragma unroll 6
            for (int k0c = 0; k0c < 24; ++k0c) {
                short8 a0 = *(const short8*)(ap0 + k0c * 32);
                short8 a1 = *(const short8*)(ap1 + k0c * 32);
                const unsigned short* bb = sB + k0c * 2048;
#pragma unroll
                for (int j = 0; j < 4; ++j) {
                    short8 bf = *(const short8*)(bb + bbase[j]);
                    acc[0][j] = __builtin_amdgcn_mfma_f32_16x16x32_bf16(a0, bf, acc[0][j], 0, 0, 0);
                    acc[1][j] = __builtin_amdgcn_mfma_f32_16x16x32_bf16(a1, bf, acc[1][j], 0, 0, 0);
                }
            }
        }

#pragma unroll
        for (int i = 0; i < 2; ++i)
#pragma unroll
            for (int r = 0; r < 4; ++r) {
                int ir = i * 4 + r;
                float gi = acc[i][0][r] + xg[i][0][r];
                float gf = acc[i][1][r] + xg[i][1][r];
                float gg = acc[i][2][r] + xg[i][2][r];
                float go = acc[i][3][r] + xg[i][3][r];
                float cn = fsigm(gf) * c[ir] + fsigm(gi) * ftanh(gg);
                float hn = fsigm(go) * ftanh(cn);
                bool upd = t < lenr[ir];
                c[ir] = upd ? cn : c[ir];
                h[ir] = upd ? hn : h[ir];
                __hip_atomic_store(Hbf + ((long)brow[ir] * Tz + t) * DHz + d, f2bf(h[ir]),
                                   __ATOMIC_RELAXED, __HIP_MEMORY_SCOPE_AGENT);
            }

        if (t + 1 < t1) {
            if (waitxw) {
                const unsigned* xc = xwcnt + (t + 1) * 32;
                if (lane == 0)
                    while (__hip_atomic_load(xc, __ATOMIC_RELAXED, __HIP_MEMORY_SCOPE_AGENT) < 48u)
                        __builtin_amdgcn_s_sleep(1);
                asm volatile("" ::: "memory");
            }
            const unsigned short* pp = xW + ((long)(t + 1) * 96 + bid) * 8192 + (long)tid * 8;
            asm volatile(
                "global_load_dwordx4 %0, %4, off\n\t"
                "global_load_dwordx4 %1, %5, off\n\t"
                "global_load_dwordx4 %2, %6, off\n\t"
                "global_load_dwordx4 %3, %7, off"
                : "=&v"(pf0), "=&v"(pf1), "=&v"(pf2), "=&v"(pf3)
                : "v"(pp), "v"(pp + 2048), "v"(pp + 4096), "v"(pp + 6144)
                : "memory");
            asm volatile("s_waitcnt vmcnt(4)" ::: "memory");
            if (lane == 0)
                __hip_atomic_store(flg + dblk * 32, (unsigned)(t + 1),
                                   __ATOMIC_RELAXED, __HIP_MEMORY_SCOPE_AGENT);
        }
    }
    // publish final-step completion (flag = t1) so producer score tiles for
    // t = t1-1 can proceed
    asm volatile("s_waitcnt vmcnt(0)" ::: "memory");
    if (lane == 0)
        __hip_atomic_store(flg + dblk * 32, (unsigned)t1,
                           __ATOMIC_RELAXED, __HIP_MEMORY_SCOPE_AGENT);
#pragma unroll
    for (int ir = 0; ir < 8; ++ir) cbuf[(long)brow[ir] * DHz + d] = c[ir];
}

// ---------- scores (fallback path only) ----------
__global__ __launch_bounds__(256) void k_scores(const unsigned short* __restrict__ Hbf,
                                                const unsigned short* __restrict__ WbP,
                                                const float* __restrict__ wv,
                                                float* __restrict__ scores) {
    __shared__ unsigned short sA[128 * 40];
    __shared__ unsigned short sB[128 * 40];
    __shared__ float sred[128];
    int tid = threadIdx.x;
    int n0 = blockIdx.x * 128;
    int m0 = blockIdx.y * 128;
    int wid = tid >> 6, lane = tid & 63, l15 = lane & 15, q = lane >> 4;
    int wm = wid >> 1, wn = wid & 1;

    int s0 = tid, s1 = tid + 256;
    int bd0 = (s0 >> 2) * 40 + (((s0 & 3) ^ (((s0 >> 2) >> 3) & 3)) << 3);
    int bd1 = (s1 >> 2) * 40 + (((s1 & 3) ^ (((s1 >> 2) >> 3) & 3)) << 3);

    f32x4 acc[4][4];
    f32x4 zz = {0.f, 0.f, 0.f, 0.f};
#pragma unroll
    for (int i = 0; i < 4; ++i)
#pragma unroll
        for (int j = 0; j < 4; ++j) acc[i][j] = zz;

    int arow = tid >> 1;
    int kp = (tid & 1) * 16;
    const unsigned short* asrc = Hbf + (long)(m0 + arow) * DHz;

    for (int k0 = 0; k0 < DHz; k0 += 32) {
        *(int4*)(sA + arow * 40 + kp) = *(const int4*)(asrc + k0 + kp);
        *(int4*)(sA + arow * 40 + kp + 8) = *(const int4*)(asrc + k0 + kp + 8);
        {
            const int4* wsrc = (const int4*)WbP
                + ((long)((k0 >> 5) * 6 + (n0 >> 7))) * 512 + tid;
            int4 v0 = wsrc[0];
            int4 v1 = wsrc[256];
            *(int4*)(sB + bd0) = v0;
            *(int4*)(sB + bd1) = v1;
        }
        __syncthreads();
        short8 af[4], bfr[4];
#pragma unroll
        for (int i = 0; i < 4; ++i)
            af[i] = *(const short8*)(sA + (wm * 64 + i * 16 + l15) * 40 + q * 8);
#pragma unroll
        for (int j = 0; j < 4; ++j) {
            int n = wn * 64 + j * 16 + l15;
            bfr[j] = *(const short8*)(sB + n * 40 + ((q ^ ((n >> 3) & 3)) << 3));
        }
#pragma unroll
        for (int i = 0; i < 4; ++i)
#pragma unroll
            for (int j = 0; j < 4; ++j)
                acc[i][j] = __builtin_amdgcn_mfma_f32_16x16x32_bf16(af[i], bfr[j], acc[i][j], 0, 0, 0);
        __syncthreads();
    }
    if (tid < 128) sred[tid] = 0.f;
    __syncthreads();
#pragma unroll
    for (int i = 0; i < 4; ++i)
#pragma unroll
        for (int r = 0; r < 4; ++r) {
            float sv = 0.f;
#pragma unroll
            for (int j = 0; j < 4; ++j) {
                int n = n0 + wn * 64 + j * 16 + l15;
                sv += ftanh(acc[i][j][r]) * wv[n];
            }
#pragma unroll
            for (int o = 1; o < 16; o <<= 1) sv += __shfl_xor(sv, o, 64);
            if (l15 == 0) atomicAdd(&sred[wm * 64 + i * 16 + q * 4 + r], sv);
        }
    __syncthreads();
    if (tid < 128) atomicAdd(&scores[m0 + tid], sred[tid]);
}

// ---------- fused masked softmax + r = alpha @ H (per-b block) ----------
__global__ __launch_bounds__(128) void k_attn(const float* __restrict__ scores,
                                              const int* __restrict__ lens,
                                              const unsigned short* __restrict__ Hbf,
                                              float* __restrict__ rbuf) {
    int b = blockIdx.x, t = threadIdx.x;
    __shared__ float sal[Tz];
    __shared__ float rA[2], rB[2];
    int len = lens[b];
    float s = (t < len) ? scores[b * Tz + t] : -1e9f;
    float m = s;
#pragma unroll
    for (int o = 32; o; o >>= 1) m = fmaxf(m, __shfl_xor(m, o, 64));
    if ((t & 63) == 0) rA[t >> 6] = m;
    __syncthreads();
    m = fmaxf(rA[0], rA[1]);
    float e = expf(s - m);
    float sum = e;
#pragma unroll
    for (int o = 32; o; o >>= 1) sum += __shfl_xor(sum, o, 64);
    if ((t & 63) == 0) rB[t >> 6] = sum;
    __syncthreads();
    sum = rB[0] + rB[1];
    sal[t] = e / sum;
    __syncthreads();
    if (t < 96) {
        const unsigned short* hp = Hbf + (long)b * Tz * DHz + t * 8;
        float acc[8] = {};
        for (int tt = 0; tt < Tz; ++tt) {
            short8 v = *(const short8*)(hp + (long)tt * DHz);
            float a = sal[tt];
            const unsigned short* pv = (const unsigned short*)&v;
#pragma unroll
            for (int e2 = 0; e2 < 8; ++e2) acc[e2] += a * bf2f(pv[e2]);
        }
        float* rp = rbuf + (long)b * DHz + t * 8;
#pragma unroll
        for (int e2 = 0; e2 < 8; ++e2) rp[e2] = acc[e2];
    }
}

// ---------- h_star = tanh([r | H_last] @ [Wp; Wx])  (bf16 MFMA, K=1536) ----------
__global__ __launch_bounds__(256) void k_hstar(const float* __restrict__ rbuf,
                                               const unsigned short* __restrict__ Hbf,
                                               const unsigned short* __restrict__ WbP,
                                               float* __restrict__ hst) {
    __shared__ unsigned short sA[128 * 40];
    __shared__ unsigned short sB[128 * 40];
    int tid = threadIdx.x;
    int n0 = blockIdx.x * 128;
    int m0 = blockIdx.y * 128;
    int wid = tid >> 6, lane = tid & 63, l15 = lane & 15, q = lane >> 4;
    int wm = wid >> 1, wn = wid & 1;
    int arow = tid >> 1;
    int kp = (tid & 1) * 16;
    int s0 = tid, s1 = tid + 256;
    int bd0 = (s0 >> 2) * 40 + (((s0 & 3) ^ (((s0 >> 2) >> 3) & 3)) << 3);
    int bd1 = (s1 >> 2) * 40 + (((s1 & 3) ^ (((s1 >> 2) >> 3) & 3)) << 3);

    f32x4 acc[4][4];
    f32x4 zz = {0.f, 0.f, 0.f, 0.f};
#pragma unroll
    for (int i = 0; i < 4; ++i)
#pragma unroll
        for (int j = 0; j < 4; ++j) acc[i][j] = zz;

    for (int k0 = 0; k0 < 2 * DHz; k0 += 32) {
        if (k0 < DHz) {
            const float* src = rbuf + (long)(m0 + arow) * DHz + k0 + kp;
            alignas(16) unsigned short tmp[16];
#pragma unroll
            for (int it = 0; it < 4; ++it) {
                float4 v = ((const float4*)src)[it];
                tmp[it * 4 + 0] = f2bf(v.x); tmp[it * 4 + 1] = f2bf(v.y);
                tmp[it * 4 + 2] = f2bf(v.z); tmp[it * 4 + 3] = f2bf(v.w);
            }
            *(int4*)(sA + arow * 40 + kp) = *(const int4*)tmp;
            *(int4*)(sA + arow * 40 + kp + 8) = *(const int4*)(tmp + 8);
        } else {
            const unsigned short* src = Hbf + ((long)(m0 + arow) * Tz + (Tz - 1)) * DHz
                                      + (k0 - DHz) + kp;
            *(int4*)(sA + arow * 40 + kp) = *(const int4*)src;
            *(int4*)(sA + arow * 40 + kp + 8) = *(const int4*)(src + 8);
        }
        {
            const int4* wsrc = (const int4*)WbP
                + ((long)((k0 >> 5) * 6 + (n0 >> 7))) * 512 + tid;
            int4 v0 = wsrc[0];
            int4 v1 = wsrc[256];
            *(int4*)(sB + bd0) = v0;
            *(int4*)(sB + bd1) = v1;
        }
        __syncthreads();
        short8 af[4], bfr[4];
#pragma unroll
        for (int i = 0; i < 4; ++i)
            af[i] = *(const short8*)(sA + (wm * 64 + i * 16 + l15) * 40 + q * 8);
#pragma unroll
        for (int j = 0; j < 4; ++j) {
            int n = wn * 64 + j * 16 + l15;
            bfr[j] = *(const short8*)(sB + n * 40 + ((q ^ ((n >> 3) & 3)) << 3));
        }
#pragma unroll
        for (int i = 0; i < 4; ++i)
#pragma unroll
            for (int j = 0; j < 4; ++j)
                acc[i][j] = __builtin_amdgcn_mfma_f32_16x16x32_bf16(af[i], bfr[j], acc[i][j], 0, 0, 0);
        __syncthreads();
    }
#pragma unroll
    for (int i = 0; i < 4; ++i)
#pragma unroll
        for (int j = 0; j < 4; ++j) {
            int col = n0 + wn * 64 + j * 16 + l15;
#pragma unroll
            for (int r = 0; r < 4; ++r) {
                int row = m0 + wm * 64 + i * 16 + q * 4 + r;
                hst[(long)row * DHz + col] = ftanh(acc[i][j][r]);
            }
        }
}

// ---------- logits ----------
__global__ void k_logits(const float* __restrict__ hst, const float* __restrict__ Wl,
                         const float* __restrict__ bl, float* __restrict__ out) {
    int b = blockIdx.x;
    int lane = threadIdx.x & 63, c = threadIdx.x >> 6;
    float s = 0.f;
    for (int k = lane; k < DHz; k += 64) s += hst[(long)b * DHz + k] * Wl[k * 3 + c];
#pragma unroll
    for (int o = 32; o; o >>= 1) s += __shfl_xor(s, o, 64);
    if (lane == 0) out[b * 3 + c] = s + bl[c];
}

extern "C" void kernel_launch(void* const* d_in, const int* in_sizes, int n_in,
                              void* d_out, int out_size, void* d_ws, size_t ws_size,
                              hipStream_t stream) {
    (void)in_sizes; (void)n_in; (void)out_size; (void)ws_size;
    const int*   sent   = (const int*)d_in[0];
    const int*   target = (const int*)d_in[1];
    const int*   lens   = (const int*)d_in[2];
    const float* emb    = (const float*)d_in[3];
    const float* temb   = (const float*)d_in[4];
    const float* W_ih   = (const float*)d_in[5];
    const float* W_hh   = (const float*)d_in[6];
    const float* b_lstm = (const float*)d_in[7];
    const float* Wh     = (const float*)d_in[8];
    const float* wv     = (const float*)d_in[10];
    const float* Wp     = (const float*)d_in[11];
    const float* Wx     = (const float*)d_in[12];
    const float* W_lin  = (const float*)d_in[13];
    const float* b_lin  = (const float*)d_in[14];
    float* out = (float*)d_out;

    char* ws = (char*)d_ws;
    size_t off = 0;
    auto alloc = [&](size_t bytes) -> void* {
        void* p = ws + off;
        off = (off + bytes + 255) & ~(size_t)255;
        return p;
    };
    unsigned short* xW    = (unsigned short*)alloc((size_t)32768 * G4z * 2);
    unsigned short* Hbf   = (unsigned short*)alloc((size_t)Bz * Tz * DHz * 2);
    unsigned short* WihbP = (unsigned short*)alloc((size_t)24 * 24 * 512 * 16);
    unsigned short* Wih2P = (unsigned short*)alloc((size_t)24 * 24 * 512 * 16);
    unsigned short* WhhP  = (unsigned short*)alloc((size_t)48 * 6144 * 16);
    unsigned short* WhbP  = (unsigned short*)alloc((size_t)24 * 6 * 512 * 16);
    unsigned short* WpxP  = (unsigned short*)alloc((size_t)48 * 6 * 512 * 16);
    float* constg = (float*)alloc((size_t)Bz * G4z * 4);
    float* cbuf   = (float*)alloc((size_t)Bz * DHz * 4);
    float* scores = (float*)alloc((size_t)Bz * Tz * 4);
    float* rbuf   = (float*)alloc((size_t)Bz * DHz * 4);
    float* hst    = (float*)alloc((size_t)Bz * DHz * 4);
    unsigned* bar = (unsigned*)alloc(65536);    // h flags: 8 groups x 48 x 128B
    unsigned* xwc = (unsigned*)alloc(16384);    // xW arrival counters: 128 x 128B

    k_prep_all<<<1584, 256, 0, stream>>>(W_ih, Wh, Wp, Wx, WihbP, Wih2P, WhbP, WpxP);
    k_prep_whh<<<1152, 256, 0, stream>>>(W_hh, WhhP);
    hipMemsetAsync(scores, 0, (size_t)Bz * Tz * 4, stream);
    hipMemsetAsync(bar, 0, 65536, stream);
    hipMemsetAsync(xwc, 0, 16384, stream);

    k_gemm_cg<<<dim3(24, 2), 256, 0, stream>>>(target, temb, Wih2P, b_lstm, constg);

    hipFuncSetAttribute((const void*)k_lstm_all,
                        hipFuncAttributeMaxDynamicSharedMemorySize, 98304);
    int t0v = 0, t1v = Tz, waitv = 1, nprodv = NGRID - NBLK;
    unsigned short* xWp = xW;
    const float* cgp = constg;
    const unsigned short* whp = WhhP;
    unsigned short* hbp = Hbf;
    float* cbp = cbuf;
    const int* lnp = lens;
    unsigned* barp = bar;
    unsigned* xwcp = xwc;
    const float* embp = emb;
    const int* sentp = sent;
    const unsigned short* wihp = WihbP;
    const unsigned short* whbp = WhbP;
    const float* wvp = wv;
    float* scp = scores;
    void* kargs[] = {&t0v, &t1v, &xWp, &cgp, &whp, &hbp, &cbp, &lnp, &barp,
                     &xwcp, &waitv, &embp, &sentp, &wihp, &nprodv,
                     &whbp, &wvp, &scp};
    hipError_t ce = hipLaunchCooperativeKernel(reinterpret_cast<void*>(k_lstm_all),
                                               dim3(NGRID), dim3(256), kargs, 98304, stream);
    if (ce != hipSuccess) {
        // fallback: serial gemm_x + per-step LSTM + separate scores
        k_gemm_x<<<dim3(24, 256), 256, 0, stream>>>(emb, sent, WihbP, xW);
        for (int t = 0; t < Tz; ++t)
            k_lstm_all<<<NBLK, 256, 98304, stream>>>(t, t + 1, xW, constg, WhhP, Hbf,
                                                     cbuf, lens, bar, xwc, 0,
                                                     emb, sent, WihbP, 0,
                                                     WhbP, wv, scores);
        k_scores<<<dim3(6, 256), 256, 0, stream>>>(Hbf, WhbP, wv, scores);
    }

    k_attn<<<Bz, 128, 0, stream>>>(scores, lens, Hbf, rbuf);
    k_hstar<<<dim3(6, 2), 256, 0, stream>>>(rbuf, Hbf, WpxP, hst);
    k_logits<<<Bz, 192, 0, stream>>>(hst, W_lin, b_lin, out);
}